// Round 7
// baseline (1252.934 us; speedup 1.0000x reference)
//
#include <hip/hip_runtime.h>
#include <hip/hip_bf16.h>
#include <math.h>

#define B_ 8
#define L_ 512
#define DV_ 512
#define DM_ 512
#define PL_ 96
#define EL_ 3
#define DS_ 16
#define DC_ 4
#define DI_ 1024
#define DTR_ 32
#define S_ 512
#define CH_ 16         // scan chunks (CS=32: round-4 proven config)
#define CS_ 32         // steps per chunk

typedef float f32x4 __attribute__((ext_vector_type(4)));
typedef short bf16x8 __attribute__((ext_vector_type(8)));
typedef short bf16x4 __attribute__((ext_vector_type(4)));

__device__ __forceinline__ float bf2f(short s) {
  unsigned u = ((unsigned)(unsigned short)s) << 16;
  return __builtin_bit_cast(float, u);
}
__device__ __forceinline__ short f2bf(float f) {
  unsigned u = __builtin_bit_cast(unsigned, f);
  u = u + 0x7FFFu + ((u >> 16) & 1u);   // RNE
  return (short)(u >> 16);
}
__device__ __forceinline__ float h2f(unsigned short u) {
  _Float16 h = __builtin_bit_cast(_Float16, u);
  return (float)h;
}
__device__ __forceinline__ unsigned short f2h(float f) {
  _Float16 h = (_Float16)f;
  return __builtin_bit_cast(unsigned short, h);
}

// global -> LDS DMA, 16B per lane.  LDS dest is wave-uniform base + lane*16.
__device__ __forceinline__ void gload16(const short* g, short* l) {
  __builtin_amdgcn_global_load_lds(
      (const __attribute__((address_space(1))) void*)g,
      (__attribute__((address_space(3))) void*)l, 16, 0, 0);
}

// ---------------------------------------------------------------------------
// One-shot fp32 -> bf16 conversion of ALL GEMM weights into workspace.
// ---------------------------------------------------------------------------
#define WC0 65536                 // emb_w      512*512
#define WC1 (WC0 + 1572864)       // m_in_w     6*2048*512
#define WC2 (WC1 + 98304)         // m_xp_w     6*64*1024
#define WC3 (WC2 + 49152)         // m_dt_w     6*1024*32
#define WC4 (WC3 + 786432)        // m_out_w    6*512*1024
#define WC5 (WC4 + 786432)        // ffn_w1     3*2048*512
#define WC6 (WC5 + 786432)        // ffn_w2     3*512*2048
#define WC7 (WC6 + 12288)        // proj_w     96*512
// WC7 = 4157440 float4s; grid = 16240 * 256 exactly.

__global__ __launch_bounds__(256)
void wcvt_k(const float* __restrict__ e, const float* __restrict__ iw,
            const float* __restrict__ xp, const float* __restrict__ dtw,
            const float* __restrict__ ow, const float* __restrict__ w1,
            const float* __restrict__ w2, const float* __restrict__ pw,
            short* __restrict__ de, short* __restrict__ di,
            short* __restrict__ dxp, short* __restrict__ ddt,
            short* __restrict__ dow, short* __restrict__ dw1,
            short* __restrict__ dw2, short* __restrict__ dpw)
{
  int idx = blockIdx.x * 256 + threadIdx.x;
  const float* s; short* d; int off;
  if (idx < WC0)      { s = e;   d = de;  off = idx; }
  else if (idx < WC1) { s = iw;  d = di;  off = idx - WC0; }
  else if (idx < WC2) { s = xp;  d = dxp; off = idx - WC1; }
  else if (idx < WC3) { s = dtw; d = ddt; off = idx - WC2; }
  else if (idx < WC4) { s = ow;  d = dow; off = idx - WC3; }
  else if (idx < WC5) { s = w1;  d = dw1; off = idx - WC4; }
  else if (idx < WC6) { s = w2;  d = dw2; off = idx - WC5; }
  else                { s = pw;  d = dpw; off = idx - WC6; }
  float4 v = ((const float4*)s)[off];
  union { short sh[4]; int2 p; } r;
  r.sh[0] = f2bf(v.x); r.sh[1] = f2bf(v.y);
  r.sh[2] = f2bf(v.z); r.sh[3] = f2bf(v.w);
  ((int2*)d)[off] = r.p;
}

// ---------------------------------------------------------------------------
// Instance-norm statistics over the time axis (L) of x (B,L,DV) fp32.
// ---------------------------------------------------------------------------
__global__ __launch_bounds__(256)
void stats_k(const float* __restrict__ x, float* __restrict__ means,
             float* __restrict__ stdev, float* __restrict__ rstd,
             float* __restrict__ xlast)
{
  int d = blockIdx.x * 256 + threadIdx.x;       // 0..511
  int b = blockIdx.y;
  const float* xp = x + (size_t)b * L_ * DV_ + d;
  float s = 0.f, ss = 0.f;
  for (int l = 0; l < L_; l++) {
    float v = xp[(size_t)l * DV_];
    s += v; ss += v * v;
  }
  float mu = s / (float)L_;
  float var = ss / (float)L_ - mu * mu;
  float sd = sqrtf(var + 1e-5f);
  float rs = 1.f / sd;
  int idx = b * DV_ + d;
  means[idx] = mu; stdev[idx] = sd; rstd[idx] = rs;
  xlast[idx] = (xp[(size_t)(L_ - 1) * DV_] - mu) * rs;
}

// ---------------------------------------------------------------------------
// Normalize + transpose: xnT[b,d,l] = (x[b,l,d]-mu[b,d])*rstd[b,d]  (bf16)
// ---------------------------------------------------------------------------
__global__ __launch_bounds__(256)
void tnorm_k(const float* __restrict__ x, const float* __restrict__ means,
             const float* __restrict__ rstd, short* __restrict__ xnT)
{
  __shared__ float tile[64][65];
  const int t = threadIdx.x;
  const int j = t & 63;
  const int i0 = t >> 6;                 // 0..3
  const int bz = blockIdx.z;
  const int l0 = blockIdx.y << 6;
  const int d0 = blockIdx.x << 6;
  const float* xp = x + ((size_t)bz * L_ + l0) * DV_ + d0;
  #pragma unroll
  for (int i = i0; i < 64; i += 4) tile[i][j] = xp[(size_t)i * DV_ + j];
  __syncthreads();
  short* op = xnT + ((size_t)bz * DV_ + d0) * L_ + l0;
  const int sb = bz * DV_ + d0;
  #pragma unroll
  for (int i = i0; i < 64; i += 4) {
    float mu = means[sb + i];
    float rs = rstd[sb + i];
    op[(size_t)i * L_ + j] = f2bf((tile[j][i] - mu) * rs);
  }
}

// ---------------------------------------------------------------------------
// Fused LayerNorm: optionally h += add (+ abias) in place, then LN -> bf16.
// ADD: 0 = plain, 1 = h += bf16 add, 2 = h += bf16 add + fp32 bias[col].
// ---------------------------------------------------------------------------
template <int ADD>
__global__ __launch_bounds__(256)
void ln_k(float* __restrict__ X, const short* __restrict__ add,
          const float* __restrict__ abias,
          const float* __restrict__ g, const float* __restrict__ b,
          short* __restrict__ Y)
{
  int row = blockIdx.x;
  float* x = X + (size_t)row * DM_;
  int t = threadIdx.x;
  float v0 = x[t], v1 = x[t + 256];
  if constexpr (ADD >= 1) {
    v0 += bf2f(add[(size_t)row * DM_ + t]);
    v1 += bf2f(add[(size_t)row * DM_ + t + 256]);
    if constexpr (ADD == 2) { v0 += abias[t]; v1 += abias[t + 256]; }
    x[t] = v0; x[t + 256] = v1;
  }
  float s = v0 + v1, ss = v0 * v0 + v1 * v1;
  #pragma unroll
  for (int o = 1; o < 64; o <<= 1) { s += __shfl_xor(s, o); ss += __shfl_xor(ss, o); }
  __shared__ float sb[8];
  int wave = t >> 6, lane = t & 63;
  if (lane == 0) { sb[wave] = s; sb[4 + wave] = ss; }
  __syncthreads();
  s = sb[0] + sb[1] + sb[2] + sb[3];
  ss = sb[4] + sb[5] + sb[6] + sb[7];
  float mu = s / (float)DM_;
  float var = ss / (float)DM_ - mu * mu;
  float rs = rsqrtf(var + 1e-5f);
  Y[(size_t)row * DM_ + t]       = f2bf((v0 - mu) * rs * g[t]       + b[t]);
  Y[(size_t)row * DM_ + t + 256] = f2bf((v1 - mu) * rs * g[t + 256] + b[t + 256]);
}

// ---------------------------------------------------------------------------
// Depthwise causal conv (DC=4 taps) + bias + silu.  Vectorized: 8 channels
// per thread (bf16x8 u loads, float4 weights, bf16x8 store).
// ---------------------------------------------------------------------------
template <int REV>
__global__ __launch_bounds__(256)
void conv_k(const short* __restrict__ xz, const float* __restrict__ w,
            const float* __restrict__ cb, short* __restrict__ xc)
{
  int idx = blockIdx.x * 256 + threadIdx.x;   // over B*S*DI/8
  int ig = (idx & 127) << 3;                  // channel group base
  int bs = idx >> 7;                          // b*S + t
  int tt0 = bs & (S_ - 1);
  int b = bs >> 9;
  const short* u = xz + (size_t)b * S_ * (2 * DI_) + ig;  // row stride 2*DI
  float4 wv[8];
  #pragma unroll
  for (int n = 0; n < 8; n++) wv[n] = *(const float4*)(w + (ig + n) * DC_);
  float acc[8];
  {
    float4 c0 = *(const float4*)(cb + ig);
    float4 c1 = *(const float4*)(cb + ig + 4);
    acc[0] = c0.x; acc[1] = c0.y; acc[2] = c0.z; acc[3] = c0.w;
    acc[4] = c1.x; acc[5] = c1.y; acc[6] = c1.z; acc[7] = c1.w;
  }
  #pragma unroll
  for (int k = 0; k < DC_; k++) {
    int tt = REV ? (tt0 + (DC_ - 1) - k) : (tt0 - (DC_ - 1) + k);
    if (tt >= 0 && tt < S_) {
      bf16x8 uv = *(const bf16x8*)(u + (size_t)tt * (2 * DI_));
      #pragma unroll
      for (int n = 0; n < 8; n++) {
        float wk = (k == 0) ? wv[n].x : (k == 1) ? wv[n].y
                 : (k == 2) ? wv[n].z : wv[n].w;
        acc[n] += wk * bf2f(uv[n]);
      }
    }
  }
  union { short sh[8]; bf16x8 v; } r;
  #pragma unroll
  for (int n = 0; n < 8; n++) {
    float sig = 1.f / (1.f + __expf(-acc[n]));
    r.sh[n] = f2bf(acc[n] * sig);
  }
  *(bf16x8*)(xc + ((size_t)bs << 10) + ig) = r.v;
}

// ---------------------------------------------------------------------------
// Chunked selective scan — round-4 proven structure: 4-way state split
// (thread (b,i,q) owns states 4q..4q+3), CS=32/CH=16, grid (128,16)=2048
// blocks (64% occ measured).  exp(dt*A) = exp2(dt*(A*log2e)) with log2e
// pre-folded into the per-state constant (saves 1 VALU mul per exp).
// ---------------------------------------------------------------------------
#define LOG2E_ 1.44269504088896f

template <int REV>
__global__ __launch_bounds__(256)
void scan_p1(const unsigned short* __restrict__ dt16, const short* __restrict__ xc,
             const short* __restrict__ xdbl, const float* __restrict__ A_log,
             unsigned short* __restrict__ part_h, unsigned short* __restrict__ part_A)
{
  const int gid = blockIdx.x * 256 + threadIdx.x;   // over B*DI*4
  const int q = gid & 3;                            // state quad
  const int i = (gid >> 2) & (DI_ - 1);
  const int b = gid >> 12;
  const int c = blockIdx.y;
  float Ai2[4];
  const float* al = A_log + i * DS_ + q * 4;
  #pragma unroll
  for (int n = 0; n < 4; n++) Ai2[n] = -__expf(al[n]) * LOG2E_;

  const int ti0 = REV ? (S_ - 1 - c * CS_) : (c * CS_);
  const unsigned short* pdt = dt16 + ((size_t)b * S_ + ti0) * DI_ + i;
  const short* pu = xc + ((size_t)b * S_ + ti0) * DI_ + i;
  const short* pbc = xdbl + (((size_t)b * S_ + ti0) << 6) + DTR_ + q * 4;
  const int sstep = REV ? -DI_ : DI_;
  const int sbc = REV ? -64 : 64;

  float h[4];
  #pragma unroll
  for (int n = 0; n < 4; n++) h[n] = 0.f;
  float dsum = 0.f;

  #pragma unroll 4
  for (int sl = 0; sl < CS_; sl++) {
    float dtv = h2f(*pdt);
    float u = bf2f(*pu);
    bf16x4 vB = *(const bf16x4*)pbc;
    float du = dtv * u;
    dsum += dtv;
    #pragma unroll
    for (int n = 0; n < 4; n++) {
      float dA = exp2f(dtv * Ai2[n]);
      h[n] = dA * h[n] + du * bf2f(vB[n]);
    }
    pdt += sstep; pu += sstep; pbc += sbc;
  }
  union { unsigned short s[4]; int2 v; } uh, ua;
  #pragma unroll
  for (int n = 0; n < 4; n++) {
    uh.s[n] = f2h(h[n]);
    ua.s[n] = f2h(exp2f(Ai2[n] * dsum));   // exact: prod exp(dt*A)=exp(A*sum dt)
  }
  const size_t ix = ((((size_t)c * B_ + b) * DI_ + i) << 4) + (q << 2);
  *(int2*)(part_h + ix) = uh.v;
  *(int2*)(part_A + ix) = ua.v;
}

__global__ __launch_bounds__(256)
void scan_p2(unsigned short* __restrict__ part_h,
             const unsigned short* __restrict__ part_A)
{
  const size_t gid = (size_t)blockIdx.x * 256 + threadIdx.x;   // B*DI*DS
  const size_t stride = (size_t)B_ * DI_ * DS_;
  float hin = 0.f;
  #pragma unroll
  for (int c = 0; c < CH_; c++) {
    size_t ix = (size_t)c * stride + gid;
    float hh = h2f(part_h[ix]);
    float pA = h2f(part_A[ix]);
    part_h[ix] = f2h(hin);            // becomes chunk c's incoming state
    hin = hh + pA * hin;
  }
}

// y may alias dt16 (element-exact same indices) — no __restrict__ on those.
template <int REV>
__global__ __launch_bounds__(256)
void scan_p3(const unsigned short* dt16, const short* __restrict__ xc,
             const short* __restrict__ xdbl, const short* __restrict__ xz,
             const float* __restrict__ A_log, const float* __restrict__ Dp,
             const unsigned short* __restrict__ part_h, short* y)
{
  const int gid = blockIdx.x * 256 + threadIdx.x;   // over B*DI*4
  const int q = gid & 3;                            // state quad
  const int i = (gid >> 2) & (DI_ - 1);
  const int b = gid >> 12;
  const int c = blockIdx.y;
  float Ai2[4];
  const float* al = A_log + i * DS_ + q * 4;
  #pragma unroll
  for (int n = 0; n < 4; n++) Ai2[n] = -__expf(al[n]) * LOG2E_;
  const float Di = Dp[i];

  float h[4];
  {
    const size_t ix = ((((size_t)c * B_ + b) * DI_ + i) << 4) + (q << 2);
    union { unsigned short s[4]; int2 v; } uh;
    uh.v = *(const int2*)(part_h + ix);
    #pragma unroll
    for (int n = 0; n < 4; n++) h[n] = h2f(uh.s[n]);
  }

  const int ti0 = REV ? (S_ - 1 - c * CS_) : (c * CS_);
  const unsigned short* pdt = dt16 + ((size_t)b * S_ + ti0) * DI_ + i;
  const short* pu = xc + ((size_t)b * S_ + ti0) * DI_ + i;
  const short* pbc = xdbl + (((size_t)b * S_ + ti0) << 6) + DTR_ + q * 4;
  const short* pz = xz + ((size_t)b * S_ + ti0) * (2 * DI_) + DI_ + i;
  short* py = y + ((size_t)b * S_ + ti0) * DI_ + i;
  const int sstep = REV ? -DI_ : DI_;
  const int sbc = REV ? -64 : 64;
  const int sz = REV ? -(2 * DI_) : (2 * DI_);

  #pragma unroll 4
  for (int sl = 0; sl < CS_; sl++) {
    float dtv = h2f(*pdt);
    float u = bf2f(*pu);
    bf16x4 vB = *(const bf16x4*)pbc;
    bf16x4 vC = *(const bf16x4*)(pbc + DS_);
    float zv = bf2f(*pz);
    float du = dtv * u;
    float yp = 0.f;
    #pragma unroll
    for (int n = 0; n < 4; n++) {
      float dA = exp2f(dtv * Ai2[n]);
      h[n] = dA * h[n] + du * bf2f(vB[n]);
      yp += h[n] * bf2f(vC[n]);
    }
    yp += __shfl_xor(yp, 1);
    yp += __shfl_xor(yp, 2);            // quad-wide sum over all 16 states
    float sil = zv / (1.f + __expf(-zv));
    float yv = (yp + u * Di) * sil;
    if (q == 0) *py = f2bf(yv);
    pdt += sstep; pu += sstep; pbc += sbc; pz += sz; py += sstep;
  }
}

// ---------------------------------------------------------------------------
// bf16 MFMA GEMM: C[M,N] = A[M,K] * W[N,K]^T, fp32 accum.  A and W bf16
// (weights pre-converted by wcvt_k).  Staging via global_load_lds DMA —
// ZERO staging registers.  Swizzle folded into the GLOBAL source chunk
// index (rule #21: linear LDS dest + inverse-swizzled source).  3 LDS
// buffers, 2 slabs in flight, raw s_barrier + counted vmcnt.
// ---------------------------------------------------------------------------
enum { EPI_F32_BIAS, EPI_BF16, EPI_F16_SOFTPLUS, EPI_HALF_BF16, EPI_GELU,
       EPI_PROJ };

template <int EPI, int BM, int BN, int BK>
__global__ __launch_bounds__(256)
void gemm_k(const short* __restrict__ A0, const short* __restrict__ A1,
            const short* __restrict__ W0, const short* __restrict__ W1,
            int khalf, int N, int K, int lda, int ldw,
            float* __restrict__ Cf, short* __restrict__ Cb, int ldc,
            const float* __restrict__ bias,
            const float* __restrict__ xlast, const float* __restrict__ stdev,
            const float* __restrict__ means)
{
  constexpr int MT = BM / 32;           // 16-row m-tiles per wave
  constexpr int NT = BN / 32;
  constexpr int KS = BK / 32;
  constexpr int CHK = BK / 8;           // 16B chunks per row
  constexpr int MSK = CHK - 1;
  constexpr int NA = (BM * CHK) / 256;  // DMA calls per wave, A slab
  constexpr int NW = (BN * CHK) / 256;  // DMA calls per wave, W slab
  constexpr int VC = NA + NW;           // vmem ops per slab per wave
  __shared__ __align__(16) short As[3][BM * BK];
  __shared__ __align__(16) short Ws[3][BN * BK];
  const int tid = threadIdx.x;
  const int m0 = blockIdx.x * BM;       // fastest dim = m (XCD locality of A)
  const int n0 = blockIdx.y * BN;
  const int wave = tid >> 6, lane = tid & 63;
  const int wm = (wave & 1) * (BM / 2), wn = (wave >> 1) * (BN / 2);
  const int quad = lane >> 4, l16 = lane & 15;

  f32x4 acc[MT][NT] = {};

  // Per-thread global offsets with the XOR swizzle folded into the SOURCE
  // chunk index; LDS destination is linear (id*16B).
  size_t aoff[NA];
  #pragma unroll
  for (int j = 0; j < NA; j++) {
    int id = j * 256 + tid;
    int r = id / CHK, qp = id % CHK;
    aoff[j] = (size_t)(m0 + r) * lda + ((qp ^ (r & MSK)) << 3);
  }
  size_t woff[NW];
  #pragma unroll
  for (int j = 0; j < NW; j++) {
    int id = j * 256 + tid;
    int r = id / CHK, qp = id % CHK;
    int wr = n0 + r; if (wr > N - 1) wr = N - 1;
    woff[j] = (size_t)wr * ldw + ((qp ^ (r & MSK)) << 3);
  }
  const int lbase = wave * 512;         // shorts; wave-uniform lane-0 base

  const int KB = K / BK;

  auto stage = [&](int slab, int bi) {
    const int k0 = slab * BK;
    const short* Ab = (k0 < khalf) ? A0 + k0 : A1 + (k0 - khalf);
    const short* Wb = (k0 < khalf) ? W0 + k0 : W1 + (k0 - khalf);
    #pragma unroll
    for (int j = 0; j < NA; j++)
      gload16(Ab + aoff[j], &As[bi][j * 2048 + lbase]);
    #pragma unroll
    for (int j = 0; j < NW; j++)
      gload16(Wb + woff[j], &Ws[bi][j * 2048 + lbase]);
  };

  // prologue: slabs 0,1 in flight; wait slab 0, barrier.
  stage(0, 0);
  if (KB > 1) stage(1, 1);
  __builtin_amdgcn_sched_barrier(0);
  if (KB > 1) asm volatile("s_waitcnt vmcnt(%0)" :: "n"(VC) : "memory");
  else        asm volatile("s_waitcnt vmcnt(0)" ::: "memory");
  __builtin_amdgcn_s_barrier();
  __builtin_amdgcn_sched_barrier(0);

  int cur = 0, nxt = 2;
  for (int kb = 0; kb < KB; kb++) {
    if (kb + 2 < KB) {
      stage(kb + 2, nxt);               // into (kb-1)%3: read finished last iter
      __builtin_amdgcn_sched_barrier(0);
    }
    bf16x8 af[MT][KS], bfr[NT][KS];
    #pragma unroll
    for (int mt = 0; mt < MT; mt++)
      #pragma unroll
      for (int st = 0; st < KS; st++)
        af[mt][st] = *(const bf16x8*)(&As[cur][0] + (wm + mt * 16 + l16) * BK +
                                      (((st * 4 + quad) ^ (l16 & MSK)) << 3));
    #pragma unroll
    for (int nt = 0; nt < NT; nt++)
      #pragma unroll
      for (int st = 0; st < KS; st++)
        bfr[nt][st] = *(const bf16x8*)(&Ws[cur][0] + (wn + nt * 16 + l16) * BK +
                                       (((st * 4 + quad) ^ (l16 & MSK)) << 3));
    #pragma unroll
    for (int st = 0; st < KS; st++)
      #pragma unroll
      for (int mt = 0; mt < MT; mt++)
        #pragma unroll
        for (int nt = 0; nt < NT; nt++)
          acc[mt][nt] = __builtin_amdgcn_mfma_f32_16x16x32_bf16(
              af[mt][st], bfr[nt][st], acc[mt][nt], 0, 0, 0);
    if (kb + 1 < KB) {
      __builtin_amdgcn_sched_barrier(0);
      // need slab kb+1 done; slab kb+2 (if issued) may stay in flight.
      if (kb + 2 < KB) asm volatile("s_waitcnt vmcnt(%0)" :: "n"(VC) : "memory");
      else             asm volatile("s_waitcnt vmcnt(0)" ::: "memory");
      __builtin_amdgcn_s_barrier();
      __builtin_amdgcn_sched_barrier(0);
      cur = (cur == 2) ? 0 : cur + 1;
      nxt = (nxt == 2) ? 0 : nxt + 1;
    }
  }

  #pragma unroll
  for (int mt = 0; mt < MT; mt++) {
    #pragma unroll
    for (int nt = 0; nt < NT; nt++) {
      int n = n0 + wn + nt * 16 + l16;
      if (n >= N) continue;
      #pragma unroll
      for (int r = 0; r < 4; r++) {
        int m = m0 + wm + mt * 16 + quad * 4 + r;
        float v = acc[mt][nt][r];
        if constexpr (EPI == EPI_F32_BIAS) {
          Cf[(size_t)m * ldc + n] = v + bias[n];
        } else if constexpr (EPI == EPI_BF16) {
          Cb[(size_t)m * ldc + n] = f2bf(v);
        } else if constexpr (EPI == EPI_F16_SOFTPLUS) {
          float tt = v + bias[n];
          float sp = (tt > 20.f) ? tt : log1pf(__expf(tt));
          ((unsigned short*)Cb)[(size_t)m * ldc + n] = f2h(sp);
        } else if constexpr (EPI == EPI_HALF_BF16) {
          Cb[(size_t)m * ldc + n] = f2bf(0.5f * v);
        } else if constexpr (EPI == EPI_GELU) {
          float tt = v + bias[n];
          Cb[(size_t)m * ldc + n] = f2bf(0.5f * tt * (1.f + erff(tt * 0.70710678118f)));
        } else if constexpr (EPI == EPI_PROJ) {
          int bb = m >> 9, d = m & 511;
          float tt = v + bias[n] + xlast[m];
          tt = tt * stdev[m] + means[m];
          Cf[((size_t)bb * PL_ + n) * DV_ + d] = tt;
        }
      }
    }
  }
}

// ---------------------------------------------------------------------------
extern "C" void kernel_launch(void* const* d_in, const int* in_sizes, int n_in,
                              void* d_out, int out_size, void* d_ws, size_t ws_size,
                              hipStream_t stream)
{
  (void)in_sizes; (void)n_in; (void)out_size; (void)ws_size;
  const float* x        = (const float*)d_in[0];
  const float* emb_w    = (const float*)d_in[1];
  const float* emb_b    = (const float*)d_in[2];
  const float* ln_g     = (const float*)d_in[3];
  const float* ln_b     = (const float*)d_in[4];
  const float* m_in_w   = (const float*)d_in[5];
  const float* m_conv_w = (const float*)d_in[6];
  const float* m_conv_b = (const float*)d_in[7];
  const float* m_xp_w   = (const float*)d_in[8];
  const float* m_dt_w   = (const float*)d_in[9];
  const float* m_dt_b   = (const float*)d_in[10];
  const float* m_A_log  = (const float*)d_in[11];
  const float* m_D      = (const float*)d_in[12];
  const float* m_out_w  = (const float*)d_in[13];
  const float* ffn_ln_g = (const float*)d_in[14];
  const float* ffn_ln_b = (const float*)d_in[15];
  const float* ffn_w1   = (const float*)d_in[16];
  const float* ffn_b1   = (const float*)d_in[17];
  const float* ffn_w2   = (const float*)d_in[18];
  const float* ffn_b2   = (const float*)d_in[19];
  const float* enc_g    = (const float*)d_in[20];
  const float* enc_b    = (const float*)d_in[21];
  const float* proj_w   = (const float*)d_in[22];
  const float* proj_b   = (const float*)d_in[23];
  float* out = (float*)d_out;

  char* ws = (char*)d_ws;
  const size_t MB = 1024 * 1024;
  float* h      = (float*)(ws + 0);        //  8 MB fp32 residual stream
  short* hn     = (short*)(ws + 8 * MB);   //  4 MB LN output bf16
  short* xz     = (short*)(ws + 12 * MB);  // 16 MB [M][2048] per-dir
  short* xc     = (short*)(ws + 28 * MB);  //  8 MB [M][1024] per-dir
  short* xdbl   = (short*)(ws + 36 * MB);  // .5 MB [M][64]
  float* stats  = (float*)(ws + 36 * MB + 512 * 1024);          // 64 KB
  unsigned short* dtb = (unsigned short*)(ws + 37 * MB); // 8 MB fp16 dt; scan_p3 dir1 writes y in place
  unsigned short* part_h = (unsigned short*)(ws + 45 * MB);     // 4 MB (scan only)
  unsigned short* part_A = (unsigned short*)(ws + 49 * MB);     // 4 MB (scan only)
  short* vtmp   = (short*)(ws + 47 * MB);  // 4 MB bf16 mamba out (after scans done)
  short* ftmp   = (short*)(ws + 47 * MB);  // 4 MB bf16 ffn2 out (aliases vtmp, sequential)
  short* yact0  = (short*)(ws + 53 * MB);  //  8 MB y(dir0); xnT aliases pre-layer
  short* xnT    = (short*)(ws + 53 * MB);
  float* means = stats, *stdevp = stats + 4096, *rstd = stats + 8192, *xlast = stats + 12288;

  // bf16 weight pool @ 61 MB (~32 MB total, high-water ~94 MB)
  short* emb_wb = (short*)(ws + 61 * MB);
  short* in_wb  = emb_wb + 262144;      // 6 x 2048x512
  short* xp_wb  = in_wb  + 6291456;     // 6 x 64x1024
  short* dt_wb  = xp_wb  + 393216;      // 6 x 1024x32
  short* out_wb = dt_wb  + 196608;      // 6 x 512x1024
  short* w1b    = out_wb + 3145728;     // 3 x 2048x512
  short* w2b    = w1b    + 3145728;     // 3 x 512x2048
  short* projb  = w2b    + 3145728;     // 96x512

  dim3 blk(256);
  const int NOSPLIT = 1 << 30;

  wcvt_k<<<dim3(16240), blk, 0, stream>>>(
      emb_w, m_in_w, m_xp_w, m_dt_w, m_out_w, ffn_w1, ffn_w2, proj_w,
      emb_wb, in_wb, xp_wb, dt_wb, out_wb, w1b, w2b, projb);

  stats_k<<<dim3(2, B_), blk, 0, stream>>>(x, means, stdevp, rstd, xlast);
  tnorm_k<<<dim3(8, 8, B_), blk, 0, stream>>>(x, means, rstd, xnT);
  // emb: M=4096, N=512, K=512 — 64x32 BK=64, grid (64, 16)
  gemm_k<EPI_F32_BIAS, 64, 32, 64><<<dim3(64, 16), blk, 0, stream>>>(
      xnT, xnT, emb_wb, emb_wb, NOSPLIT, DM_, L_, L_, L_,
      h, nullptr, DM_, emb_b, nullptr, nullptr, nullptr);

  for (int il = 0; il < EL_; il++) {
    if (il == 0)
      ln_k<0><<<dim3(4096), blk, 0, stream>>>(h, nullptr, nullptr, ln_g, ln_b, hn);
    else
      ln_k<2><<<dim3(4096), blk, 0, stream>>>(h, ftmp, ffn_b2 + (il - 1) * DM_,
          ln_g + il * DM_, ln_b + il * DM_, hn);
    for (int dir = 0; dir < 2; dir++) {
      int mod = 2 * il + dir;
      // in-proj: N=2048, K=512 — 64x128 BK=32, grid (64, 16) = 1024 blocks
      gemm_k<EPI_BF16, 64, 128, 32><<<dim3(64, 16), blk, 0, stream>>>(
          hn, hn, in_wb + (size_t)mod * 2 * DI_ * DM_,
          in_wb + (size_t)mod * 2 * DI_ * DM_, NOSPLIT, 2 * DI_, DM_, DM_, DM_,
          nullptr, xz, 2 * DI_, nullptr, nullptr, nullptr, nullptr);
      if (dir == 0)
        conv_k<0><<<dim3(2048), blk, 0, stream>>>(
            xz, m_conv_w + (size_t)mod * DI_ * DC_, m_conv_b + (size_t)mod * DI_, xc);
      else
        conv_k<1><<<dim3(2048), blk, 0, stream>>>(
            xz, m_conv_w + (size_t)mod * DI_ * DC_, m_conv_b + (size_t)mod * DI_, xc);
      // xdbl: N=64, K=1024 — 32x32 BK=64, grid (128, 2)
      gemm_k<EPI_BF16, 32, 32, 64><<<dim3(128, 2), blk, 0, stream>>>(
          xc, xc, xp_wb + (size_t)mod * (DTR_ + 2 * DS_) * DI_,
          xp_wb + (size_t)mod * (DTR_ + 2 * DS_) * DI_, NOSPLIT,
          DTR_ + 2 * DS_, DI_, DI_, DI_,
          nullptr, xdbl, DTR_ + 2 * DS_, nullptr, nullptr, nullptr, nullptr);
      // dt: N=1024, K=32 — 64x64 BK=32, grid (64, 16)
      gemm_k<EPI_F16_SOFTPLUS, 64, 64, 32><<<dim3(64, 16), blk, 0, stream>>>(
          xdbl, xdbl, dt_wb + (size_t)mod * DI_ * DTR_,
          dt_wb + (size_t)mod * DI_ * DTR_, NOSPLIT, DI_, DTR_, DTR_ + 2 * DS_, DTR_,
          nullptr, (short*)dtb, DI_, m_dt_b + (size_t)mod * DI_, nullptr, nullptr, nullptr);
      const float* Alog = m_A_log + (size_t)mod * DI_ * DS_;
      const float* Dp = m_D + (size_t)mod * DI_;
      short* ydst = (dir == 0) ? yact0 : (short*)dtb;   // dir1: in-place over dtb
      if (dir == 0) {
        scan_p1<0><<<dim3(128, CH_), blk, 0, stream>>>(dtb, xc, xdbl, Alog, part_h, part_A);
        scan_p2<<<dim3(512), blk, 0, stream>>>(part_h, part_A);
        scan_p3<0><<<dim3(128, CH_), blk, 0, stream>>>(dtb, xc, xdbl, xz, Alog, Dp, part_h, ydst);
      } else {
        scan_p1<1><<<dim3(128, CH_), blk, 0, stream>>>(dtb, xc, xdbl, Alog, part_h, part_A);
        scan_p2<<<dim3(512), blk, 0, stream>>>(part_h, part_A);
        scan_p3<1><<<dim3(128, CH_), blk, 0, stream>>>(dtb, xc, xdbl, xz, Alog, Dp, part_h, ydst);
      }
    }
    // out-proj (concat-K): vtmp = 0.5*(yf.Wf^T + yb.Wb^T) — 64x32 BK=64, grid (64,16)
    gemm_k<EPI_HALF_BF16, 64, 32, 64><<<dim3(64, 16), blk, 0, stream>>>(
        yact0, (const short*)dtb,
        out_wb + (size_t)(2 * il) * DM_ * DI_,
        out_wb + (size_t)(2 * il + 1) * DM_ * DI_,
        DI_, DM_, 2 * DI_, DI_, DI_,
        nullptr, vtmp, DM_, nullptr, nullptr, nullptr, nullptr);
    // fused: h += vtmp, then LN
    ln_k<1><<<dim3(4096), blk, 0, stream>>>(h, vtmp, nullptr,
        ffn_ln_g + il * DM_, ffn_ln_b + il * DM_, hn);
    // ffn1: N=2048, K=512 — 64x128 BK=32, grid (64, 16)
    gemm_k<EPI_GELU, 64, 128, 32><<<dim3(64, 16), blk, 0, stream>>>(
        hn, hn, w1b + (size_t)il * 4 * DM_ * DM_,
        w1b + (size_t)il * 4 * DM_ * DM_, NOSPLIT, 4 * DM_, DM_, DM_, DM_,
        nullptr, xz, 4 * DM_, ffn_b1 + (size_t)il * 4 * DM_, nullptr, nullptr, nullptr);
    // ffn2: N=512, K=2048 — 64x32 BK=64, grid (64, 16); streaming bf16 out
    gemm_k<EPI_BF16, 64, 32, 64><<<dim3(64, 16), blk, 0, stream>>>(
        xz, xz, w2b + (size_t)il * DM_ * 4 * DM_,
        w2b + (size_t)il * DM_ * 4 * DM_, NOSPLIT, DM_, 4 * DM_, 4 * DM_, 4 * DM_,
        nullptr, ftmp, DM_, nullptr, nullptr, nullptr, nullptr);
    // h += ftmp + ffn_b2 happens in the next layer's LN (or enc-LN below)
  }

  ln_k<2><<<dim3(4096), blk, 0, stream>>>(h, ftmp, ffn_b2 + 2 * DM_,
      enc_g, enc_b, hn);
  // proj: N=96, K=512 — 64x32 BK=64, grid (64, 3)
  gemm_k<EPI_PROJ, 64, 32, 64><<<dim3(64, 3), blk, 0, stream>>>(
      hn, hn, projb, projb, NOSPLIT, PL_, DM_, DM_, DM_,
      out, nullptr, 0, proj_b, xlast, stdevp, means);
}

// Round 8
// 1090.746 us; speedup vs baseline: 1.1487x; 1.1487x over previous
//
#include <hip/hip_runtime.h>
#include <hip/hip_bf16.h>
#include <math.h>

#define B_ 8
#define L_ 512
#define DV_ 512
#define DM_ 512
#define PL_ 96
#define EL_ 3
#define DS_ 16
#define DC_ 4
#define DI_ 1024
#define DTR_ 32
#define S_ 512
#define M_ 4096        // B*S
#define CH_ 16         // scan chunks
#define CS_ 32         // steps per chunk

typedef float f32x4 __attribute__((ext_vector_type(4)));
typedef short bf16x8 __attribute__((ext_vector_type(8)));
typedef short bf16x4 __attribute__((ext_vector_type(4)));

__device__ __forceinline__ float bf2f(short s) {
  unsigned u = ((unsigned)(unsigned short)s) << 16;
  return __builtin_bit_cast(float, u);
}
__device__ __forceinline__ short f2bf(float f) {
  unsigned u = __builtin_bit_cast(unsigned, f);
  u = u + 0x7FFFu + ((u >> 16) & 1u);   // RNE
  return (short)(u >> 16);
}
__device__ __forceinline__ float h2f(unsigned short u) {
  _Float16 h = __builtin_bit_cast(_Float16, u);
  return (float)h;
}
__device__ __forceinline__ unsigned short f2h(float f) {
  _Float16 h = (_Float16)f;
  return __builtin_bit_cast(unsigned short, h);
}

// global -> LDS DMA, 16B per lane.  LDS dest is wave-uniform base + lane*16.
__device__ __forceinline__ void gload16(const short* g, short* l) {
  __builtin_amdgcn_global_load_lds(
      (const __attribute__((address_space(1))) void*)g,
      (__attribute__((address_space(3))) void*)l, 16, 0, 0);
}

// ---------------------------------------------------------------------------
// One-shot fp32 -> bf16 conversion of ALL GEMM weights into workspace.
// ---------------------------------------------------------------------------
#define WC0 65536                 // emb_w      512*512
#define WC1 (WC0 + 1572864)       // m_in_w     6*2048*512
#define WC2 (WC1 + 98304)         // m_xp_w     6*64*1024
#define WC3 (WC2 + 49152)         // m_dt_w     6*1024*32
#define WC4 (WC3 + 786432)        // m_out_w    6*512*1024
#define WC5 (WC4 + 786432)        // ffn_w1     3*2048*512
#define WC6 (WC5 + 786432)        // ffn_w2     3*512*2048
#define WC7 (WC6 + 12288)        // proj_w     96*512
// WC7 = 4157440 float4s; grid = 16240 * 256 exactly.

__global__ __launch_bounds__(256)
void wcvt_k(const float* __restrict__ e, const float* __restrict__ iw,
            const float* __restrict__ xp, const float* __restrict__ dtw,
            const float* __restrict__ ow, const float* __restrict__ w1,
            const float* __restrict__ w2, const float* __restrict__ pw,
            short* __restrict__ de, short* __restrict__ di,
            short* __restrict__ dxp, short* __restrict__ ddt,
            short* __restrict__ dow, short* __restrict__ dw1,
            short* __restrict__ dw2, short* __restrict__ dpw)
{
  int idx = blockIdx.x * 256 + threadIdx.x;
  const float* s; short* d; int off;
  if (idx < WC0)      { s = e;   d = de;  off = idx; }
  else if (idx < WC1) { s = iw;  d = di;  off = idx - WC0; }
  else if (idx < WC2) { s = xp;  d = dxp; off = idx - WC1; }
  else if (idx < WC3) { s = dtw; d = ddt; off = idx - WC2; }
  else if (idx < WC4) { s = ow;  d = dow; off = idx - WC3; }
  else if (idx < WC5) { s = w1;  d = dw1; off = idx - WC4; }
  else if (idx < WC6) { s = w2;  d = dw2; off = idx - WC5; }
  else                { s = pw;  d = dpw; off = idx - WC6; }
  float4 v = ((const float4*)s)[off];
  union { short sh[4]; int2 p; } r;
  r.sh[0] = f2bf(v.x); r.sh[1] = f2bf(v.y);
  r.sh[2] = f2bf(v.z); r.sh[3] = f2bf(v.w);
  ((int2*)d)[off] = r.p;
}

// ---------------------------------------------------------------------------
// Instance-norm statistics over the time axis (L) of x (B,L,DV) fp32.
// ---------------------------------------------------------------------------
__global__ __launch_bounds__(256)
void stats_k(const float* __restrict__ x, float* __restrict__ means,
             float* __restrict__ stdev, float* __restrict__ rstd,
             float* __restrict__ xlast)
{
  int d = blockIdx.x * 256 + threadIdx.x;       // 0..511
  int b = blockIdx.y;
  const float* xp = x + (size_t)b * L_ * DV_ + d;
  float s = 0.f, ss = 0.f;
  for (int l = 0; l < L_; l++) {
    float v = xp[(size_t)l * DV_];
    s += v; ss += v * v;
  }
  float mu = s / (float)L_;
  float var = ss / (float)L_ - mu * mu;
  float sd = sqrtf(var + 1e-5f);
  float rs = 1.f / sd;
  int idx = b * DV_ + d;
  means[idx] = mu; stdev[idx] = sd; rstd[idx] = rs;
  xlast[idx] = (xp[(size_t)(L_ - 1) * DV_] - mu) * rs;
}

// ---------------------------------------------------------------------------
// Normalize + transpose: xnT[b,d,l] = (x[b,l,d]-mu[b,d])*rstd[b,d]  (bf16)
// ---------------------------------------------------------------------------
__global__ __launch_bounds__(256)
void tnorm_k(const float* __restrict__ x, const float* __restrict__ means,
             const float* __restrict__ rstd, short* __restrict__ xnT)
{
  __shared__ float tile[64][65];
  const int t = threadIdx.x;
  const int j = t & 63;
  const int i0 = t >> 6;                 // 0..3
  const int bz = blockIdx.z;
  const int l0 = blockIdx.y << 6;
  const int d0 = blockIdx.x << 6;
  const float* xp = x + ((size_t)bz * L_ + l0) * DV_ + d0;
  #pragma unroll
  for (int i = i0; i < 64; i += 4) tile[i][j] = xp[(size_t)i * DV_ + j];
  __syncthreads();
  short* op = xnT + ((size_t)bz * DV_ + d0) * L_ + l0;
  const int sb = bz * DV_ + d0;
  #pragma unroll
  for (int i = i0; i < 64; i += 4) {
    float mu = means[sb + i];
    float rs = rstd[sb + i];
    op[(size_t)i * L_ + j] = f2bf((tile[j][i] - mu) * rs);
  }
}

// ---------------------------------------------------------------------------
// Fused LayerNorm: optionally h += add (+ abias) in place, then LN -> bf16.
// ---------------------------------------------------------------------------
template <int ADD>
__global__ __launch_bounds__(256)
void ln_k(float* __restrict__ X, const short* __restrict__ add,
          const float* __restrict__ abias,
          const float* __restrict__ g, const float* __restrict__ b,
          short* __restrict__ Y)
{
  int row = blockIdx.x;
  float* x = X + (size_t)row * DM_;
  int t = threadIdx.x;
  float v0 = x[t], v1 = x[t + 256];
  if constexpr (ADD >= 1) {
    v0 += bf2f(add[(size_t)row * DM_ + t]);
    v1 += bf2f(add[(size_t)row * DM_ + t + 256]);
    if constexpr (ADD == 2) { v0 += abias[t]; v1 += abias[t + 256]; }
    x[t] = v0; x[t + 256] = v1;
  }
  float s = v0 + v1, ss = v0 * v0 + v1 * v1;
  #pragma unroll
  for (int o = 1; o < 64; o <<= 1) { s += __shfl_xor(s, o); ss += __shfl_xor(ss, o); }
  __shared__ float sb[8];
  int wave = t >> 6, lane = t & 63;
  if (lane == 0) { sb[wave] = s; sb[4 + wave] = ss; }
  __syncthreads();
  s = sb[0] + sb[1] + sb[2] + sb[3];
  ss = sb[4] + sb[5] + sb[6] + sb[7];
  float mu = s / (float)DM_;
  float var = ss / (float)DM_ - mu * mu;
  float rs = rsqrtf(var + 1e-5f);
  Y[(size_t)row * DM_ + t]       = f2bf((v0 - mu) * rs * g[t]       + b[t]);
  Y[(size_t)row * DM_ + t + 256] = f2bf((v1 - mu) * rs * g[t + 256] + b[t + 256]);
}

// ---------------------------------------------------------------------------
// Depthwise causal conv (DC=4 taps) + bias + silu.  Vectorized: 8 channels
// per thread.  Input is the conv-scratch [M][DI] (xc-half of in-proj).
// ---------------------------------------------------------------------------
template <int REV>
__global__ __launch_bounds__(256)
void conv_k(const short* __restrict__ xcin, const float* __restrict__ w,
            const float* __restrict__ cb, short* __restrict__ xcout)
{
  int idx = blockIdx.x * 256 + threadIdx.x;   // over B*S*DI/8
  int ig = (idx & 127) << 3;                  // channel group base
  int bs = idx >> 7;                          // b*S + t
  int tt0 = bs & (S_ - 1);
  int b = bs >> 9;
  const short* u = xcin + (size_t)(b * S_) * DI_ + ig;  // row stride DI
  float4 wv[8];
  #pragma unroll
  for (int n = 0; n < 8; n++) wv[n] = *(const float4*)(w + (ig + n) * DC_);
  float acc[8];
  {
    float4 c0 = *(const float4*)(cb + ig);
    float4 c1 = *(const float4*)(cb + ig + 4);
    acc[0] = c0.x; acc[1] = c0.y; acc[2] = c0.z; acc[3] = c0.w;
    acc[4] = c1.x; acc[5] = c1.y; acc[6] = c1.z; acc[7] = c1.w;
  }
  #pragma unroll
  for (int k = 0; k < DC_; k++) {
    int tt = REV ? (tt0 + (DC_ - 1) - k) : (tt0 - (DC_ - 1) + k);
    if (tt >= 0 && tt < S_) {
      bf16x8 uv = *(const bf16x8*)(u + (size_t)tt * DI_);
      #pragma unroll
      for (int n = 0; n < 8; n++) {
        float wk = (k == 0) ? wv[n].x : (k == 1) ? wv[n].y
                 : (k == 2) ? wv[n].z : wv[n].w;
        acc[n] += wk * bf2f(uv[n]);
      }
    }
  }
  union { short sh[8]; bf16x8 v; } r;
  #pragma unroll
  for (int n = 0; n < 8; n++) {
    float sig = 1.f / (1.f + __expf(-acc[n]));
    r.sh[n] = f2bf(acc[n] * sig);
  }
  *(bf16x8*)(xcout + ((size_t)bs << 10) + ig) = r.v;
}

// ---------------------------------------------------------------------------
// Chunked selective scan — BOTH DIRECTIONS FUSED per dispatch (round 8).
// Per-thread structure is round-4-exact (4-way state split, __expf, CS=32)
// — that config measured 42.7 us @64% occ; the exp2f variant regressed to
// 51 us (libm exp2f carries denormal fixups; __expf is the native path).
// dir = top bit of gid; REV becomes runtime stride selection (uniform).
// Grid (256,16) = 4096 blocks = 8 blocks/CU.
// y is written IN PLACE over dt for both dirs (wave-local exact-index
// aliasing, validated rounds 4-7 for dir1).
// ---------------------------------------------------------------------------
__global__ __launch_bounds__(256)
void scan_p1(const unsigned short* __restrict__ dt16, const short* __restrict__ xc,
             const short* __restrict__ xdbl, const float* __restrict__ A_log,
             unsigned short* __restrict__ part_h, unsigned short* __restrict__ part_A)
{
  const int gid = blockIdx.x * 256 + threadIdx.x;   // over 2*B*DI*4
  const int q = gid & 3;
  const int i = (gid >> 2) & (DI_ - 1);
  const int b = (gid >> 12) & (B_ - 1);
  const int dir = gid >> 15;
  const int c = blockIdx.y;
  float Ai[4];
  const float* al = A_log + (size_t)dir * DI_ * DS_ + i * DS_ + q * 4;
  #pragma unroll
  for (int n = 0; n < 4; n++) Ai[n] = -__expf(al[n]);

  const int ti0 = dir ? (S_ - 1 - c * CS_) : (c * CS_);
  const size_t dof = (size_t)dir * M_ * DI_;
  const unsigned short* pdt = dt16 + dof + ((size_t)b * S_ + ti0) * DI_ + i;
  const short* pu = xc + dof + ((size_t)b * S_ + ti0) * DI_ + i;
  const short* pbc = xdbl + (size_t)dir * M_ * 64 +
                     (((size_t)b * S_ + ti0) << 6) + DTR_ + q * 4;
  const int sstep = dir ? -DI_ : DI_;
  const int sbc = dir ? -64 : 64;

  float h[4];
  #pragma unroll
  for (int n = 0; n < 4; n++) h[n] = 0.f;
  float dsum = 0.f;

  #pragma unroll 4
  for (int sl = 0; sl < CS_; sl++) {
    float dtv = h2f(*pdt);
    float u = bf2f(*pu);
    bf16x4 vB = *(const bf16x4*)pbc;
    float du = dtv * u;
    dsum += dtv;
    #pragma unroll
    for (int n = 0; n < 4; n++) {
      float dA = __expf(dtv * Ai[n]);
      h[n] = dA * h[n] + du * bf2f(vB[n]);
    }
    pdt += sstep; pu += sstep; pbc += sbc;
  }
  union { unsigned short s[4]; int2 v; } uh, ua;
  #pragma unroll
  for (int n = 0; n < 4; n++) {
    uh.s[n] = f2h(h[n]);
    ua.s[n] = f2h(__expf(Ai[n] * dsum));   // exact: prod exp(dt*A)=exp(A*sum dt)
  }
  const size_t ix = ((((size_t)c * 2 * B_ + dir * B_ + b) * DI_ + i) << 4) + (q << 2);
  *(int2*)(part_h + ix) = uh.v;
  *(int2*)(part_A + ix) = ua.v;
}

__global__ __launch_bounds__(256)
void scan_p2(unsigned short* __restrict__ part_h,
             const unsigned short* __restrict__ part_A)
{
  const size_t gid = (size_t)blockIdx.x * 256 + threadIdx.x;   // 2*B*DI*DS
  const size_t stride = (size_t)2 * B_ * DI_ * DS_;
  float hin = 0.f;
  #pragma unroll
  for (int c = 0; c < CH_; c++) {
    size_t ix = (size_t)c * stride + gid;
    float hh = h2f(part_h[ix]);
    float pA = h2f(part_A[ix]);
    part_h[ix] = f2h(hin);            // becomes chunk c's incoming state
    hin = hh + pA * hin;
  }
}

// y overwrites dt16 in place (element-exact same indices) — no __restrict__.
__global__ __launch_bounds__(256)
void scan_p3(unsigned short* dt16, const short* __restrict__ xc,
             const short* __restrict__ xdbl, const short* __restrict__ zb,
             const float* __restrict__ A_log, const float* __restrict__ Dp,
             const unsigned short* __restrict__ part_h)
{
  const int gid = blockIdx.x * 256 + threadIdx.x;   // over 2*B*DI*4
  const int q = gid & 3;
  const int i = (gid >> 2) & (DI_ - 1);
  const int b = (gid >> 12) & (B_ - 1);
  const int dir = gid >> 15;
  const int c = blockIdx.y;
  float Ai[4];
  const float* al = A_log + (size_t)dir * DI_ * DS_ + i * DS_ + q * 4;
  #pragma unroll
  for (int n = 0; n < 4; n++) Ai[n] = -__expf(al[n]);
  const float Di = Dp[(size_t)dir * DI_ + i];

  float h[4];
  {
    const size_t ix = ((((size_t)c * 2 * B_ + dir * B_ + b) * DI_ + i) << 4) + (q << 2);
    union { unsigned short s[4]; int2 v; } uh;
    uh.v = *(const int2*)(part_h + ix);
    #pragma unroll
    for (int n = 0; n < 4; n++) h[n] = h2f(uh.s[n]);
  }

  const int ti0 = dir ? (S_ - 1 - c * CS_) : (c * CS_);
  const size_t dof = (size_t)dir * M_ * DI_;
  unsigned short* pdt = dt16 + dof + ((size_t)b * S_ + ti0) * DI_ + i;
  const short* pu = xc + dof + ((size_t)b * S_ + ti0) * DI_ + i;
  const short* pbc = xdbl + (size_t)dir * M_ * 64 +
                     (((size_t)b * S_ + ti0) << 6) + DTR_ + q * 4;
  const short* pz = zb + dof + ((size_t)b * S_ + ti0) * DI_ + i;
  const int sstep = dir ? -DI_ : DI_;
  const int sbc = dir ? -64 : 64;

  #pragma unroll 4
  for (int sl = 0; sl < CS_; sl++) {
    float dtv = h2f(*pdt);
    float u = bf2f(*pu);
    bf16x4 vB = *(const bf16x4*)pbc;
    bf16x4 vC = *(const bf16x4*)(pbc + DS_);
    float zv = bf2f(*pz);
    float du = dtv * u;
    float yp = 0.f;
    #pragma unroll
    for (int n = 0; n < 4; n++) {
      float dA = __expf(dtv * Ai[n]);
      h[n] = dA * h[n] + du * bf2f(vB[n]);
      yp += h[n] * bf2f(vC[n]);
    }
    yp += __shfl_xor(yp, 1);
    yp += __shfl_xor(yp, 2);            // quad-wide sum over all 16 states
    float sil = zv / (1.f + __expf(-zv));
    float yv = (yp + u * Di) * sil;
    if (q == 0) *(short*)pdt = f2bf(yv);   // in-place y over dt (post-read)
    pdt += sstep; pu += sstep; pbc += sbc; pz += sstep;
  }
}

// ---------------------------------------------------------------------------
// bf16 MFMA GEMM: C[M,N] = A[M,K] * W[N,K]^T, fp32 accum.  global_load_lds
// DMA staging (zero staging registers), source-swizzled, 3 LDS buffers,
// counted vmcnt.  khalf: concat-K source switch.  mhalf: block-uniform
// M-half weight/bias switch (fused two-direction GEMMs).
// ---------------------------------------------------------------------------
enum { EPI_F32_BIAS, EPI_BF16, EPI_F16_SOFTPLUS, EPI_HALF_BF16, EPI_GELU,
       EPI_PROJ, EPI_INPROJ };

template <int EPI, int BM, int BN, int BK>
__global__ __launch_bounds__(256)
void gemm_k(const short* __restrict__ A0, const short* __restrict__ A1,
            const short* __restrict__ W0, const short* __restrict__ W1,
            int khalf, int mhalf, int N, int K, int lda, int ldw,
            float* __restrict__ Cf, short* __restrict__ Cb, int ldc,
            const float* __restrict__ bias,
            const float* __restrict__ xlast, const float* __restrict__ stdev,
            const float* __restrict__ means)
{
  constexpr int MT = BM / 32;
  constexpr int NT = BN / 32;
  constexpr int KS = BK / 32;
  constexpr int CHK = BK / 8;
  constexpr int MSK = CHK - 1;
  constexpr int NA = (BM * CHK) / 256;
  constexpr int NW = (BN * CHK) / 256;
  constexpr int VC = NA + NW;
  __shared__ __align__(16) short As[3][BM * BK];
  __shared__ __align__(16) short Ws[3][BN * BK];
  const int tid = threadIdx.x;
  const int m0 = blockIdx.x * BM;
  const int n0 = blockIdx.y * BN;
  const int wave = tid >> 6, lane = tid & 63;
  const int wm = (wave & 1) * (BM / 2), wn = (wave >> 1) * (BN / 2);
  const int quad = lane >> 4, l16 = lane & 15;

  const short* W0m = (m0 < mhalf) ? W0 : W1;   // block-uniform M-half switch

  f32x4 acc[MT][NT] = {};

  size_t aoff[NA];
  #pragma unroll
  for (int j = 0; j < NA; j++) {
    int id = j * 256 + tid;
    int r = id / CHK, qp = id % CHK;
    aoff[j] = (size_t)(m0 + r) * lda + ((qp ^ (r & MSK)) << 3);
  }
  size_t woff[NW];
  #pragma unroll
  for (int j = 0; j < NW; j++) {
    int id = j * 256 + tid;
    int r = id / CHK, qp = id % CHK;
    int wr = n0 + r; if (wr > N - 1) wr = N - 1;
    woff[j] = (size_t)wr * ldw + ((qp ^ (r & MSK)) << 3);
  }
  const int lbase = wave * 512;

  const int KB = K / BK;

  auto stage = [&](int slab, int bi) {
    const int k0 = slab * BK;
    const short* Ab = (k0 < khalf) ? A0 + k0 : A1 + (k0 - khalf);
    const short* Wb = (k0 < khalf) ? W0m + k0 : W1 + (k0 - khalf);
    #pragma unroll
    for (int j = 0; j < NA; j++)
      gload16(Ab + aoff[j], &As[bi][j * 2048 + lbase]);
    #pragma unroll
    for (int j = 0; j < NW; j++)
      gload16(Wb + woff[j], &Ws[bi][j * 2048 + lbase]);
  };

  stage(0, 0);
  if (KB > 1) stage(1, 1);
  __builtin_amdgcn_sched_barrier(0);
  if (KB > 1) asm volatile("s_waitcnt vmcnt(%0)" :: "n"(VC) : "memory");
  else        asm volatile("s_waitcnt vmcnt(0)" ::: "memory");
  __builtin_amdgcn_s_barrier();
  __builtin_amdgcn_sched_barrier(0);

  int cur = 0, nxt = 2;
  for (int kb = 0; kb < KB; kb++) {
    if (kb + 2 < KB) {
      stage(kb + 2, nxt);
      __builtin_amdgcn_sched_barrier(0);
    }
    bf16x8 af[MT][KS], bfr[NT][KS];
    #pragma unroll
    for (int mt = 0; mt < MT; mt++)
      #pragma unroll
      for (int st = 0; st < KS; st++)
        af[mt][st] = *(const bf16x8*)(&As[cur][0] + (wm + mt * 16 + l16) * BK +
                                      (((st * 4 + quad) ^ (l16 & MSK)) << 3));
    #pragma unroll
    for (int nt = 0; nt < NT; nt++)
      #pragma unroll
      for (int st = 0; st < KS; st++)
        bfr[nt][st] = *(const bf16x8*)(&Ws[cur][0] + (wn + nt * 16 + l16) * BK +
                                       (((st * 4 + quad) ^ (l16 & MSK)) << 3));
    #pragma unroll
    for (int st = 0; st < KS; st++)
      #pragma unroll
      for (int mt = 0; mt < MT; mt++)
        #pragma unroll
        for (int nt = 0; nt < NT; nt++)
          acc[mt][nt] = __builtin_amdgcn_mfma_f32_16x16x32_bf16(
              af[mt][st], bfr[nt][st], acc[mt][nt], 0, 0, 0);
    if (kb + 1 < KB) {
      __builtin_amdgcn_sched_barrier(0);
      if (kb + 2 < KB) asm volatile("s_waitcnt vmcnt(%0)" :: "n"(VC) : "memory");
      else             asm volatile("s_waitcnt vmcnt(0)" ::: "memory");
      __builtin_amdgcn_s_barrier();
      __builtin_amdgcn_sched_barrier(0);
      cur = (cur == 2) ? 0 : cur + 1;
      nxt = (nxt == 2) ? 0 : nxt + 1;
    }
  }

  const int boff = (m0 < mhalf) ? 0 : N;   // M-half bias switch (contiguous)

  #pragma unroll
  for (int mt = 0; mt < MT; mt++) {
    #pragma unroll
    for (int nt = 0; nt < NT; nt++) {
      int n = n0 + wn + nt * 16 + l16;
      if (n >= N) continue;
      #pragma unroll
      for (int r = 0; r < 4; r++) {
        int m = m0 + wm + mt * 16 + quad * 4 + r;
        float v = acc[mt][nt][r];
        if constexpr (EPI == EPI_F32_BIAS) {
          Cf[(size_t)m * ldc + n] = v + bias[n];
        } else if constexpr (EPI == EPI_BF16) {
          Cb[(size_t)m * ldc + n] = f2bf(v);
        } else if constexpr (EPI == EPI_F16_SOFTPLUS) {
          float tt = v + bias[n + boff];
          float sp = (tt > 20.f) ? tt : log1pf(__expf(tt));
          ((unsigned short*)Cb)[(size_t)m * ldc + n] = f2h(sp);
        } else if constexpr (EPI == EPI_HALF_BF16) {
          Cb[(size_t)m * ldc + n] = f2bf(0.5f * v);
        } else if constexpr (EPI == EPI_GELU) {
          float tt = v + bias[n];
          Cb[(size_t)m * ldc + n] = f2bf(0.5f * tt * (1.f + erff(tt * 0.70710678118f)));
        } else if constexpr (EPI == EPI_PROJ) {
          int bb = m >> 9, d = m & 511;
          float tt = v + bias[n] + xlast[m];
          tt = tt * stdev[m] + means[m];
          Cf[((size_t)bb * PL_ + n) * DV_ + d] = tt;
        } else if constexpr (EPI == EPI_INPROJ) {
          // n<1024 -> conv scratch [M][DI]; n>=1024 -> z buffer (Cf cast)
          if (n < DI_) Cb[(size_t)m * ldc + n] = f2bf(v);
          else ((short*)Cf)[(size_t)m * DI_ + (n - DI_)] = f2bf(v);
        }
      }
    }
  }
}

// ---------------------------------------------------------------------------
extern "C" void kernel_launch(void* const* d_in, const int* in_sizes, int n_in,
                              void* d_out, int out_size, void* d_ws, size_t ws_size,
                              hipStream_t stream)
{
  (void)in_sizes; (void)n_in; (void)out_size; (void)ws_size;
  const float* x        = (const float*)d_in[0];
  const float* emb_w    = (const float*)d_in[1];
  const float* emb_b    = (const float*)d_in[2];
  const float* ln_g     = (const float*)d_in[3];
  const float* ln_b     = (const float*)d_in[4];
  const float* m_in_w   = (const float*)d_in[5];
  const float* m_conv_w = (const float*)d_in[6];
  const float* m_conv_b = (const float*)d_in[7];
  const float* m_xp_w   = (const float*)d_in[8];
  const float* m_dt_w   = (const float*)d_in[9];
  const float* m_dt_b   = (const float*)d_in[10];
  const float* m_A_log  = (const float*)d_in[11];
  const float* m_D      = (const float*)d_in[12];
  const float* m_out_w  = (const float*)d_in[13];
  const float* ffn_ln_g = (const float*)d_in[14];
  const float* ffn_ln_b = (const float*)d_in[15];
  const float* ffn_w1   = (const float*)d_in[16];
  const float* ffn_b1   = (const float*)d_in[17];
  const float* ffn_w2   = (const float*)d_in[18];
  const float* ffn_b2   = (const float*)d_in[19];
  const float* enc_g    = (const float*)d_in[20];
  const float* enc_b    = (const float*)d_in[21];
  const float* proj_w   = (const float*)d_in[22];
  const float* proj_b   = (const float*)d_in[23];
  float* out = (float*)d_out;

  char* ws = (char*)d_ws;
  const size_t MB = 1024 * 1024;
  // Lifetime-verified layout (high-water 112 MB):
  //  0-8   h (fp32 residual)
  //  8-12  hn (bf16 LN out)          } part_A aliases 8-16 (p1..p2 window)
  // 12-16  ftmp/vtmp (bf16)          }
  // 16-24  conv scratch [M][DI]      } part_h aliases 16-24 (p1..p3 window)
  // 24-40  zbuf [2][M][DI]; also xnT (pre-layers) and ffn1-out [M][2048]
  // 40-56  xc [2][M][DI]
  // 56-72  dtb [2][M][DI] fp16; y written in place by scan_p3
  // 72-73  xdbl [2M][64]
  // 73-..  stats (64 KB)
  // 80-112 bf16 weight pool
  float* h      = (float*)(ws + 0);
  short* hn     = (short*)(ws + 8 * MB);
  short* ftmp   = (short*)(ws + 12 * MB);
  short* vtmp   = ftmp;
  short* scratch= (short*)(ws + 16 * MB);
  short* zbuf   = (short*)(ws + 24 * MB);
  short* xnT    = zbuf;
  short* f1out  = zbuf;
  short* xc     = (short*)(ws + 40 * MB);
  unsigned short* dtb = (unsigned short*)(ws + 56 * MB);
  short* xdbl   = (short*)(ws + 72 * MB);
  float* stats  = (float*)(ws + 73 * MB);
  unsigned short* part_A = (unsigned short*)(ws + 8 * MB);
  unsigned short* part_h = (unsigned short*)(ws + 16 * MB);
  float* means = stats, *stdevp = stats + 4096, *rstd = stats + 8192, *xlast = stats + 12288;

  short* emb_wb = (short*)(ws + 80 * MB);
  short* in_wb  = emb_wb + 262144;      // 6 x 2048x512
  short* xp_wb  = in_wb  + 6291456;     // 6 x 64x1024
  short* dt_wb  = xp_wb  + 393216;      // 6 x 1024x32
  short* out_wb = dt_wb  + 196608;      // 6 x 512x1024
  short* w1b    = out_wb + 3145728;     // 3 x 2048x512
  short* w2b    = w1b    + 3145728;     // 3 x 512x2048
  short* projb  = w2b    + 3145728;     // 96x512

  dim3 blk(256);
  const int NOSPLIT = 1 << 30;

  wcvt_k<<<dim3(16240), blk, 0, stream>>>(
      emb_w, m_in_w, m_xp_w, m_dt_w, m_out_w, ffn_w1, ffn_w2, proj_w,
      emb_wb, in_wb, xp_wb, dt_wb, out_wb, w1b, w2b, projb);

  stats_k<<<dim3(2, B_), blk, 0, stream>>>(x, means, stdevp, rstd, xlast);
  tnorm_k<<<dim3(8, 8, B_), blk, 0, stream>>>(x, means, rstd, xnT);
  // emb: M=4096, N=512, K=512
  gemm_k<EPI_F32_BIAS, 64, 32, 64><<<dim3(64, 16), blk, 0, stream>>>(
      xnT, xnT, emb_wb, emb_wb, NOSPLIT, NOSPLIT, DM_, L_, L_, L_,
      h, nullptr, DM_, emb_b, nullptr, nullptr, nullptr);

  for (int il = 0; il < EL_; il++) {
    if (il == 0)
      ln_k<0><<<dim3(4096), blk, 0, stream>>>(h, nullptr, nullptr, ln_g, ln_b, hn);
    else
      ln_k<2><<<dim3(4096), blk, 0, stream>>>(h, ftmp, ffn_b2 + (il - 1) * DM_,
          ln_g + il * DM_, ln_b + il * DM_, hn);
    for (int dir = 0; dir < 2; dir++) {
      int mod = 2 * il + dir;
      // in-proj dir: N=2048, K=512; split epilogue -> scratch + zbuf[dir]
      gemm_k<EPI_INPROJ, 64, 128, 32><<<dim3(64, 16), blk, 0, stream>>>(
          hn, hn, in_wb + (size_t)mod * 2 * DI_ * DM_,
          in_wb + (size_t)mod * 2 * DI_ * DM_, NOSPLIT, NOSPLIT,
          2 * DI_, DM_, DM_, DM_,
          (float*)(zbuf + (size_t)dir * M_ * DI_), scratch, DI_,
          nullptr, nullptr, nullptr, nullptr);
      if (dir == 0)
        conv_k<0><<<dim3(2048), blk, 0, stream>>>(
            scratch, m_conv_w + (size_t)mod * DI_ * DC_,
            m_conv_b + (size_t)mod * DI_, xc + (size_t)dir * M_ * DI_);
      else
        conv_k<1><<<dim3(2048), blk, 0, stream>>>(
            scratch, m_conv_w + (size_t)mod * DI_ * DC_,
            m_conv_b + (size_t)mod * DI_, xc + (size_t)dir * M_ * DI_);
    }
    // xdbl (both dirs): M=8192, N=64, K=1024; W switches at m=4096
    gemm_k<EPI_BF16, 32, 32, 64><<<dim3(256, 2), blk, 0, stream>>>(
        xc, xc, xp_wb + (size_t)(2 * il) * 64 * DI_,
        xp_wb + (size_t)(2 * il + 1) * 64 * DI_, NOSPLIT, M_,
        64, DI_, DI_, DI_,
        nullptr, xdbl, 64, nullptr, nullptr, nullptr, nullptr);
    // dt (both dirs): M=8192, N=1024, K=32; W+bias switch at m=4096
    gemm_k<EPI_F16_SOFTPLUS, 64, 64, 32><<<dim3(128, 16), blk, 0, stream>>>(
        xdbl, xdbl, dt_wb + (size_t)(2 * il) * DI_ * DTR_,
        dt_wb + (size_t)(2 * il + 1) * DI_ * DTR_, NOSPLIT, M_,
        DI_, DTR_, 64, DTR_,
        nullptr, (short*)dtb, DI_, m_dt_b + (size_t)(2 * il) * DI_,
        nullptr, nullptr, nullptr);
    // fused scans: grid (256,16) = 4096 blocks, both dirs
    const float* Alog = m_A_log + (size_t)(2 * il) * DI_ * DS_;
    const float* Dp = m_D + (size_t)(2 * il) * DI_;
    scan_p1<<<dim3(256, CH_), blk, 0, stream>>>(dtb, xc, xdbl, Alog, part_h, part_A);
    scan_p2<<<dim3(1024), blk, 0, stream>>>(part_h, part_A);
    scan_p3<<<dim3(256, CH_), blk, 0, stream>>>(dtb, xc, xdbl, zbuf, Alog, Dp, part_h);
    // out-proj (concat-K over y0|y1, both in place over dtb)
    gemm_k<EPI_HALF_BF16, 64, 32, 64><<<dim3(64, 16), blk, 0, stream>>>(
        (const short*)dtb, (const short*)(dtb + (size_t)M_ * DI_),
        out_wb + (size_t)(2 * il) * DM_ * DI_,
        out_wb + (size_t)(2 * il + 1) * DM_ * DI_,
        DI_, NOSPLIT, DM_, 2 * DI_, DI_, DI_,
        nullptr, vtmp, DM_, nullptr, nullptr, nullptr, nullptr);
    ln_k<1><<<dim3(4096), blk, 0, stream>>>(h, vtmp, nullptr,
        ffn_ln_g + il * DM_, ffn_ln_b + il * DM_, hn);
    // ffn1: N=2048, K=512 -> f1out [M][2048]
    gemm_k<EPI_GELU, 64, 128, 32><<<dim3(64, 16), blk, 0, stream>>>(
        hn, hn, w1b + (size_t)il * 4 * DM_ * DM_,
        w1b + (size_t)il * 4 * DM_ * DM_, NOSPLIT, NOSPLIT,
        4 * DM_, DM_, DM_, DM_,
        nullptr, f1out, 4 * DM_, ffn_b1 + (size_t)il * 4 * DM_,
        nullptr, nullptr, nullptr);
    // ffn2: N=512, K=2048 -> ftmp
    gemm_k<EPI_BF16, 64, 32, 64><<<dim3(64, 16), blk, 0, stream>>>(
        f1out, f1out, w2b + (size_t)il * DM_ * 4 * DM_,
        w2b + (size_t)il * DM_ * 4 * DM_, NOSPLIT, NOSPLIT,
        DM_, 4 * DM_, 4 * DM_, 4 * DM_,
        nullptr, ftmp, DM_, nullptr, nullptr, nullptr, nullptr);
  }

  ln_k<2><<<dim3(4096), blk, 0, stream>>>(h, ftmp, ffn_b2 + 2 * DM_,
      enc_g, enc_b, hn);
  // proj: N=96, K=512
  gemm_k<EPI_PROJ, 64, 32, 64><<<dim3(64, 3), blk, 0, stream>>>(
      hn, hn, projb, projb, NOSPLIT, NOSPLIT, PL_, DM_, DM_, DM_,
      out, nullptr, 0, proj_b, xlast, stdevp, means);
}

// Round 9
// 1079.587 us; speedup vs baseline: 1.1606x; 1.0103x over previous
//
#include <hip/hip_runtime.h>
#include <hip/hip_bf16.h>
#include <math.h>

#define B_ 8
#define L_ 512
#define DV_ 512
#define DM_ 512
#define PL_ 96
#define EL_ 3
#define DS_ 16
#define DC_ 4
#define DI_ 1024
#define DTR_ 32
#define S_ 512
#define M_ 4096        // B*S
#define CH_ 16         // scan chunks
#define CS_ 32         // steps per chunk
#define LOG2E_ 1.44269504088896f

typedef float f32x4 __attribute__((ext_vector_type(4)));
typedef short bf16x8 __attribute__((ext_vector_type(8)));
typedef short bf16x4 __attribute__((ext_vector_type(4)));

__device__ __forceinline__ float bf2f(short s) {
  unsigned u = ((unsigned)(unsigned short)s) << 16;
  return __builtin_bit_cast(float, u);
}
__device__ __forceinline__ short f2bf(float f) {
  unsigned u = __builtin_bit_cast(unsigned, f);
  u = u + 0x7FFFu + ((u >> 16) & 1u);   // RNE
  return (short)(u >> 16);
}
__device__ __forceinline__ float h2f(unsigned short u) {
  _Float16 h = __builtin_bit_cast(_Float16, u);
  return (float)h;
}
__device__ __forceinline__ unsigned short f2h(float f) {
  _Float16 h = (_Float16)f;
  return __builtin_bit_cast(unsigned short, h);
}

// Native v_exp_f32 (exp2).  NOT libm exp2f (denormal fixups — round-7
// regression).  Fallback keeps correctness if the builtin is missing.
__device__ __forceinline__ float exp2n(float x) {
#if __has_builtin(__builtin_amdgcn_exp2f)
  return __builtin_amdgcn_exp2f(x);
#else
  return __expf(x * 0.69314718055994531f);
#endif
}

// global -> LDS DMA, 16B per lane.  LDS dest is wave-uniform base + lane*16.
__device__ __forceinline__ void gload16(const short* g, short* l) {
  __builtin_amdgcn_global_load_lds(
      (const __attribute__((address_space(1))) void*)g,
      (__attribute__((address_space(3))) void*)l, 16, 0, 0);
}

// ---------------------------------------------------------------------------
// One-shot fp32 -> bf16 conversion of ALL GEMM weights into workspace.
// ---------------------------------------------------------------------------
#define WC0 65536                 // emb_w      512*512
#define WC1 (WC0 + 1572864)       // m_in_w     6*2048*512
#define WC2 (WC1 + 98304)         // m_xp_w     6*64*1024
#define WC3 (WC2 + 49152)         // m_dt_w     6*1024*32
#define WC4 (WC3 + 786432)        // m_out_w    6*512*1024
#define WC5 (WC4 + 786432)        // ffn_w1     3*2048*512
#define WC6 (WC5 + 786432)        // ffn_w2     3*512*2048
#define WC7 (WC6 + 12288)        // proj_w     96*512
// WC7 = 4157440 float4s; grid = 16240 * 256 exactly.

__global__ __launch_bounds__(256)
void wcvt_k(const float* __restrict__ e, const float* __restrict__ iw,
            const float* __restrict__ xp, const float* __restrict__ dtw,
            const float* __restrict__ ow, const float* __restrict__ w1,
            const float* __restrict__ w2, const float* __restrict__ pw,
            short* __restrict__ de, short* __restrict__ di,
            short* __restrict__ dxp, short* __restrict__ ddt,
            short* __restrict__ dow, short* __restrict__ dw1,
            short* __restrict__ dw2, short* __restrict__ dpw)
{
  int idx = blockIdx.x * 256 + threadIdx.x;
  const float* s; short* d; int off;
  if (idx < WC0)      { s = e;   d = de;  off = idx; }
  else if (idx < WC1) { s = iw;  d = di;  off = idx - WC0; }
  else if (idx < WC2) { s = xp;  d = dxp; off = idx - WC1; }
  else if (idx < WC3) { s = dtw; d = ddt; off = idx - WC2; }
  else if (idx < WC4) { s = ow;  d = dow; off = idx - WC3; }
  else if (idx < WC5) { s = w1;  d = dw1; off = idx - WC4; }
  else if (idx < WC6) { s = w2;  d = dw2; off = idx - WC5; }
  else                { s = pw;  d = dpw; off = idx - WC6; }
  float4 v = ((const float4*)s)[off];
  union { short sh[4]; int2 p; } r;
  r.sh[0] = f2bf(v.x); r.sh[1] = f2bf(v.y);
  r.sh[2] = f2bf(v.z); r.sh[3] = f2bf(v.w);
  ((int2*)d)[off] = r.p;
}

// ---------------------------------------------------------------------------
// Instance-norm statistics over the time axis (L) of x (B,L,DV) fp32.
// ---------------------------------------------------------------------------
__global__ __launch_bounds__(256)
void stats_k(const float* __restrict__ x, float* __restrict__ means,
             float* __restrict__ stdev, float* __restrict__ rstd,
             float* __restrict__ xlast)
{
  int d = blockIdx.x * 256 + threadIdx.x;       // 0..511
  int b = blockIdx.y;
  const float* xp = x + (size_t)b * L_ * DV_ + d;
  float s = 0.f, ss = 0.f;
  for (int l = 0; l < L_; l++) {
    float v = xp[(size_t)l * DV_];
    s += v; ss += v * v;
  }
  float mu = s / (float)L_;
  float var = ss / (float)L_ - mu * mu;
  float sd = sqrtf(var + 1e-5f);
  float rs = 1.f / sd;
  int idx = b * DV_ + d;
  means[idx] = mu; stdev[idx] = sd; rstd[idx] = rs;
  xlast[idx] = (xp[(size_t)(L_ - 1) * DV_] - mu) * rs;
}

// ---------------------------------------------------------------------------
// Normalize + transpose: xnT[b,d,l] = (x[b,l,d]-mu[b,d])*rstd[b,d]  (bf16)
// ---------------------------------------------------------------------------
__global__ __launch_bounds__(256)
void tnorm_k(const float* __restrict__ x, const float* __restrict__ means,
             const float* __restrict__ rstd, short* __restrict__ xnT)
{
  __shared__ float tile[64][65];
  const int t = threadIdx.x;
  const int j = t & 63;
  const int i0 = t >> 6;                 // 0..3
  const int bz = blockIdx.z;
  const int l0 = blockIdx.y << 6;
  const int d0 = blockIdx.x << 6;
  const float* xp = x + ((size_t)bz * L_ + l0) * DV_ + d0;
  #pragma unroll
  for (int i = i0; i < 64; i += 4) tile[i][j] = xp[(size_t)i * DV_ + j];
  __syncthreads();
  short* op = xnT + ((size_t)bz * DV_ + d0) * L_ + l0;
  const int sb = bz * DV_ + d0;
  #pragma unroll
  for (int i = i0; i < 64; i += 4) {
    float mu = means[sb + i];
    float rs = rstd[sb + i];
    op[(size_t)i * L_ + j] = f2bf((tile[j][i] - mu) * rs);
  }
}

// ---------------------------------------------------------------------------
// Fused LayerNorm: optionally h += add (+ abias) in place, then LN -> bf16.
// ---------------------------------------------------------------------------
template <int ADD>
__global__ __launch_bounds__(256)
void ln_k(float* __restrict__ X, const short* __restrict__ add,
          const float* __restrict__ abias,
          const float* __restrict__ g, const float* __restrict__ b,
          short* __restrict__ Y)
{
  int row = blockIdx.x;
  float* x = X + (size_t)row * DM_;
  int t = threadIdx.x;
  float v0 = x[t], v1 = x[t + 256];
  if constexpr (ADD >= 1) {
    v0 += bf2f(add[(size_t)row * DM_ + t]);
    v1 += bf2f(add[(size_t)row * DM_ + t + 256]);
    if constexpr (ADD == 2) { v0 += abias[t]; v1 += abias[t + 256]; }
    x[t] = v0; x[t + 256] = v1;
  }
  float s = v0 + v1, ss = v0 * v0 + v1 * v1;
  #pragma unroll
  for (int o = 1; o < 64; o <<= 1) { s += __shfl_xor(s, o); ss += __shfl_xor(ss, o); }
  __shared__ float sb[8];
  int wave = t >> 6, lane = t & 63;
  if (lane == 0) { sb[wave] = s; sb[4 + wave] = ss; }
  __syncthreads();
  s = sb[0] + sb[1] + sb[2] + sb[3];
  ss = sb[4] + sb[5] + sb[6] + sb[7];
  float mu = s / (float)DM_;
  float var = ss / (float)DM_ - mu * mu;
  float rs = rsqrtf(var + 1e-5f);
  Y[(size_t)row * DM_ + t]       = f2bf((v0 - mu) * rs * g[t]       + b[t]);
  Y[(size_t)row * DM_ + t + 256] = f2bf((v1 - mu) * rs * g[t + 256] + b[t + 256]);
}

// ---------------------------------------------------------------------------
// Depthwise causal conv (DC=4 taps) + bias + silu.  Vectorized, 8 ch/thread.
// FORWARD ONLY: dir-1 input arrives already time-reversed (v-domain), so
// reversed-causal conv == plain causal conv on the reversed input.
// ---------------------------------------------------------------------------
__global__ __launch_bounds__(256)
void conv_k(const short* __restrict__ xcin, const float* __restrict__ w,
            const float* __restrict__ cb, short* __restrict__ xcout)
{
  int idx = blockIdx.x * 256 + threadIdx.x;   // over B*S*DI/8
  int ig = (idx & 127) << 3;                  // channel group base
  int bs = idx >> 7;                          // b*S + tau
  int tt0 = bs & (S_ - 1);
  int b = bs >> 9;
  const short* u = xcin + (size_t)(b * S_) * DI_ + ig;  // row stride DI
  float4 wv[8];
  #pragma unroll
  for (int n = 0; n < 8; n++) wv[n] = *(const float4*)(w + (ig + n) * DC_);
  float acc[8];
  {
    float4 c0 = *(const float4*)(cb + ig);
    float4 c1 = *(const float4*)(cb + ig + 4);
    acc[0] = c0.x; acc[1] = c0.y; acc[2] = c0.z; acc[3] = c0.w;
    acc[4] = c1.x; acc[5] = c1.y; acc[6] = c1.z; acc[7] = c1.w;
  }
  #pragma unroll
  for (int k = 0; k < DC_; k++) {
    int tt = tt0 - (DC_ - 1) + k;
    if (tt >= 0) {
      bf16x8 uv = *(const bf16x8*)(u + (size_t)tt * DI_);
      #pragma unroll
      for (int n = 0; n < 8; n++) {
        float wk = (k == 0) ? wv[n].x : (k == 1) ? wv[n].y
                 : (k == 2) ? wv[n].z : wv[n].w;
        acc[n] += wk * bf2f(uv[n]);
      }
    }
  }
  union { short sh[8]; bf16x8 v; } r;
  #pragma unroll
  for (int n = 0; n < 8; n++) {
    float sig = 1.f / (1.f + __expf(-acc[n]));
    r.sh[n] = f2bf(acc[n] * sig);
  }
  *(bf16x8*)(xcout + ((size_t)bs << 10) + ig) = r.v;
}

// ---------------------------------------------------------------------------
// Chunked selective scan, both dirs fused, FORWARD-ONLY traversal (round 9):
// dir-1 data lives in reversed time (v-domain), so strides are the
// compile-time constants +DI/+64 — indexed loads off one base let the
// compiler fold immediate offsets (round-8 runtime strides cost ~8 VALU
// ptr-arith per step).  dA = exp2(dt*(A*log2e)) via NATIVE v_exp.
// ---------------------------------------------------------------------------
__global__ __launch_bounds__(256)
void scan_p1(const unsigned short* __restrict__ dt16, const short* __restrict__ xc,
             const short* __restrict__ xdbl, const float* __restrict__ A_log,
             unsigned short* __restrict__ part_h, unsigned short* __restrict__ part_A)
{
  const int gid = blockIdx.x * 256 + threadIdx.x;   // over 2*B*DI*4
  const int q = gid & 3;
  const int i = (gid >> 2) & (DI_ - 1);
  const int b = (gid >> 12) & (B_ - 1);
  const int dir = gid >> 15;
  const int c = blockIdx.y;
  float Ai2[4];
  const float* al = A_log + (size_t)dir * DI_ * DS_ + i * DS_ + q * 4;
  #pragma unroll
  for (int n = 0; n < 4; n++) Ai2[n] = -__expf(al[n]) * LOG2E_;

  const size_t base = (size_t)dir * M_ * DI_ + ((size_t)b * S_ + c * CS_) * DI_ + i;
  const unsigned short* pdt = dt16 + base;
  const short* pu = xc + base;
  const short* pbc = xdbl + (size_t)dir * M_ * 64 +
                     (((size_t)b * S_ + c * CS_) << 6) + DTR_ + q * 4;

  float h[4];
  #pragma unroll
  for (int n = 0; n < 4; n++) h[n] = 0.f;
  float dsum = 0.f;

  for (int s0 = 0; s0 < CS_; s0 += 4) {
    #pragma unroll
    for (int k = 0; k < 4; k++) {
      float dtv = h2f(pdt[(size_t)k * DI_]);
      float u = bf2f(pu[(size_t)k * DI_]);
      bf16x4 vB = *(const bf16x4*)(pbc + k * 64);
      float du = dtv * u;
      dsum += dtv;
      #pragma unroll
      for (int n = 0; n < 4; n++) {
        float dA = exp2n(dtv * Ai2[n]);
        h[n] = dA * h[n] + du * bf2f(vB[n]);
      }
    }
    pdt += 4 * DI_; pu += 4 * DI_; pbc += 4 * 64;
  }
  union { unsigned short s[4]; int2 v; } uh, ua;
  #pragma unroll
  for (int n = 0; n < 4; n++) {
    uh.s[n] = f2h(h[n]);
    ua.s[n] = f2h(exp2n(Ai2[n] * dsum));   // exact: prod exp(dt*A)=exp(A*sum dt)
  }
  const size_t ix = ((((size_t)c * 2 * B_ + dir * B_ + b) * DI_ + i) << 4) + (q << 2);
  *(int2*)(part_h + ix) = uh.v;
  *(int2*)(part_A + ix) = ua.v;
}

__global__ __launch_bounds__(256)
void scan_p2(unsigned short* __restrict__ part_h,
             const unsigned short* __restrict__ part_A)
{
  const size_t gid = (size_t)blockIdx.x * 256 + threadIdx.x;   // 2*B*DI*DS
  const size_t stride = (size_t)2 * B_ * DI_ * DS_;
  float hin = 0.f;
  #pragma unroll
  for (int c = 0; c < CH_; c++) {
    size_t ix = (size_t)c * stride + gid;
    float hh = h2f(part_h[ix]);
    float pA = h2f(part_A[ix]);
    part_h[ix] = f2h(hin);            // becomes chunk c's incoming state
    hin = hh + pA * hin;
  }
}

// y overwrites dt16 in place (element-exact same indices) — no __restrict__.
__global__ __launch_bounds__(256)
void scan_p3(unsigned short* dt16, const short* __restrict__ xc,
             const short* __restrict__ xdbl, const short* __restrict__ zb,
             const float* __restrict__ A_log, const float* __restrict__ Dp,
             const unsigned short* __restrict__ part_h)
{
  const int gid = blockIdx.x * 256 + threadIdx.x;   // over 2*B*DI*4
  const int q = gid & 3;
  const int i = (gid >> 2) & (DI_ - 1);
  const int b = (gid >> 12) & (B_ - 1);
  const int dir = gid >> 15;
  const int c = blockIdx.y;
  float Ai2[4];
  const float* al = A_log + (size_t)dir * DI_ * DS_ + i * DS_ + q * 4;
  #pragma unroll
  for (int n = 0; n < 4; n++) Ai2[n] = -__expf(al[n]) * LOG2E_;
  const float Di = Dp[(size_t)dir * DI_ + i];

  float h[4];
  {
    const size_t ix = ((((size_t)c * 2 * B_ + dir * B_ + b) * DI_ + i) << 4) + (q << 2);
    union { unsigned short s[4]; int2 v; } uh;
    uh.v = *(const int2*)(part_h + ix);
    #pragma unroll
    for (int n = 0; n < 4; n++) h[n] = h2f(uh.s[n]);
  }

  const size_t base = (size_t)dir * M_ * DI_ + ((size_t)b * S_ + c * CS_) * DI_ + i;
  unsigned short* pdt = dt16 + base;
  const short* pu = xc + base;
  const short* pz = zb + base;
  const short* pbc = xdbl + (size_t)dir * M_ * 64 +
                     (((size_t)b * S_ + c * CS_) << 6) + DTR_ + q * 4;

  for (int s0 = 0; s0 < CS_; s0 += 4) {
    #pragma unroll
    for (int k = 0; k < 4; k++) {
      float dtv = h2f(pdt[(size_t)k * DI_]);
      float u = bf2f(pu[(size_t)k * DI_]);
      bf16x4 vB = *(const bf16x4*)(pbc + k * 64);
      bf16x4 vC = *(const bf16x4*)(pbc + k * 64 + DS_);
      float zv = bf2f(pz[(size_t)k * DI_]);
      float du = dtv * u;
      float yp = 0.f;
      #pragma unroll
      for (int n = 0; n < 4; n++) {
        float dA = exp2n(dtv * Ai2[n]);
        h[n] = dA * h[n] + du * bf2f(vB[n]);
        yp += h[n] * bf2f(vC[n]);
      }
      yp += __shfl_xor(yp, 1);
      yp += __shfl_xor(yp, 2);          // quad-wide sum over all 16 states
      float sil = zv / (1.f + __expf(-zv));
      float yv = (yp + u * Di) * sil;
      if (q == 0) *(short*)(pdt + (size_t)k * DI_) = f2bf(yv);  // y over dt
    }
    pdt += 4 * DI_; pu += 4 * DI_; pz += 4 * DI_; pbc += 4 * 64;
  }
}

// ---------------------------------------------------------------------------
// bf16 MFMA GEMM: C[M,N] = A[M,K] * W[N,K]^T, fp32 accum.  global_load_lds
// DMA staging, source-swizzled, 3 LDS buffers, counted vmcnt.
// khalf: concat-K source switch.  mhalf: block-uniform M-half W switch.
// REVA: reverse time (row^511) when reading A1 slabs (y-backward operand
// stored in v-domain).
// ---------------------------------------------------------------------------
enum { EPI_F32_BIAS, EPI_BF16, EPI_F16_SOFTPLUS, EPI_HALF_BF16, EPI_GELU,
       EPI_PROJ, EPI_INPROJ, EPI_INPROJ_REV };

template <int EPI, int BM, int BN, int BK, int REVA = 0>
__global__ __launch_bounds__(256)
void gemm_k(const short* __restrict__ A0, const short* __restrict__ A1,
            const short* __restrict__ W0, const short* __restrict__ W1,
            int khalf, int mhalf, int N, int K, int lda, int ldw,
            float* __restrict__ Cf, short* __restrict__ Cb, int ldc,
            const float* __restrict__ bias,
            const float* __restrict__ xlast, const float* __restrict__ stdev,
            const float* __restrict__ means)
{
  constexpr int MT = BM / 32;
  constexpr int NT = BN / 32;
  constexpr int KS = BK / 32;
  constexpr int CHK = BK / 8;
  constexpr int MSK = CHK - 1;
  constexpr int NA = (BM * CHK) / 256;
  constexpr int NW = (BN * CHK) / 256;
  constexpr int VC = NA + NW;
  __shared__ __align__(16) short As[3][BM * BK];
  __shared__ __align__(16) short Ws[3][BN * BK];
  const int tid = threadIdx.x;
  const int m0 = blockIdx.x * BM;
  const int n0 = blockIdx.y * BN;
  const int wave = tid >> 6, lane = tid & 63;
  const int wm = (wave & 1) * (BM / 2), wn = (wave >> 1) * (BN / 2);
  const int quad = lane >> 4, l16 = lane & 15;

  const short* W0m = (m0 < mhalf) ? W0 : W1;   // block-uniform M-half switch

  f32x4 acc[MT][NT] = {};

  size_t aoff[NA], aoffR[REVA ? NA : 1];
  #pragma unroll
  for (int j = 0; j < NA; j++) {
    int id = j * 256 + tid;
    int r = id / CHK, qp = id % CHK;
    aoff[j] = (size_t)(m0 + r) * lda + ((qp ^ (r & MSK)) << 3);
    if constexpr (REVA)
      aoffR[j] = (size_t)((m0 + r) ^ (S_ - 1)) * lda + ((qp ^ (r & MSK)) << 3);
  }
  size_t woff[NW];
  #pragma unroll
  for (int j = 0; j < NW; j++) {
    int id = j * 256 + tid;
    int r = id / CHK, qp = id % CHK;
    int wr = n0 + r; if (wr > N - 1) wr = N - 1;
    woff[j] = (size_t)wr * ldw + ((qp ^ (r & MSK)) << 3);
  }
  const int lbase = wave * 512;

  const int KB = K / BK;

  auto stage = [&](int slab, int bi) {
    const int k0 = slab * BK;
    const short* Ab = (k0 < khalf) ? A0 + k0 : A1 + (k0 - khalf);
    const short* Wb = (k0 < khalf) ? W0m + k0 : W1 + (k0 - khalf);
    const size_t* ao = (REVA && k0 >= khalf) ? aoffR : aoff;
    #pragma unroll
    for (int j = 0; j < NA; j++)
      gload16(Ab + ao[j], &As[bi][j * 2048 + lbase]);
    #pragma unroll
    for (int j = 0; j < NW; j++)
      gload16(Wb + woff[j], &Ws[bi][j * 2048 + lbase]);
  };

  stage(0, 0);
  if (KB > 1) stage(1, 1);
  __builtin_amdgcn_sched_barrier(0);
  if (KB > 1) asm volatile("s_waitcnt vmcnt(%0)" :: "n"(VC) : "memory");
  else        asm volatile("s_waitcnt vmcnt(0)" ::: "memory");
  __builtin_amdgcn_s_barrier();
  __builtin_amdgcn_sched_barrier(0);

  int cur = 0, nxt = 2;
  for (int kb = 0; kb < KB; kb++) {
    if (kb + 2 < KB) {
      stage(kb + 2, nxt);
      __builtin_amdgcn_sched_barrier(0);
    }
    bf16x8 af[MT][KS], bfr[NT][KS];
    #pragma unroll
    for (int mt = 0; mt < MT; mt++)
      #pragma unroll
      for (int st = 0; st < KS; st++)
        af[mt][st] = *(const bf16x8*)(&As[cur][0] + (wm + mt * 16 + l16) * BK +
                                      (((st * 4 + quad) ^ (l16 & MSK)) << 3));
    #pragma unroll
    for (int nt = 0; nt < NT; nt++)
      #pragma unroll
      for (int st = 0; st < KS; st++)
        bfr[nt][st] = *(const bf16x8*)(&Ws[cur][0] + (wn + nt * 16 + l16) * BK +
                                       (((st * 4 + quad) ^ (l16 & MSK)) << 3));
    #pragma unroll
    for (int st = 0; st < KS; st++)
      #pragma unroll
      for (int mt = 0; mt < MT; mt++)
        #pragma unroll
        for (int nt = 0; nt < NT; nt++)
          acc[mt][nt] = __builtin_amdgcn_mfma_f32_16x16x32_bf16(
              af[mt][st], bfr[nt][st], acc[mt][nt], 0, 0, 0);
    if (kb + 1 < KB) {
      __builtin_amdgcn_sched_barrier(0);
      if (kb + 2 < KB) asm volatile("s_waitcnt vmcnt(%0)" :: "n"(VC) : "memory");
      else             asm volatile("s_waitcnt vmcnt(0)" ::: "memory");
      __builtin_amdgcn_s_barrier();
      __builtin_amdgcn_sched_barrier(0);
      cur = (cur == 2) ? 0 : cur + 1;
      nxt = (nxt == 2) ? 0 : nxt + 1;
    }
  }

  const int boff = (m0 < mhalf) ? 0 : N;   // M-half bias switch (contiguous)

  #pragma unroll
  for (int mt = 0; mt < MT; mt++) {
    #pragma unroll
    for (int nt = 0; nt < NT; nt++) {
      int n = n0 + wn + nt * 16 + l16;
      if (n >= N) continue;
      #pragma unroll
      for (int r = 0; r < 4; r++) {
        int m = m0 + wm + mt * 16 + quad * 4 + r;
        float v = acc[mt][nt][r];
        if constexpr (EPI == EPI_F32_BIAS) {
          Cf[(size_t)m * ldc + n] = v + bias[n];
        } else if constexpr (EPI == EPI_BF16) {
          Cb[(size_t)m * ldc + n] = f2bf(v);
        } else if constexpr (EPI == EPI_F16_SOFTPLUS) {
          float tt = v + bias[n + boff];
          float sp = (tt > 20.f) ? tt : log1pf(__expf(tt));
          ((unsigned short*)Cb)[(size_t)m * ldc + n] = f2h(sp);
        } else if constexpr (EPI == EPI_HALF_BF16) {
          Cb[(size_t)m * ldc + n] = f2bf(0.5f * v);
        } else if constexpr (EPI == EPI_GELU) {
          float tt = v + bias[n];
          Cb[(size_t)m * ldc + n] = f2bf(0.5f * tt * (1.f + erff(tt * 0.70710678118f)));
        } else if constexpr (EPI == EPI_PROJ) {
          int bb = m >> 9, d = m & 511;
          float tt = v + bias[n] + xlast[m];
          tt = tt * stdev[m] + means[m];
          Cf[((size_t)bb * PL_ + n) * DV_ + d] = tt;
        } else if constexpr (EPI == EPI_INPROJ) {
          if (n < DI_) Cb[(size_t)m * ldc + n] = f2bf(v);
          else ((short*)Cf)[(size_t)m * DI_ + (n - DI_)] = f2bf(v);
        } else if constexpr (EPI == EPI_INPROJ_REV) {
          // store in reversed time-domain: row m -> m^511 (t -> S-1-t)
          int mr = m ^ (S_ - 1);
          if (n < DI_) Cb[(size_t)mr * ldc + n] = f2bf(v);
          else ((short*)Cf)[(size_t)mr * DI_ + (n - DI_)] = f2bf(v);
        }
      }
    }
  }
}

// ---------------------------------------------------------------------------
extern "C" void kernel_launch(void* const* d_in, const int* in_sizes, int n_in,
                              void* d_out, int out_size, void* d_ws, size_t ws_size,
                              hipStream_t stream)
{
  (void)in_sizes; (void)n_in; (void)out_size; (void)ws_size;
  const float* x        = (const float*)d_in[0];
  const float* emb_w    = (const float*)d_in[1];
  const float* emb_b    = (const float*)d_in[2];
  const float* ln_g     = (const float*)d_in[3];
  const float* ln_b     = (const float*)d_in[4];
  const float* m_in_w   = (const float*)d_in[5];
  const float* m_conv_w = (const float*)d_in[6];
  const float* m_conv_b = (const float*)d_in[7];
  const float* m_xp_w   = (const float*)d_in[8];
  const float* m_dt_w   = (const float*)d_in[9];
  const float* m_dt_b   = (const float*)d_in[10];
  const float* m_A_log  = (const float*)d_in[11];
  const float* m_D      = (const float*)d_in[12];
  const float* m_out_w  = (const float*)d_in[13];
  const float* ffn_ln_g = (const float*)d_in[14];
  const float* ffn_ln_b = (const float*)d_in[15];
  const float* ffn_w1   = (const float*)d_in[16];
  const float* ffn_b1   = (const float*)d_in[17];
  const float* ffn_w2   = (const float*)d_in[18];
  const float* ffn_b2   = (const float*)d_in[19];
  const float* enc_g    = (const float*)d_in[20];
  const float* enc_b    = (const float*)d_in[21];
  const float* proj_w   = (const float*)d_in[22];
  const float* proj_b   = (const float*)d_in[23];
  float* out = (float*)d_out;

  char* ws = (char*)d_ws;
  const size_t MB = 1024 * 1024;
  // Layout (high-water 112 MB), identical to round 8:
  //  0-8   h | 8-12 hn | 12-16 ftmp/vtmp | 16-24 conv scratch (+part_h alias)
  //  8-16  part_A alias | 24-40 zbuf/xnT/f1out | 40-56 xc | 56-72 dtb (y in
  //  place) | 72-73 xdbl | 73 stats | 80-112 bf16 weight pool
  float* h      = (float*)(ws + 0);
  short* hn     = (short*)(ws + 8 * MB);
  short* ftmp   = (short*)(ws + 12 * MB);
  short* vtmp   = ftmp;
  short* scratch= (short*)(ws + 16 * MB);
  short* zbuf   = (short*)(ws + 24 * MB);
  short* xnT    = zbuf;
  short* f1out  = zbuf;
  short* xc     = (short*)(ws + 40 * MB);
  unsigned short* dtb = (unsigned short*)(ws + 56 * MB);
  short* xdbl   = (short*)(ws + 72 * MB);
  float* stats  = (float*)(ws + 73 * MB);
  unsigned short* part_A = (unsigned short*)(ws + 8 * MB);
  unsigned short* part_h = (unsigned short*)(ws + 16 * MB);
  float* means = stats, *stdevp = stats + 4096, *rstd = stats + 8192, *xlast = stats + 12288;

  short* emb_wb = (short*)(ws + 80 * MB);
  short* in_wb  = emb_wb + 262144;      // 6 x 2048x512
  short* xp_wb  = in_wb  + 6291456;     // 6 x 64x1024
  short* dt_wb  = xp_wb  + 393216;      // 6 x 1024x32
  short* out_wb = dt_wb  + 196608;      // 6 x 512x1024
  short* w1b    = out_wb + 3145728;     // 3 x 2048x512
  short* w2b    = w1b    + 3145728;     // 3 x 512x2048
  short* projb  = w2b    + 3145728;     // 96x512

  dim3 blk(256);
  const int NOSPLIT = 1 << 30;

  wcvt_k<<<dim3(16240), blk, 0, stream>>>(
      emb_w, m_in_w, m_xp_w, m_dt_w, m_out_w, ffn_w1, ffn_w2, proj_w,
      emb_wb, in_wb, xp_wb, dt_wb, out_wb, w1b, w2b, projb);

  stats_k<<<dim3(2, B_), blk, 0, stream>>>(x, means, stdevp, rstd, xlast);
  tnorm_k<<<dim3(8, 8, B_), blk, 0, stream>>>(x, means, rstd, xnT);
  // emb: M=4096, N=512, K=512
  gemm_k<EPI_F32_BIAS, 64, 32, 64><<<dim3(64, 16), blk, 0, stream>>>(
      xnT, xnT, emb_wb, emb_wb, NOSPLIT, NOSPLIT, DM_, L_, L_, L_,
      h, nullptr, DM_, emb_b, nullptr, nullptr, nullptr);

  for (int il = 0; il < EL_; il++) {
    if (il == 0)
      ln_k<0><<<dim3(4096), blk, 0, stream>>>(h, nullptr, nullptr, ln_g, ln_b, hn);
    else
      ln_k<2><<<dim3(4096), blk, 0, stream>>>(h, ftmp, ffn_b2 + (il - 1) * DM_,
          ln_g + il * DM_, ln_b + il * DM_, hn);
    for (int dir = 0; dir < 2; dir++) {
      int mod = 2 * il + dir;
      // in-proj dir: N=2048, K=512; dir1 stores BOTH outputs time-reversed
      if (dir == 0)
        gemm_k<EPI_INPROJ, 64, 128, 32><<<dim3(64, 16), blk, 0, stream>>>(
            hn, hn, in_wb + (size_t)mod * 2 * DI_ * DM_,
            in_wb + (size_t)mod * 2 * DI_ * DM_, NOSPLIT, NOSPLIT,
            2 * DI_, DM_, DM_, DM_,
            (float*)(zbuf + (size_t)dir * M_ * DI_), scratch, DI_,
            nullptr, nullptr, nullptr, nullptr);
      else
        gemm_k<EPI_INPROJ_REV, 64, 128, 32><<<dim3(64, 16), blk, 0, stream>>>(
            hn, hn, in_wb + (size_t)mod * 2 * DI_ * DM_,
            in_wb + (size_t)mod * 2 * DI_ * DM_, NOSPLIT, NOSPLIT,
            2 * DI_, DM_, DM_, DM_,
            (float*)(zbuf + (size_t)dir * M_ * DI_), scratch, DI_,
            nullptr, nullptr, nullptr, nullptr);
      // conv: plain forward for both dirs (dir1 input already reversed)
      conv_k<<<dim3(2048), blk, 0, stream>>>(
          scratch, m_conv_w + (size_t)mod * DI_ * DC_,
          m_conv_b + (size_t)mod * DI_, xc + (size_t)dir * M_ * DI_);
    }
    // xdbl (both dirs): M=8192, N=64, K=1024; W switches at m=4096
    gemm_k<EPI_BF16, 32, 32, 64><<<dim3(256, 2), blk, 0, stream>>>(
        xc, xc, xp_wb + (size_t)(2 * il) * 64 * DI_,
        xp_wb + (size_t)(2 * il + 1) * 64 * DI_, NOSPLIT, M_,
        64, DI_, DI_, DI_,
        nullptr, xdbl, 64, nullptr, nullptr, nullptr, nullptr);
    // dt (both dirs): M=8192, N=1024, K=32; W+bias switch at m=4096
    gemm_k<EPI_F16_SOFTPLUS, 64, 64, 32><<<dim3(128, 16), blk, 0, stream>>>(
        xdbl, xdbl, dt_wb + (size_t)(2 * il) * DI_ * DTR_,
        dt_wb + (size_t)(2 * il + 1) * DI_ * DTR_, NOSPLIT, M_,
        DI_, DTR_, 64, DTR_,
        nullptr, (short*)dtb, DI_, m_dt_b + (size_t)(2 * il) * DI_,
        nullptr, nullptr, nullptr);
    // fused scans, forward-only: grid (256,16) = 4096 blocks
    const float* Alog = m_A_log + (size_t)(2 * il) * DI_ * DS_;
    const float* Dp = m_D + (size_t)(2 * il) * DI_;
    scan_p1<<<dim3(256, CH_), blk, 0, stream>>>(dtb, xc, xdbl, Alog, part_h, part_A);
    scan_p2<<<dim3(1024), blk, 0, stream>>>(part_h, part_A);
    scan_p3<<<dim3(256, CH_), blk, 0, stream>>>(dtb, xc, xdbl, zbuf, Alog, Dp, part_h);
    // out-proj (concat-K over y0|y1); A1 rows un-reversed via REVA=1
    gemm_k<EPI_HALF_BF16, 64, 32, 64, 1><<<dim3(64, 16), blk, 0, stream>>>(
        (const short*)dtb, (const short*)(dtb + (size_t)M_ * DI_),
        out_wb + (size_t)(2 * il) * DM_ * DI_,
        out_wb + (size_t)(2 * il + 1) * DM_ * DI_,
        DI_, NOSPLIT, DM_, 2 * DI_, DI_, DI_,
        nullptr, vtmp, DM_, nullptr, nullptr, nullptr, nullptr);
    ln_k<1><<<dim3(4096), blk, 0, stream>>>(h, vtmp, nullptr,
        ffn_ln_g + il * DM_, ffn_ln_b + il * DM_, hn);
    // ffn1: N=2048, K=512 -> f1out [M][2048]
    gemm_k<EPI_GELU, 64, 128, 32><<<dim3(64, 16), blk, 0, stream>>>(
        hn, hn, w1b + (size_t)il * 4 * DM_ * DM_,
        w1b + (size_t)il * 4 * DM_ * DM_, NOSPLIT, NOSPLIT,
        4 * DM_, DM_, DM_, DM_,
        nullptr, f1out, 4 * DM_, ffn_b1 + (size_t)il * 4 * DM_,
        nullptr, nullptr, nullptr);
    // ffn2: N=512, K=2048 -> ftmp
    gemm_k<EPI_BF16, 64, 32, 64><<<dim3(64, 16), blk, 0, stream>>>(
        f1out, f1out, w2b + (size_t)il * DM_ * 4 * DM_,
        w2b + (size_t)il * DM_ * 4 * DM_, NOSPLIT, NOSPLIT,
        DM_, 4 * DM_, 4 * DM_, 4 * DM_,
        nullptr, ftmp, DM_, nullptr, nullptr, nullptr, nullptr);
  }

  ln_k<2><<<dim3(4096), blk, 0, stream>>>(h, ftmp, ffn_b2 + 2 * DM_,
      enc_g, enc_b, hn);
  // proj: N=96, K=512
  gemm_k<EPI_PROJ, 64, 32, 64><<<dim3(64, 3), blk, 0, stream>>>(
      hn, hn, projb, projb, NOSPLIT, NOSPLIT, PL_, DM_, DM_, DM_,
      out, nullptr, 0, proj_b, xlast, stdevp, means);
}

// Round 10
// 1069.220 us; speedup vs baseline: 1.1718x; 1.0097x over previous
//
#include <hip/hip_runtime.h>
#include <hip/hip_bf16.h>
#include <math.h>

#define B_ 8
#define L_ 512
#define DV_ 512
#define DM_ 512
#define PL_ 96
#define EL_ 3
#define DS_ 16
#define DC_ 4
#define DI_ 1024
#define DTR_ 32
#define S_ 512
#define M_ 4096        // B*S
#define CH_ 16         // scan chunks
#define CS_ 32         // steps per chunk
#define LOG2E_ 1.44269504088896f

typedef float f32x4 __attribute__((ext_vector_type(4)));
typedef short bf16x8 __attribute__((ext_vector_type(8)));
typedef short bf16x4 __attribute__((ext_vector_type(4)));

__device__ __forceinline__ float bf2f(short s) {
  unsigned u = ((unsigned)(unsigned short)s) << 16;
  return __builtin_bit_cast(float, u);
}
__device__ __forceinline__ short f2bf(float f) {
  unsigned u = __builtin_bit_cast(unsigned, f);
  u = u + 0x7FFFu + ((u >> 16) & 1u);   // RNE
  return (short)(u >> 16);
}
__device__ __forceinline__ float h2f(unsigned short u) {
  _Float16 h = __builtin_bit_cast(_Float16, u);
  return (float)h;
}
__device__ __forceinline__ unsigned short f2h(float f) {
  _Float16 h = (_Float16)f;
  return __builtin_bit_cast(unsigned short, h);
}

// Native v_exp_f32 (exp2).  NOT libm exp2f (denormal fixups — round-7
// regression).  Fallback keeps correctness if the builtin is missing.
__device__ __forceinline__ float exp2n(float x) {
#if __has_builtin(__builtin_amdgcn_exp2f)
  return __builtin_amdgcn_exp2f(x);
#else
  return __expf(x * 0.69314718055994531f);
#endif
}

// global -> LDS DMA, 16B per lane.  LDS dest is wave-uniform base + lane*16.
__device__ __forceinline__ void gload16(const short* g, short* l) {
  __builtin_amdgcn_global_load_lds(
      (const __attribute__((address_space(1))) void*)g,
      (__attribute__((address_space(3))) void*)l, 16, 0, 0);
}

// ---------------------------------------------------------------------------
// One-shot fp32 -> bf16 conversion of ALL GEMM weights into workspace.
// ---------------------------------------------------------------------------
#define WC0 65536                 // emb_w      512*512
#define WC1 (WC0 + 1572864)       // m_in_w     6*2048*512
#define WC2 (WC1 + 98304)         // m_xp_w     6*64*1024
#define WC3 (WC2 + 49152)         // m_dt_w     6*1024*32
#define WC4 (WC3 + 786432)        // m_out_w    6*512*1024
#define WC5 (WC4 + 786432)        // ffn_w1     3*2048*512
#define WC6 (WC5 + 786432)        // ffn_w2     3*512*2048
#define WC7 (WC6 + 12288)        // proj_w     96*512
// WC7 = 4157440 float4s; grid = 16240 * 256 exactly.

__global__ __launch_bounds__(256)
void wcvt_k(const float* __restrict__ e, const float* __restrict__ iw,
            const float* __restrict__ xp, const float* __restrict__ dtw,
            const float* __restrict__ ow, const float* __restrict__ w1,
            const float* __restrict__ w2, const float* __restrict__ pw,
            short* __restrict__ de, short* __restrict__ di,
            short* __restrict__ dxp, short* __restrict__ ddt,
            short* __restrict__ dow, short* __restrict__ dw1,
            short* __restrict__ dw2, short* __restrict__ dpw)
{
  int idx = blockIdx.x * 256 + threadIdx.x;
  const float* s; short* d; int off;
  if (idx < WC0)      { s = e;   d = de;  off = idx; }
  else if (idx < WC1) { s = iw;  d = di;  off = idx - WC0; }
  else if (idx < WC2) { s = xp;  d = dxp; off = idx - WC1; }
  else if (idx < WC3) { s = dtw; d = ddt; off = idx - WC2; }
  else if (idx < WC4) { s = ow;  d = dow; off = idx - WC3; }
  else if (idx < WC5) { s = w1;  d = dw1; off = idx - WC4; }
  else if (idx < WC6) { s = w2;  d = dw2; off = idx - WC5; }
  else                { s = pw;  d = dpw; off = idx - WC6; }
  float4 v = ((const float4*)s)[off];
  union { short sh[4]; int2 p; } r;
  r.sh[0] = f2bf(v.x); r.sh[1] = f2bf(v.y);
  r.sh[2] = f2bf(v.z); r.sh[3] = f2bf(v.w);
  ((int2*)d)[off] = r.p;
}

// ---------------------------------------------------------------------------
// Instance-norm statistics over the time axis (L) of x (B,L,DV) fp32.
// ---------------------------------------------------------------------------
__global__ __launch_bounds__(256)
void stats_k(const float* __restrict__ x, float* __restrict__ means,
             float* __restrict__ stdev, float* __restrict__ rstd,
             float* __restrict__ xlast)
{
  int d = blockIdx.x * 256 + threadIdx.x;       // 0..511
  int b = blockIdx.y;
  const float* xp = x + (size_t)b * L_ * DV_ + d;
  float s = 0.f, ss = 0.f;
  for (int l = 0; l < L_; l++) {
    float v = xp[(size_t)l * DV_];
    s += v; ss += v * v;
  }
  float mu = s / (float)L_;
  float var = ss / (float)L_ - mu * mu;
  float sd = sqrtf(var + 1e-5f);
  float rs = 1.f / sd;
  int idx = b * DV_ + d;
  means[idx] = mu; stdev[idx] = sd; rstd[idx] = rs;
  xlast[idx] = (xp[(size_t)(L_ - 1) * DV_] - mu) * rs;
}

// ---------------------------------------------------------------------------
// Normalize + transpose: xnT[b,d,l] = (x[b,l,d]-mu[b,d])*rstd[b,d]  (bf16)
// ---------------------------------------------------------------------------
__global__ __launch_bounds__(256)
void tnorm_k(const float* __restrict__ x, const float* __restrict__ means,
             const float* __restrict__ rstd, short* __restrict__ xnT)
{
  __shared__ float tile[64][65];
  const int t = threadIdx.x;
  const int j = t & 63;
  const int i0 = t >> 6;                 // 0..3
  const int bz = blockIdx.z;
  const int l0 = blockIdx.y << 6;
  const int d0 = blockIdx.x << 6;
  const float* xp = x + ((size_t)bz * L_ + l0) * DV_ + d0;
  #pragma unroll
  for (int i = i0; i < 64; i += 4) tile[i][j] = xp[(size_t)i * DV_ + j];
  __syncthreads();
  short* op = xnT + ((size_t)bz * DV_ + d0) * L_ + l0;
  const int sb = bz * DV_ + d0;
  #pragma unroll
  for (int i = i0; i < 64; i += 4) {
    float mu = means[sb + i];
    float rs = rstd[sb + i];
    op[(size_t)i * L_ + j] = f2bf((tile[j][i] - mu) * rs);
  }
}

// ---------------------------------------------------------------------------
// Fused LayerNorm: optionally h += add (+ abias) in place, then LN -> bf16.
// ---------------------------------------------------------------------------
template <int ADD>
__global__ __launch_bounds__(256)
void ln_k(float* __restrict__ X, const short* __restrict__ add,
          const float* __restrict__ abias,
          const float* __restrict__ g, const float* __restrict__ b,
          short* __restrict__ Y)
{
  int row = blockIdx.x;
  float* x = X + (size_t)row * DM_;
  int t = threadIdx.x;
  float v0 = x[t], v1 = x[t + 256];
  if constexpr (ADD >= 1) {
    v0 += bf2f(add[(size_t)row * DM_ + t]);
    v1 += bf2f(add[(size_t)row * DM_ + t + 256]);
    if constexpr (ADD == 2) { v0 += abias[t]; v1 += abias[t + 256]; }
    x[t] = v0; x[t + 256] = v1;
  }
  float s = v0 + v1, ss = v0 * v0 + v1 * v1;
  #pragma unroll
  for (int o = 1; o < 64; o <<= 1) { s += __shfl_xor(s, o); ss += __shfl_xor(ss, o); }
  __shared__ float sb[8];
  int wave = t >> 6, lane = t & 63;
  if (lane == 0) { sb[wave] = s; sb[4 + wave] = ss; }
  __syncthreads();
  s = sb[0] + sb[1] + sb[2] + sb[3];
  ss = sb[4] + sb[5] + sb[6] + sb[7];
  float mu = s / (float)DM_;
  float var = ss / (float)DM_ - mu * mu;
  float rs = rsqrtf(var + 1e-5f);
  Y[(size_t)row * DM_ + t]       = f2bf((v0 - mu) * rs * g[t]       + b[t]);
  Y[(size_t)row * DM_ + t + 256] = f2bf((v1 - mu) * rs * g[t + 256] + b[t + 256]);
}

// ---------------------------------------------------------------------------
// Depthwise causal conv (DC=4 taps) + bias + silu.  Vectorized, 8 ch/thread.
// FORWARD ONLY: dir-1 input arrives already time-reversed (v-domain), so
// reversed-causal conv == plain causal conv on the reversed input.
// ---------------------------------------------------------------------------
__global__ __launch_bounds__(256)
void conv_k(const short* __restrict__ xcin, const float* __restrict__ w,
            const float* __restrict__ cb, short* __restrict__ xcout)
{
  int idx = blockIdx.x * 256 + threadIdx.x;   // over B*S*DI/8
  int ig = (idx & 127) << 3;                  // channel group base
  int bs = idx >> 7;                          // b*S + tau
  int tt0 = bs & (S_ - 1);
  int b = bs >> 9;
  const short* u = xcin + (size_t)(b * S_) * DI_ + ig;  // row stride DI
  float4 wv[8];
  #pragma unroll
  for (int n = 0; n < 8; n++) wv[n] = *(const float4*)(w + (ig + n) * DC_);
  float acc[8];
  {
    float4 c0 = *(const float4*)(cb + ig);
    float4 c1 = *(const float4*)(cb + ig + 4);
    acc[0] = c0.x; acc[1] = c0.y; acc[2] = c0.z; acc[3] = c0.w;
    acc[4] = c1.x; acc[5] = c1.y; acc[6] = c1.z; acc[7] = c1.w;
  }
  #pragma unroll
  for (int k = 0; k < DC_; k++) {
    int tt = tt0 - (DC_ - 1) + k;
    if (tt >= 0) {
      bf16x8 uv = *(const bf16x8*)(u + (size_t)tt * DI_);
      #pragma unroll
      for (int n = 0; n < 8; n++) {
        float wk = (k == 0) ? wv[n].x : (k == 1) ? wv[n].y
                 : (k == 2) ? wv[n].z : wv[n].w;
        acc[n] += wk * bf2f(uv[n]);
      }
    }
  }
  union { short sh[8]; bf16x8 v; } r;
  #pragma unroll
  for (int n = 0; n < 8; n++) {
    float sig = 1.f / (1.f + __expf(-acc[n]));
    r.sh[n] = f2bf(acc[n] * sig);
  }
  *(bf16x8*)(xcout + ((size_t)bs << 10) + ig) = r.v;
}

// ---------------------------------------------------------------------------
// Chunked selective scan, both dirs fused, forward-only traversal.
// Round 10: silu(z) is PRE-APPLIED by the in-proj epilogue (zbuf holds
// silu(z) bf16), so p3's per-step silu chain (exp+add+rcp+mul, ~18 cy of
// the ~59-cy step budget, duplicated across the quad) collapses to one
// bf16 load + mul.
// ---------------------------------------------------------------------------
__global__ __launch_bounds__(256)
void scan_p1(const unsigned short* __restrict__ dt16, const short* __restrict__ xc,
             const short* __restrict__ xdbl, const float* __restrict__ A_log,
             unsigned short* __restrict__ part_h, unsigned short* __restrict__ part_A)
{
  const int gid = blockIdx.x * 256 + threadIdx.x;   // over 2*B*DI*4
  const int q = gid & 3;
  const int i = (gid >> 2) & (DI_ - 1);
  const int b = (gid >> 12) & (B_ - 1);
  const int dir = gid >> 15;
  const int c = blockIdx.y;
  float Ai2[4];
  const float* al = A_log + (size_t)dir * DI_ * DS_ + i * DS_ + q * 4;
  #pragma unroll
  for (int n = 0; n < 4; n++) Ai2[n] = -__expf(al[n]) * LOG2E_;

  const size_t base = (size_t)dir * M_ * DI_ + ((size_t)b * S_ + c * CS_) * DI_ + i;
  const unsigned short* pdt = dt16 + base;
  const short* pu = xc + base;
  const short* pbc = xdbl + (size_t)dir * M_ * 64 +
                     (((size_t)b * S_ + c * CS_) << 6) + DTR_ + q * 4;

  float h[4];
  #pragma unroll
  for (int n = 0; n < 4; n++) h[n] = 0.f;
  float dsum = 0.f;

  for (int s0 = 0; s0 < CS_; s0 += 4) {
    #pragma unroll
    for (int k = 0; k < 4; k++) {
      float dtv = h2f(pdt[(size_t)k * DI_]);
      float u = bf2f(pu[(size_t)k * DI_]);
      bf16x4 vB = *(const bf16x4*)(pbc + k * 64);
      float du = dtv * u;
      dsum += dtv;
      #pragma unroll
      for (int n = 0; n < 4; n++) {
        float dA = exp2n(dtv * Ai2[n]);
        h[n] = dA * h[n] + du * bf2f(vB[n]);
      }
    }
    pdt += 4 * DI_; pu += 4 * DI_; pbc += 4 * 64;
  }
  union { unsigned short s[4]; int2 v; } uh, ua;
  #pragma unroll
  for (int n = 0; n < 4; n++) {
    uh.s[n] = f2h(h[n]);
    ua.s[n] = f2h(exp2n(Ai2[n] * dsum));   // exact: prod exp(dt*A)=exp(A*sum dt)
  }
  const size_t ix = ((((size_t)c * 2 * B_ + dir * B_ + b) * DI_ + i) << 4) + (q << 2);
  *(int2*)(part_h + ix) = uh.v;
  *(int2*)(part_A + ix) = ua.v;
}

__global__ __launch_bounds__(256)
void scan_p2(unsigned short* __restrict__ part_h,
             const unsigned short* __restrict__ part_A)
{
  const size_t gid = (size_t)blockIdx.x * 256 + threadIdx.x;   // 2*B*DI*DS
  const size_t stride = (size_t)2 * B_ * DI_ * DS_;
  float hin = 0.f;
  #pragma unroll
  for (int c = 0; c < CH_; c++) {
    size_t ix = (size_t)c * stride + gid;
    float hh = h2f(part_h[ix]);
    float pA = h2f(part_A[ix]);
    part_h[ix] = f2h(hin);            // becomes chunk c's incoming state
    hin = hh + pA * hin;
  }
}

// y overwrites dt16 in place (element-exact same indices) — no __restrict__.
// zb holds PRE-SILU'd z (bf16).
__global__ __launch_bounds__(256)
void scan_p3(unsigned short* dt16, const short* __restrict__ xc,
             const short* __restrict__ xdbl, const short* __restrict__ zb,
             const float* __restrict__ A_log, const float* __restrict__ Dp,
             const unsigned short* __restrict__ part_h)
{
  const int gid = blockIdx.x * 256 + threadIdx.x;   // over 2*B*DI*4
  const int q = gid & 3;
  const int i = (gid >> 2) & (DI_ - 1);
  const int b = (gid >> 12) & (B_ - 1);
  const int dir = gid >> 15;
  const int c = blockIdx.y;
  float Ai2[4];
  const float* al = A_log + (size_t)dir * DI_ * DS_ + i * DS_ + q * 4;
  #pragma unroll
  for (int n = 0; n < 4; n++) Ai2[n] = -__expf(al[n]) * LOG2E_;
  const float Di = Dp[(size_t)dir * DI_ + i];

  float h[4];
  {
    const size_t ix = ((((size_t)c * 2 * B_ + dir * B_ + b) * DI_ + i) << 4) + (q << 2);
    union { unsigned short s[4]; int2 v; } uh;
    uh.v = *(const int2*)(part_h + ix);
    #pragma unroll
    for (int n = 0; n < 4; n++) h[n] = h2f(uh.s[n]);
  }

  const size_t base = (size_t)dir * M_ * DI_ + ((size_t)b * S_ + c * CS_) * DI_ + i;
  unsigned short* pdt = dt16 + base;
  const short* pu = xc + base;
  const short* pz = zb + base;
  const short* pbc = xdbl + (size_t)dir * M_ * 64 +
                     (((size_t)b * S_ + c * CS_) << 6) + DTR_ + q * 4;

  for (int s0 = 0; s0 < CS_; s0 += 4) {
    #pragma unroll
    for (int k = 0; k < 4; k++) {
      float dtv = h2f(pdt[(size_t)k * DI_]);
      float u = bf2f(pu[(size_t)k * DI_]);
      bf16x4 vB = *(const bf16x4*)(pbc + k * 64);
      bf16x4 vC = *(const bf16x4*)(pbc + k * 64 + DS_);
      float sil = bf2f(pz[(size_t)k * DI_]);   // silu pre-applied at in-proj
      float du = dtv * u;
      float yp = 0.f;
      #pragma unroll
      for (int n = 0; n < 4; n++) {
        float dA = exp2n(dtv * Ai2[n]);
        h[n] = dA * h[n] + du * bf2f(vB[n]);
        yp += h[n] * bf2f(vC[n]);
      }
      yp += __shfl_xor(yp, 1);
      yp += __shfl_xor(yp, 2);          // quad-wide sum over all 16 states
      float yv = (yp + u * Di) * sil;
      if (q == 0) *(short*)(pdt + (size_t)k * DI_) = f2bf(yv);  // y over dt
    }
    pdt += 4 * DI_; pu += 4 * DI_; pz += 4 * DI_; pbc += 4 * 64;
  }
}

// ---------------------------------------------------------------------------
// bf16 MFMA GEMM: C[M,N] = A[M,K] * W[N,K]^T, fp32 accum.  global_load_lds
// DMA staging, source-swizzled, 3 LDS buffers, counted vmcnt.
// khalf: concat-K source switch.  mhalf: block-uniform M-half W switch.
// REVA: reverse time (row^511) when reading A1 slabs.
// INPROJ epilogues: z-half is written as silu(z) (scan consumes it directly).
// ---------------------------------------------------------------------------
enum { EPI_F32_BIAS, EPI_BF16, EPI_F16_SOFTPLUS, EPI_HALF_BF16, EPI_GELU,
       EPI_PROJ, EPI_INPROJ, EPI_INPROJ_REV };

template <int EPI, int BM, int BN, int BK, int REVA = 0>
__global__ __launch_bounds__(256)
void gemm_k(const short* __restrict__ A0, const short* __restrict__ A1,
            const short* __restrict__ W0, const short* __restrict__ W1,
            int khalf, int mhalf, int N, int K, int lda, int ldw,
            float* __restrict__ Cf, short* __restrict__ Cb, int ldc,
            const float* __restrict__ bias,
            const float* __restrict__ xlast, const float* __restrict__ stdev,
            const float* __restrict__ means)
{
  constexpr int MT = BM / 32;
  constexpr int NT = BN / 32;
  constexpr int KS = BK / 32;
  constexpr int CHK = BK / 8;
  constexpr int MSK = CHK - 1;
  constexpr int NA = (BM * CHK) / 256;
  constexpr int NW = (BN * CHK) / 256;
  constexpr int VC = NA + NW;
  __shared__ __align__(16) short As[3][BM * BK];
  __shared__ __align__(16) short Ws[3][BN * BK];
  const int tid = threadIdx.x;
  const int m0 = blockIdx.x * BM;
  const int n0 = blockIdx.y * BN;
  const int wave = tid >> 6, lane = tid & 63;
  const int wm = (wave & 1) * (BM / 2), wn = (wave >> 1) * (BN / 2);
  const int quad = lane >> 4, l16 = lane & 15;

  const short* W0m = (m0 < mhalf) ? W0 : W1;   // block-uniform M-half switch

  f32x4 acc[MT][NT] = {};

  size_t aoff[NA], aoffR[REVA ? NA : 1];
  #pragma unroll
  for (int j = 0; j < NA; j++) {
    int id = j * 256 + tid;
    int r = id / CHK, qp = id % CHK;
    aoff[j] = (size_t)(m0 + r) * lda + ((qp ^ (r & MSK)) << 3);
    if constexpr (REVA)
      aoffR[j] = (size_t)((m0 + r) ^ (S_ - 1)) * lda + ((qp ^ (r & MSK)) << 3);
  }
  size_t woff[NW];
  #pragma unroll
  for (int j = 0; j < NW; j++) {
    int id = j * 256 + tid;
    int r = id / CHK, qp = id % CHK;
    int wr = n0 + r; if (wr > N - 1) wr = N - 1;
    woff[j] = (size_t)wr * ldw + ((qp ^ (r & MSK)) << 3);
  }
  const int lbase = wave * 512;

  const int KB = K / BK;

  auto stage = [&](int slab, int bi) {
    const int k0 = slab * BK;
    const short* Ab = (k0 < khalf) ? A0 + k0 : A1 + (k0 - khalf);
    const short* Wb = (k0 < khalf) ? W0m + k0 : W1 + (k0 - khalf);
    const size_t* ao = (REVA && k0 >= khalf) ? aoffR : aoff;
    #pragma unroll
    for (int j = 0; j < NA; j++)
      gload16(Ab + ao[j], &As[bi][j * 2048 + lbase]);
    #pragma unroll
    for (int j = 0; j < NW; j++)
      gload16(Wb + woff[j], &Ws[bi][j * 2048 + lbase]);
  };

  stage(0, 0);
  if (KB > 1) stage(1, 1);
  __builtin_amdgcn_sched_barrier(0);
  if (KB > 1) asm volatile("s_waitcnt vmcnt(%0)" :: "n"(VC) : "memory");
  else        asm volatile("s_waitcnt vmcnt(0)" ::: "memory");
  __builtin_amdgcn_s_barrier();
  __builtin_amdgcn_sched_barrier(0);

  int cur = 0, nxt = 2;
  for (int kb = 0; kb < KB; kb++) {
    if (kb + 2 < KB) {
      stage(kb + 2, nxt);
      __builtin_amdgcn_sched_barrier(0);
    }
    bf16x8 af[MT][KS], bfr[NT][KS];
    #pragma unroll
    for (int mt = 0; mt < MT; mt++)
      #pragma unroll
      for (int st = 0; st < KS; st++)
        af[mt][st] = *(const bf16x8*)(&As[cur][0] + (wm + mt * 16 + l16) * BK +
                                      (((st * 4 + quad) ^ (l16 & MSK)) << 3));
    #pragma unroll
    for (int nt = 0; nt < NT; nt++)
      #pragma unroll
      for (int st = 0; st < KS; st++)
        bfr[nt][st] = *(const bf16x8*)(&Ws[cur][0] + (wn + nt * 16 + l16) * BK +
                                       (((st * 4 + quad) ^ (l16 & MSK)) << 3));
    #pragma unroll
    for (int st = 0; st < KS; st++)
      #pragma unroll
      for (int mt = 0; mt < MT; mt++)
        #pragma unroll
        for (int nt = 0; nt < NT; nt++)
          acc[mt][nt] = __builtin_amdgcn_mfma_f32_16x16x32_bf16(
              af[mt][st], bfr[nt][st], acc[mt][nt], 0, 0, 0);
    if (kb + 1 < KB) {
      __builtin_amdgcn_sched_barrier(0);
      if (kb + 2 < KB) asm volatile("s_waitcnt vmcnt(%0)" :: "n"(VC) : "memory");
      else             asm volatile("s_waitcnt vmcnt(0)" ::: "memory");
      __builtin_amdgcn_s_barrier();
      __builtin_amdgcn_sched_barrier(0);
      cur = (cur == 2) ? 0 : cur + 1;
      nxt = (nxt == 2) ? 0 : nxt + 1;
    }
  }

  const int boff = (m0 < mhalf) ? 0 : N;   // M-half bias switch (contiguous)

  #pragma unroll
  for (int mt = 0; mt < MT; mt++) {
    #pragma unroll
    for (int nt = 0; nt < NT; nt++) {
      int n = n0 + wn + nt * 16 + l16;
      if (n >= N) continue;
      #pragma unroll
      for (int r = 0; r < 4; r++) {
        int m = m0 + wm + mt * 16 + quad * 4 + r;
        float v = acc[mt][nt][r];
        if constexpr (EPI == EPI_F32_BIAS) {
          Cf[(size_t)m * ldc + n] = v + bias[n];
        } else if constexpr (EPI == EPI_BF16) {
          Cb[(size_t)m * ldc + n] = f2bf(v);
        } else if constexpr (EPI == EPI_F16_SOFTPLUS) {
          float tt = v + bias[n + boff];
          float sp = (tt > 20.f) ? tt : log1pf(__expf(tt));
          ((unsigned short*)Cb)[(size_t)m * ldc + n] = f2h(sp);
        } else if constexpr (EPI == EPI_HALF_BF16) {
          Cb[(size_t)m * ldc + n] = f2bf(0.5f * v);
        } else if constexpr (EPI == EPI_GELU) {
          float tt = v + bias[n];
          Cb[(size_t)m * ldc + n] = f2bf(0.5f * tt * (1.f + erff(tt * 0.70710678118f)));
        } else if constexpr (EPI == EPI_PROJ) {
          int bb = m >> 9, d = m & 511;
          float tt = v + bias[n] + xlast[m];
          tt = tt * stdev[m] + means[m];
          Cf[((size_t)bb * PL_ + n) * DV_ + d] = tt;
        } else if constexpr (EPI == EPI_INPROJ) {
          if (n < DI_) Cb[(size_t)m * ldc + n] = f2bf(v);
          else {
            float sz = v / (1.f + __expf(-v));     // pre-apply silu to z
            ((short*)Cf)[(size_t)m * DI_ + (n - DI_)] = f2bf(sz);
          }
        } else if constexpr (EPI == EPI_INPROJ_REV) {
          // store in reversed time-domain: row m -> m^511 (t -> S-1-t)
          int mr = m ^ (S_ - 1);
          if (n < DI_) Cb[(size_t)mr * ldc + n] = f2bf(v);
          else {
            float sz = v / (1.f + __expf(-v));     // pre-apply silu to z
            ((short*)Cf)[(size_t)mr * DI_ + (n - DI_)] = f2bf(sz);
          }
        }
      }
    }
  }
}

// ---------------------------------------------------------------------------
extern "C" void kernel_launch(void* const* d_in, const int* in_sizes, int n_in,
                              void* d_out, int out_size, void* d_ws, size_t ws_size,
                              hipStream_t stream)
{
  (void)in_sizes; (void)n_in; (void)out_size; (void)ws_size;
  const float* x        = (const float*)d_in[0];
  const float* emb_w    = (const float*)d_in[1];
  const float* emb_b    = (const float*)d_in[2];
  const float* ln_g     = (const float*)d_in[3];
  const float* ln_b     = (const float*)d_in[4];
  const float* m_in_w   = (const float*)d_in[5];
  const float* m_conv_w = (const float*)d_in[6];
  const float* m_conv_b = (const float*)d_in[7];
  const float* m_xp_w   = (const float*)d_in[8];
  const float* m_dt_w   = (const float*)d_in[9];
  const float* m_dt_b   = (const float*)d_in[10];
  const float* m_A_log  = (const float*)d_in[11];
  const float* m_D      = (const float*)d_in[12];
  const float* m_out_w  = (const float*)d_in[13];
  const float* ffn_ln_g = (const float*)d_in[14];
  const float* ffn_ln_b = (const float*)d_in[15];
  const float* ffn_w1   = (const float*)d_in[16];
  const float* ffn_b1   = (const float*)d_in[17];
  const float* ffn_w2   = (const float*)d_in[18];
  const float* ffn_b2   = (const float*)d_in[19];
  const float* enc_g    = (const float*)d_in[20];
  const float* enc_b    = (const float*)d_in[21];
  const float* proj_w   = (const float*)d_in[22];
  const float* proj_b   = (const float*)d_in[23];
  float* out = (float*)d_out;

  char* ws = (char*)d_ws;
  const size_t MB = 1024 * 1024;
  // Layout (high-water 112 MB), identical to rounds 8-9:
  //  0-8   h | 8-12 hn | 12-16 ftmp/vtmp | 16-24 conv scratch (+part_h alias)
  //  8-16  part_A alias | 24-40 zbuf/xnT/f1out | 40-56 xc | 56-72 dtb (y in
  //  place) | 72-73 xdbl | 73 stats | 80-112 bf16 weight pool
  float* h      = (float*)(ws + 0);
  short* hn     = (short*)(ws + 8 * MB);
  short* ftmp   = (short*)(ws + 12 * MB);
  short* vtmp   = ftmp;
  short* scratch= (short*)(ws + 16 * MB);
  short* zbuf   = (short*)(ws + 24 * MB);
  short* xnT    = zbuf;
  short* f1out  = zbuf;
  short* xc     = (short*)(ws + 40 * MB);
  unsigned short* dtb = (unsigned short*)(ws + 56 * MB);
  short* xdbl   = (short*)(ws + 72 * MB);
  float* stats  = (float*)(ws + 73 * MB);
  unsigned short* part_A = (unsigned short*)(ws + 8 * MB);
  unsigned short* part_h = (unsigned short*)(ws + 16 * MB);
  float* means = stats, *stdevp = stats + 4096, *rstd = stats + 8192, *xlast = stats + 12288;

  short* emb_wb = (short*)(ws + 80 * MB);
  short* in_wb  = emb_wb + 262144;      // 6 x 2048x512
  short* xp_wb  = in_wb  + 6291456;     // 6 x 64x1024
  short* dt_wb  = xp_wb  + 393216;      // 6 x 1024x32
  short* out_wb = dt_wb  + 196608;      // 6 x 512x1024
  short* w1b    = out_wb + 3145728;     // 3 x 2048x512
  short* w2b    = w1b    + 3145728;     // 3 x 512x2048
  short* projb  = w2b    + 3145728;     // 96x512

  dim3 blk(256);
  const int NOSPLIT = 1 << 30;

  wcvt_k<<<dim3(16240), blk, 0, stream>>>(
      emb_w, m_in_w, m_xp_w, m_dt_w, m_out_w, ffn_w1, ffn_w2, proj_w,
      emb_wb, in_wb, xp_wb, dt_wb, out_wb, w1b, w2b, projb);

  stats_k<<<dim3(2, B_), blk, 0, stream>>>(x, means, stdevp, rstd, xlast);
  tnorm_k<<<dim3(8, 8, B_), blk, 0, stream>>>(x, means, rstd, xnT);
  // emb: M=4096, N=512, K=512
  gemm_k<EPI_F32_BIAS, 64, 32, 64><<<dim3(64, 16), blk, 0, stream>>>(
      xnT, xnT, emb_wb, emb_wb, NOSPLIT, NOSPLIT, DM_, L_, L_, L_,
      h, nullptr, DM_, emb_b, nullptr, nullptr, nullptr);

  for (int il = 0; il < EL_; il++) {
    if (il == 0)
      ln_k<0><<<dim3(4096), blk, 0, stream>>>(h, nullptr, nullptr, ln_g, ln_b, hn);
    else
      ln_k<2><<<dim3(4096), blk, 0, stream>>>(h, ftmp, ffn_b2 + (il - 1) * DM_,
          ln_g + il * DM_, ln_b + il * DM_, hn);
    for (int dir = 0; dir < 2; dir++) {
      int mod = 2 * il + dir;
      // in-proj dir: N=2048, K=512; dir1 stores BOTH outputs time-reversed;
      // z-half stored as silu(z)
      if (dir == 0)
        gemm_k<EPI_INPROJ, 64, 128, 32><<<dim3(64, 16), blk, 0, stream>>>(
            hn, hn, in_wb + (size_t)mod * 2 * DI_ * DM_,
            in_wb + (size_t)mod * 2 * DI_ * DM_, NOSPLIT, NOSPLIT,
            2 * DI_, DM_, DM_, DM_,
            (float*)(zbuf + (size_t)dir * M_ * DI_), scratch, DI_,
            nullptr, nullptr, nullptr, nullptr);
      else
        gemm_k<EPI_INPROJ_REV, 64, 128, 32><<<dim3(64, 16), blk, 0, stream>>>(
            hn, hn, in_wb + (size_t)mod * 2 * DI_ * DM_,
            in_wb + (size_t)mod * 2 * DI_ * DM_, NOSPLIT, NOSPLIT,
            2 * DI_, DM_, DM_, DM_,
            (float*)(zbuf + (size_t)dir * M_ * DI_), scratch, DI_,
            nullptr, nullptr, nullptr, nullptr);
      // conv: plain forward for both dirs (dir1 input already reversed)
      conv_k<<<dim3(2048), blk, 0, stream>>>(
          scratch, m_conv_w + (size_t)mod * DI_ * DC_,
          m_conv_b + (size_t)mod * DI_, xc + (size_t)dir * M_ * DI_);
    }
    // xdbl (both dirs): M=8192, N=64, K=1024; W switches at m=4096
    gemm_k<EPI_BF16, 32, 32, 64><<<dim3(256, 2), blk, 0, stream>>>(
        xc, xc, xp_wb + (size_t)(2 * il) * 64 * DI_,
        xp_wb + (size_t)(2 * il + 1) * 64 * DI_, NOSPLIT, M_,
        64, DI_, DI_, DI_,
        nullptr, xdbl, 64, nullptr, nullptr, nullptr, nullptr);
    // dt (both dirs): M=8192, N=1024, K=32; W+bias switch at m=4096
    gemm_k<EPI_F16_SOFTPLUS, 64, 64, 32><<<dim3(128, 16), blk, 0, stream>>>(
        xdbl, xdbl, dt_wb + (size_t)(2 * il) * DI_ * DTR_,
        dt_wb + (size_t)(2 * il + 1) * DI_ * DTR_, NOSPLIT, M_,
        DI_, DTR_, 64, DTR_,
        nullptr, (short*)dtb, DI_, m_dt_b + (size_t)(2 * il) * DI_,
        nullptr, nullptr, nullptr);
    // fused scans, forward-only: grid (256,16) = 4096 blocks
    const float* Alog = m_A_log + (size_t)(2 * il) * DI_ * DS_;
    const float* Dp = m_D + (size_t)(2 * il) * DI_;
    scan_p1<<<dim3(256, CH_), blk, 0, stream>>>(dtb, xc, xdbl, Alog, part_h, part_A);
    scan_p2<<<dim3(1024), blk, 0, stream>>>(part_h, part_A);
    scan_p3<<<dim3(256, CH_), blk, 0, stream>>>(dtb, xc, xdbl, zbuf, Alog, Dp, part_h);
    // out-proj (concat-K over y0|y1); A1 rows un-reversed via REVA=1
    gemm_k<EPI_HALF_BF16, 64, 32, 64, 1><<<dim3(64, 16), blk, 0, stream>>>(
        (const short*)dtb, (const short*)(dtb + (size_t)M_ * DI_),
        out_wb + (size_t)(2 * il) * DM_ * DI_,
        out_wb + (size_t)(2 * il + 1) * DM_ * DI_,
        DI_, NOSPLIT, DM_, 2 * DI_, DI_, DI_,
        nullptr, vtmp, DM_, nullptr, nullptr, nullptr, nullptr);
    ln_k<1><<<dim3(4096), blk, 0, stream>>>(h, vtmp, nullptr,
        ffn_ln_g + il * DM_, ffn_ln_b + il * DM_, hn);
    // ffn1: N=2048, K=512 -> f1out [M][2048]
    gemm_k<EPI_GELU, 64, 128, 32><<<dim3(64, 16), blk, 0, stream>>>(
        hn, hn, w1b + (size_t)il * 4 * DM_ * DM_,
        w1b + (size_t)il * 4 * DM_ * DM_, NOSPLIT, NOSPLIT,
        4 * DM_, DM_, DM_, DM_,
        nullptr, f1out, 4 * DM_, ffn_b1 + (size_t)il * 4 * DM_,
        nullptr, nullptr, nullptr);
    // ffn2: N=512, K=2048 -> ftmp
    gemm_k<EPI_BF16, 64, 32, 64><<<dim3(64, 16), blk, 0, stream>>>(
        f1out, f1out, w2b + (size_t)il * DM_ * 4 * DM_,
        w2b + (size_t)il * DM_ * 4 * DM_, NOSPLIT, NOSPLIT,
        DM_, 4 * DM_, 4 * DM_, 4 * DM_,
        nullptr, ftmp, DM_, nullptr, nullptr, nullptr, nullptr);
  }

  ln_k<2><<<dim3(4096), blk, 0, stream>>>(h, ftmp, ffn_b2 + 2 * DM_,
      enc_g, enc_b, hn);
  // proj: N=96, K=512
  gemm_k<EPI_PROJ, 64, 32, 64><<<dim3(64, 3), blk, 0, stream>>>(
      hn, hn, projb, projb, NOSPLIT, NOSPLIT, PL_, DM_, DM_, DM_,
      out, nullptr, 0, proj_b, xlast, stdevp, means);
}

// Round 11
// 1060.153 us; speedup vs baseline: 1.1818x; 1.0086x over previous
//
#include <hip/hip_runtime.h>
#include <hip/hip_bf16.h>
#include <math.h>

#define B_ 8
#define L_ 512
#define DV_ 512
#define DM_ 512
#define PL_ 96
#define EL_ 3
#define DS_ 16
#define DC_ 4
#define DI_ 1024
#define DTR_ 32
#define S_ 512
#define M_ 4096        // B*S
#define CH_ 16         // scan chunks
#define CS_ 32         // steps per chunk
#define LOG2E_ 1.44269504088896f

typedef float f32x4 __attribute__((ext_vector_type(4)));
typedef short bf16x8 __attribute__((ext_vector_type(8)));
typedef short bf16x4 __attribute__((ext_vector_type(4)));

__device__ __forceinline__ float bf2f(short s) {
  unsigned u = ((unsigned)(unsigned short)s) << 16;
  return __builtin_bit_cast(float, u);
}
__device__ __forceinline__ short f2bf(float f) {
  unsigned u = __builtin_bit_cast(unsigned, f);
  u = u + 0x7FFFu + ((u >> 16) & 1u);   // RNE
  return (short)(u >> 16);
}
__device__ __forceinline__ float h2f(unsigned short u) {
  _Float16 h = __builtin_bit_cast(_Float16, u);
  return (float)h;
}
__device__ __forceinline__ unsigned short f2h(float f) {
  _Float16 h = (_Float16)f;
  return __builtin_bit_cast(unsigned short, h);
}

// Native v_exp_f32 (exp2).  NOT libm exp2f (denormal fixups — round-7
// regression).  Fallback keeps correctness if the builtin is missing.
__device__ __forceinline__ float exp2n(float x) {
#if __has_builtin(__builtin_amdgcn_exp2f)
  return __builtin_amdgcn_exp2f(x);
#else
  return __expf(x * 0.69314718055994531f);
#endif
}

// global -> LDS DMA, 16B per lane.  LDS dest is wave-uniform base + lane*16.
__device__ __forceinline__ void gload16(const short* g, short* l) {
  __builtin_amdgcn_global_load_lds(
      (const __attribute__((address_space(1))) void*)g,
      (__attribute__((address_space(3))) void*)l, 16, 0, 0);
}

// ---------------------------------------------------------------------------
// One-shot fp32 -> bf16 conversion of ALL GEMM weights into workspace.
// ---------------------------------------------------------------------------
#define WC0 65536                 // emb_w      512*512
#define WC1 (WC0 + 1572864)       // m_in_w     6*2048*512
#define WC2 (WC1 + 98304)         // m_xp_w     6*64*1024
#define WC3 (WC2 + 49152)         // m_dt_w     6*1024*32
#define WC4 (WC3 + 786432)        // m_out_w    6*512*1024
#define WC5 (WC4 + 786432)        // ffn_w1     3*2048*512
#define WC6 (WC5 + 786432)        // ffn_w2     3*512*2048
#define WC7 (WC6 + 12288)        // proj_w     96*512
// WC7 = 4157440 float4s; grid = 16240 * 256 exactly.

__global__ __launch_bounds__(256)
void wcvt_k(const float* __restrict__ e, const float* __restrict__ iw,
            const float* __restrict__ xp, const float* __restrict__ dtw,
            const float* __restrict__ ow, const float* __restrict__ w1,
            const float* __restrict__ w2, const float* __restrict__ pw,
            short* __restrict__ de, short* __restrict__ di,
            short* __restrict__ dxp, short* __restrict__ ddt,
            short* __restrict__ dow, short* __restrict__ dw1,
            short* __restrict__ dw2, short* __restrict__ dpw)
{
  int idx = blockIdx.x * 256 + threadIdx.x;
  const float* s; short* d; int off;
  if (idx < WC0)      { s = e;   d = de;  off = idx; }
  else if (idx < WC1) { s = iw;  d = di;  off = idx - WC0; }
  else if (idx < WC2) { s = xp;  d = dxp; off = idx - WC1; }
  else if (idx < WC3) { s = dtw; d = ddt; off = idx - WC2; }
  else if (idx < WC4) { s = ow;  d = dow; off = idx - WC3; }
  else if (idx < WC5) { s = w1;  d = dw1; off = idx - WC4; }
  else if (idx < WC6) { s = w2;  d = dw2; off = idx - WC5; }
  else                { s = pw;  d = dpw; off = idx - WC6; }
  float4 v = ((const float4*)s)[off];
  union { short sh[4]; int2 p; } r;
  r.sh[0] = f2bf(v.x); r.sh[1] = f2bf(v.y);
  r.sh[2] = f2bf(v.z); r.sh[3] = f2bf(v.w);
  ((int2*)d)[off] = r.p;
}

// ---------------------------------------------------------------------------
// Instance-norm statistics over the time axis (L) of x (B,L,DV) fp32.
// ---------------------------------------------------------------------------
__global__ __launch_bounds__(256)
void stats_k(const float* __restrict__ x, float* __restrict__ means,
             float* __restrict__ stdev, float* __restrict__ rstd,
             float* __restrict__ xlast)
{
  int d = blockIdx.x * 256 + threadIdx.x;       // 0..511
  int b = blockIdx.y;
  const float* xp = x + (size_t)b * L_ * DV_ + d;
  float s = 0.f, ss = 0.f;
  for (int l = 0; l < L_; l++) {
    float v = xp[(size_t)l * DV_];
    s += v; ss += v * v;
  }
  float mu = s / (float)L_;
  float var = ss / (float)L_ - mu * mu;
  float sd = sqrtf(var + 1e-5f);
  float rs = 1.f / sd;
  int idx = b * DV_ + d;
  means[idx] = mu; stdev[idx] = sd; rstd[idx] = rs;
  xlast[idx] = (xp[(size_t)(L_ - 1) * DV_] - mu) * rs;
}

// ---------------------------------------------------------------------------
// Normalize + transpose: xnT[b,d,l] = (x[b,l,d]-mu[b,d])*rstd[b,d]  (bf16)
// ---------------------------------------------------------------------------
__global__ __launch_bounds__(256)
void tnorm_k(const float* __restrict__ x, const float* __restrict__ means,
             const float* __restrict__ rstd, short* __restrict__ xnT)
{
  __shared__ float tile[64][65];
  const int t = threadIdx.x;
  const int j = t & 63;
  const int i0 = t >> 6;                 // 0..3
  const int bz = blockIdx.z;
  const int l0 = blockIdx.y << 6;
  const int d0 = blockIdx.x << 6;
  const float* xp = x + ((size_t)bz * L_ + l0) * DV_ + d0;
  #pragma unroll
  for (int i = i0; i < 64; i += 4) tile[i][j] = xp[(size_t)i * DV_ + j];
  __syncthreads();
  short* op = xnT + ((size_t)bz * DV_ + d0) * L_ + l0;
  const int sb = bz * DV_ + d0;
  #pragma unroll
  for (int i = i0; i < 64; i += 4) {
    float mu = means[sb + i];
    float rs = rstd[sb + i];
    op[(size_t)i * L_ + j] = f2bf((tile[j][i] - mu) * rs);
  }
}

// ---------------------------------------------------------------------------
// Fused LayerNorm: optionally h += add (+ abias) in place, then LN -> bf16.
// ---------------------------------------------------------------------------
template <int ADD>
__global__ __launch_bounds__(256)
void ln_k(float* __restrict__ X, const short* __restrict__ add,
          const float* __restrict__ abias,
          const float* __restrict__ g, const float* __restrict__ b,
          short* __restrict__ Y)
{
  int row = blockIdx.x;
  float* x = X + (size_t)row * DM_;
  int t = threadIdx.x;
  float v0 = x[t], v1 = x[t + 256];
  if constexpr (ADD >= 1) {
    v0 += bf2f(add[(size_t)row * DM_ + t]);
    v1 += bf2f(add[(size_t)row * DM_ + t + 256]);
    if constexpr (ADD == 2) { v0 += abias[t]; v1 += abias[t + 256]; }
    x[t] = v0; x[t + 256] = v1;
  }
  float s = v0 + v1, ss = v0 * v0 + v1 * v1;
  #pragma unroll
  for (int o = 1; o < 64; o <<= 1) { s += __shfl_xor(s, o); ss += __shfl_xor(ss, o); }
  __shared__ float sb[8];
  int wave = t >> 6, lane = t & 63;
  if (lane == 0) { sb[wave] = s; sb[4 + wave] = ss; }
  __syncthreads();
  s = sb[0] + sb[1] + sb[2] + sb[3];
  ss = sb[4] + sb[5] + sb[6] + sb[7];
  float mu = s / (float)DM_;
  float var = ss / (float)DM_ - mu * mu;
  float rs = rsqrtf(var + 1e-5f);
  Y[(size_t)row * DM_ + t]       = f2bf((v0 - mu) * rs * g[t]       + b[t]);
  Y[(size_t)row * DM_ + t + 256] = f2bf((v1 - mu) * rs * g[t + 256] + b[t + 256]);
}

// ---------------------------------------------------------------------------
// Depthwise causal conv (DC=4 taps) + bias + silu.  Vectorized, 8 ch/thread.
// FORWARD ONLY: dir-1 input arrives already time-reversed (v-domain).
// ---------------------------------------------------------------------------
__global__ __launch_bounds__(256)
void conv_k(const short* __restrict__ xcin, const float* __restrict__ w,
            const float* __restrict__ cb, short* __restrict__ xcout)
{
  int idx = blockIdx.x * 256 + threadIdx.x;   // over B*S*DI/8
  int ig = (idx & 127) << 3;                  // channel group base
  int bs = idx >> 7;                          // b*S + tau
  int tt0 = bs & (S_ - 1);
  int b = bs >> 9;
  const short* u = xcin + (size_t)(b * S_) * DI_ + ig;  // row stride DI
  float4 wv[8];
  #pragma unroll
  for (int n = 0; n < 8; n++) wv[n] = *(const float4*)(w + (ig + n) * DC_);
  float acc[8];
  {
    float4 c0 = *(const float4*)(cb + ig);
    float4 c1 = *(const float4*)(cb + ig + 4);
    acc[0] = c0.x; acc[1] = c0.y; acc[2] = c0.z; acc[3] = c0.w;
    acc[4] = c1.x; acc[5] = c1.y; acc[6] = c1.z; acc[7] = c1.w;
  }
  #pragma unroll
  for (int k = 0; k < DC_; k++) {
    int tt = tt0 - (DC_ - 1) + k;
    if (tt >= 0) {
      bf16x8 uv = *(const bf16x8*)(u + (size_t)tt * DI_);
      #pragma unroll
      for (int n = 0; n < 8; n++) {
        float wk = (k == 0) ? wv[n].x : (k == 1) ? wv[n].y
                 : (k == 2) ? wv[n].z : wv[n].w;
        acc[n] += wk * bf2f(uv[n]);
      }
    }
  }
  union { short sh[8]; bf16x8 v; } r;
  #pragma unroll
  for (int n = 0; n < 8; n++) {
    float sig = 1.f / (1.f + __expf(-acc[n]));
    r.sh[n] = f2bf(acc[n] * sig);
  }
  *(bf16x8*)(xcout + ((size_t)bs << 10) + ig) = r.v;
}

// ---------------------------------------------------------------------------
// Chunked selective scan, both dirs fused, forward-only traversal.
// Round 11: EXPLICIT GROUP-BATCHED LOADS.  Round-10 PMC (VALUBusy 52%,
// occ 73%, dur 68us vs ~21us issue floor) matches a per-step
// load->wait(~400cy)->compute(~100cy) serial pattern: the compiler was not
// hoisting the group's loads ahead of compute (in-place y-over-dt store +
// conditional store inhibit reordering).  Batch the whole group's inputs
// into statically-indexed registers BEFORE any compute/store: the
// serialization point drops from per-step to per-group.  p1 group=8 (no
// stores), p3 group=4 (keeps VGPR < 64 for 8 blocks/CU).
// ---------------------------------------------------------------------------
__global__ __launch_bounds__(256)
void scan_p1(const unsigned short* __restrict__ dt16, const short* __restrict__ xc,
             const short* __restrict__ xdbl, const float* __restrict__ A_log,
             unsigned short* __restrict__ part_h, unsigned short* __restrict__ part_A)
{
  const int gid = blockIdx.x * 256 + threadIdx.x;   // over 2*B*DI*4
  const int q = gid & 3;
  const int i = (gid >> 2) & (DI_ - 1);
  const int b = (gid >> 12) & (B_ - 1);
  const int dir = gid >> 15;
  const int c = blockIdx.y;
  float Ai2[4];
  const float* al = A_log + (size_t)dir * DI_ * DS_ + i * DS_ + q * 4;
  #pragma unroll
  for (int n = 0; n < 4; n++) Ai2[n] = -__expf(al[n]) * LOG2E_;

  const size_t base = (size_t)dir * M_ * DI_ + ((size_t)b * S_ + c * CS_) * DI_ + i;
  const unsigned short* pdt = dt16 + base;
  const short* pu = xc + base;
  const short* pbc = xdbl + (size_t)dir * M_ * 64 +
                     (((size_t)b * S_ + c * CS_) << 6) + DTR_ + q * 4;

  float h[4];
  #pragma unroll
  for (int n = 0; n < 4; n++) h[n] = 0.f;
  float dsum = 0.f;

  for (int s0 = 0; s0 < CS_; s0 += 8) {
    float dtv[8], uu[8];
    bf16x4 vB8[8];
    #pragma unroll
    for (int k = 0; k < 8; k++) {
      dtv[k] = h2f(pdt[(size_t)k * DI_]);
      uu[k]  = bf2f(pu[(size_t)k * DI_]);
      vB8[k] = *(const bf16x4*)(pbc + k * 64);
    }
    #pragma unroll
    for (int k = 0; k < 8; k++) {
      float du = dtv[k] * uu[k];
      dsum += dtv[k];
      #pragma unroll
      for (int n = 0; n < 4; n++) {
        float dA = exp2n(dtv[k] * Ai2[n]);
        h[n] = dA * h[n] + du * bf2f(vB8[k][n]);
      }
    }
    pdt += 8 * DI_; pu += 8 * DI_; pbc += 8 * 64;
  }
  union { unsigned short s[4]; int2 v; } uh, ua;
  #pragma unroll
  for (int n = 0; n < 4; n++) {
    uh.s[n] = f2h(h[n]);
    ua.s[n] = f2h(exp2n(Ai2[n] * dsum));   // exact: prod exp(dt*A)=exp(A*sum dt)
  }
  const size_t ix = ((((size_t)c * 2 * B_ + dir * B_ + b) * DI_ + i) << 4) + (q << 2);
  *(int2*)(part_h + ix) = uh.v;
  *(int2*)(part_A + ix) = ua.v;
}

__global__ __launch_bounds__(256)
void scan_p2(unsigned short* __restrict__ part_h,
             const unsigned short* __restrict__ part_A)
{
  const size_t gid = (size_t)blockIdx.x * 256 + threadIdx.x;   // 2*B*DI*DS
  const size_t stride = (size_t)2 * B_ * DI_ * DS_;
  float hin = 0.f;
  #pragma unroll
  for (int c = 0; c < CH_; c++) {
    size_t ix = (size_t)c * stride + gid;
    float hh = h2f(part_h[ix]);
    float pA = h2f(part_A[ix]);
    part_h[ix] = f2h(hin);            // becomes chunk c's incoming state
    hin = hh + pA * hin;
  }
}

// y overwrites dt16 in place (element-exact same indices) — no __restrict__.
// zb holds PRE-SILU'd z (bf16).
__global__ __launch_bounds__(256)
void scan_p3(unsigned short* dt16, const short* __restrict__ xc,
             const short* __restrict__ xdbl, const short* __restrict__ zb,
             const float* __restrict__ A_log, const float* __restrict__ Dp,
             const unsigned short* __restrict__ part_h)
{
  const int gid = blockIdx.x * 256 + threadIdx.x;   // over 2*B*DI*4
  const int q = gid & 3;
  const int i = (gid >> 2) & (DI_ - 1);
  const int b = (gid >> 12) & (B_ - 1);
  const int dir = gid >> 15;
  const int c = blockIdx.y;
  float Ai2[4];
  const float* al = A_log + (size_t)dir * DI_ * DS_ + i * DS_ + q * 4;
  #pragma unroll
  for (int n = 0; n < 4; n++) Ai2[n] = -__expf(al[n]) * LOG2E_;
  const float Di = Dp[(size_t)dir * DI_ + i];

  float h[4];
  {
    const size_t ix = ((((size_t)c * 2 * B_ + dir * B_ + b) * DI_ + i) << 4) + (q << 2);
    union { unsigned short s[4]; int2 v; } uh;
    uh.v = *(const int2*)(part_h + ix);
    #pragma unroll
    for (int n = 0; n < 4; n++) h[n] = h2f(uh.s[n]);
  }

  const size_t base = (size_t)dir * M_ * DI_ + ((size_t)b * S_ + c * CS_) * DI_ + i;
  unsigned short* pdt = dt16 + base;
  const short* pu = xc + base;
  const short* pz = zb + base;
  const short* pbc = xdbl + (size_t)dir * M_ * 64 +
                     (((size_t)b * S_ + c * CS_) << 6) + DTR_ + q * 4;

  for (int s0 = 0; s0 < CS_; s0 += 4) {
    float dtv[4], uu[4], sil4[4];
    bf16x4 vB4[4], vC4[4];
    #pragma unroll
    for (int k = 0; k < 4; k++) {
      dtv[k]  = h2f(pdt[(size_t)k * DI_]);
      uu[k]   = bf2f(pu[(size_t)k * DI_]);
      vB4[k]  = *(const bf16x4*)(pbc + k * 64);
      vC4[k]  = *(const bf16x4*)(pbc + k * 64 + DS_);
      sil4[k] = bf2f(pz[(size_t)k * DI_]);   // silu pre-applied at in-proj
    }
    #pragma unroll
    for (int k = 0; k < 4; k++) {
      float du = dtv[k] * uu[k];
      float yp = 0.f;
      #pragma unroll
      for (int n = 0; n < 4; n++) {
        float dA = exp2n(dtv[k] * Ai2[n]);
        h[n] = dA * h[n] + du * bf2f(vB4[k][n]);
        yp += h[n] * bf2f(vC4[k][n]);
      }
      yp += __shfl_xor(yp, 1);
      yp += __shfl_xor(yp, 2);          // quad-wide sum over all 16 states
      float yv = (yp + uu[k] * Di) * sil4[k];
      if (q == 0) *(short*)(pdt + (size_t)k * DI_) = f2bf(yv);  // y over dt
    }
    pdt += 4 * DI_; pu += 4 * DI_; pz += 4 * DI_; pbc += 4 * 64;
  }
}

// ---------------------------------------------------------------------------
// bf16 MFMA GEMM: C[M,N] = A[M,K] * W[N,K]^T, fp32 accum.  global_load_lds
// DMA staging, source-swizzled, 3 LDS buffers, counted vmcnt.
// khalf: concat-K source switch.  mhalf: block-uniform M-half W switch.
// REVA: reverse time (row^511) when reading A1 slabs.
// INPROJ epilogues: z-half is written as silu(z) (scan consumes it directly).
// ---------------------------------------------------------------------------
enum { EPI_F32_BIAS, EPI_BF16, EPI_F16_SOFTPLUS, EPI_HALF_BF16, EPI_GELU,
       EPI_PROJ, EPI_INPROJ, EPI_INPROJ_REV };

template <int EPI, int BM, int BN, int BK, int REVA = 0>
__global__ __launch_bounds__(256)
void gemm_k(const short* __restrict__ A0, const short* __restrict__ A1,
            const short* __restrict__ W0, const short* __restrict__ W1,
            int khalf, int mhalf, int N, int K, int lda, int ldw,
            float* __restrict__ Cf, short* __restrict__ Cb, int ldc,
            const float* __restrict__ bias,
            const float* __restrict__ xlast, const float* __restrict__ stdev,
            const float* __restrict__ means)
{
  constexpr int MT = BM / 32;
  constexpr int NT = BN / 32;
  constexpr int KS = BK / 32;
  constexpr int CHK = BK / 8;
  constexpr int MSK = CHK - 1;
  constexpr int NA = (BM * CHK) / 256;
  constexpr int NW = (BN * CHK) / 256;
  constexpr int VC = NA + NW;
  __shared__ __align__(16) short As[3][BM * BK];
  __shared__ __align__(16) short Ws[3][BN * BK];
  const int tid = threadIdx.x;
  const int m0 = blockIdx.x * BM;
  const int n0 = blockIdx.y * BN;
  const int wave = tid >> 6, lane = tid & 63;
  const int wm = (wave & 1) * (BM / 2), wn = (wave >> 1) * (BN / 2);
  const int quad = lane >> 4, l16 = lane & 15;

  const short* W0m = (m0 < mhalf) ? W0 : W1;   // block-uniform M-half switch

  f32x4 acc[MT][NT] = {};

  size_t aoff[NA], aoffR[REVA ? NA : 1];
  #pragma unroll
  for (int j = 0; j < NA; j++) {
    int id = j * 256 + tid;
    int r = id / CHK, qp = id % CHK;
    aoff[j] = (size_t)(m0 + r) * lda + ((qp ^ (r & MSK)) << 3);
    if constexpr (REVA)
      aoffR[j] = (size_t)((m0 + r) ^ (S_ - 1)) * lda + ((qp ^ (r & MSK)) << 3);
  }
  size_t woff[NW];
  #pragma unroll
  for (int j = 0; j < NW; j++) {
    int id = j * 256 + tid;
    int r = id / CHK, qp = id % CHK;
    int wr = n0 + r; if (wr > N - 1) wr = N - 1;
    woff[j] = (size_t)wr * ldw + ((qp ^ (r & MSK)) << 3);
  }
  const int lbase = wave * 512;

  const int KB = K / BK;

  auto stage = [&](int slab, int bi) {
    const int k0 = slab * BK;
    const short* Ab = (k0 < khalf) ? A0 + k0 : A1 + (k0 - khalf);
    const short* Wb = (k0 < khalf) ? W0m + k0 : W1 + (k0 - khalf);
    const size_t* ao = (REVA && k0 >= khalf) ? aoffR : aoff;
    #pragma unroll
    for (int j = 0; j < NA; j++)
      gload16(Ab + ao[j], &As[bi][j * 2048 + lbase]);
    #pragma unroll
    for (int j = 0; j < NW; j++)
      gload16(Wb + woff[j], &Ws[bi][j * 2048 + lbase]);
  };

  stage(0, 0);
  if (KB > 1) stage(1, 1);
  __builtin_amdgcn_sched_barrier(0);
  if (KB > 1) asm volatile("s_waitcnt vmcnt(%0)" :: "n"(VC) : "memory");
  else        asm volatile("s_waitcnt vmcnt(0)" ::: "memory");
  __builtin_amdgcn_s_barrier();
  __builtin_amdgcn_sched_barrier(0);

  int cur = 0, nxt = 2;
  for (int kb = 0; kb < KB; kb++) {
    if (kb + 2 < KB) {
      stage(kb + 2, nxt);
      __builtin_amdgcn_sched_barrier(0);
    }
    bf16x8 af[MT][KS], bfr[NT][KS];
    #pragma unroll
    for (int mt = 0; mt < MT; mt++)
      #pragma unroll
      for (int st = 0; st < KS; st++)
        af[mt][st] = *(const bf16x8*)(&As[cur][0] + (wm + mt * 16 + l16) * BK +
                                      (((st * 4 + quad) ^ (l16 & MSK)) << 3));
    #pragma unroll
    for (int nt = 0; nt < NT; nt++)
      #pragma unroll
      for (int st = 0; st < KS; st++)
        bfr[nt][st] = *(const bf16x8*)(&Ws[cur][0] + (wn + nt * 16 + l16) * BK +
                                       (((st * 4 + quad) ^ (l16 & MSK)) << 3));
    #pragma unroll
    for (int st = 0; st < KS; st++)
      #pragma unroll
      for (int mt = 0; mt < MT; mt++)
        #pragma unroll
        for (int nt = 0; nt < NT; nt++)
          acc[mt][nt] = __builtin_amdgcn_mfma_f32_16x16x32_bf16(
              af[mt][st], bfr[nt][st], acc[mt][nt], 0, 0, 0);
    if (kb + 1 < KB) {
      __builtin_amdgcn_sched_barrier(0);
      if (kb + 2 < KB) asm volatile("s_waitcnt vmcnt(%0)" :: "n"(VC) : "memory");
      else             asm volatile("s_waitcnt vmcnt(0)" ::: "memory");
      __builtin_amdgcn_s_barrier();
      __builtin_amdgcn_sched_barrier(0);
      cur = (cur == 2) ? 0 : cur + 1;
      nxt = (nxt == 2) ? 0 : nxt + 1;
    }
  }

  const int boff = (m0 < mhalf) ? 0 : N;   // M-half bias switch (contiguous)

  #pragma unroll
  for (int mt = 0; mt < MT; mt++) {
    #pragma unroll
    for (int nt = 0; nt < NT; nt++) {
      int n = n0 + wn + nt * 16 + l16;
      if (n >= N) continue;
      #pragma unroll
      for (int r = 0; r < 4; r++) {
        int m = m0 + wm + mt * 16 + quad * 4 + r;
        float v = acc[mt][nt][r];
        if constexpr (EPI == EPI_F32_BIAS) {
          Cf[(size_t)m * ldc + n] = v + bias[n];
        } else if constexpr (EPI == EPI_BF16) {
          Cb[(size_t)m * ldc + n] = f2bf(v);
        } else if constexpr (EPI == EPI_F16_SOFTPLUS) {
          float tt = v + bias[n + boff];
          float sp = (tt > 20.f) ? tt : log1pf(__expf(tt));
          ((unsigned short*)Cb)[(size_t)m * ldc + n] = f2h(sp);
        } else if constexpr (EPI == EPI_HALF_BF16) {
          Cb[(size_t)m * ldc + n] = f2bf(0.5f * v);
        } else if constexpr (EPI == EPI_GELU) {
          float tt = v + bias[n];
          Cb[(size_t)m * ldc + n] = f2bf(0.5f * tt * (1.f + erff(tt * 0.70710678118f)));
        } else if constexpr (EPI == EPI_PROJ) {
          int bb = m >> 9, d = m & 511;
          float tt = v + bias[n] + xlast[m];
          tt = tt * stdev[m] + means[m];
          Cf[((size_t)bb * PL_ + n) * DV_ + d] = tt;
        } else if constexpr (EPI == EPI_INPROJ) {
          if (n < DI_) Cb[(size_t)m * ldc + n] = f2bf(v);
          else {
            float sz = v / (1.f + __expf(-v));     // pre-apply silu to z
            ((short*)Cf)[(size_t)m * DI_ + (n - DI_)] = f2bf(sz);
          }
        } else if constexpr (EPI == EPI_INPROJ_REV) {
          // store in reversed time-domain: row m -> m^511 (t -> S-1-t)
          int mr = m ^ (S_ - 1);
          if (n < DI_) Cb[(size_t)mr * ldc + n] = f2bf(v);
          else {
            float sz = v / (1.f + __expf(-v));     // pre-apply silu to z
            ((short*)Cf)[(size_t)mr * DI_ + (n - DI_)] = f2bf(sz);
          }
        }
      }
    }
  }
}

// ---------------------------------------------------------------------------
extern "C" void kernel_launch(void* const* d_in, const int* in_sizes, int n_in,
                              void* d_out, int out_size, void* d_ws, size_t ws_size,
                              hipStream_t stream)
{
  (void)in_sizes; (void)n_in; (void)out_size; (void)ws_size;
  const float* x        = (const float*)d_in[0];
  const float* emb_w    = (const float*)d_in[1];
  const float* emb_b    = (const float*)d_in[2];
  const float* ln_g     = (const float*)d_in[3];
  const float* ln_b     = (const float*)d_in[4];
  const float* m_in_w   = (const float*)d_in[5];
  const float* m_conv_w = (const float*)d_in[6];
  const float* m_conv_b = (const float*)d_in[7];
  const float* m_xp_w   = (const float*)d_in[8];
  const float* m_dt_w   = (const float*)d_in[9];
  const float* m_dt_b   = (const float*)d_in[10];
  const float* m_A_log  = (const float*)d_in[11];
  const float* m_D      = (const float*)d_in[12];
  const float* m_out_w  = (const float*)d_in[13];
  const float* ffn_ln_g = (const float*)d_in[14];
  const float* ffn_ln_b = (const float*)d_in[15];
  const float* ffn_w1   = (const float*)d_in[16];
  const float* ffn_b1   = (const float*)d_in[17];
  const float* ffn_w2   = (const float*)d_in[18];
  const float* ffn_b2   = (const float*)d_in[19];
  const float* enc_g    = (const float*)d_in[20];
  const float* enc_b    = (const float*)d_in[21];
  const float* proj_w   = (const float*)d_in[22];
  const float* proj_b   = (const float*)d_in[23];
  float* out = (float*)d_out;

  char* ws = (char*)d_ws;
  const size_t MB = 1024 * 1024;
  // Layout (high-water 112 MB), identical to rounds 8-10:
  //  0-8   h | 8-12 hn | 12-16 ftmp/vtmp | 16-24 conv scratch (+part_h alias)
  //  8-16  part_A alias | 24-40 zbuf/xnT/f1out | 40-56 xc | 56-72 dtb (y in
  //  place) | 72-73 xdbl | 73 stats | 80-112 bf16 weight pool
  float* h      = (float*)(ws + 0);
  short* hn     = (short*)(ws + 8 * MB);
  short* ftmp   = (short*)(ws + 12 * MB);
  short* vtmp   = ftmp;
  short* scratch= (short*)(ws + 16 * MB);
  short* zbuf   = (short*)(ws + 24 * MB);
  short* xnT    = zbuf;
  short* f1out  = zbuf;
  short* xc     = (short*)(ws + 40 * MB);
  unsigned short* dtb = (unsigned short*)(ws + 56 * MB);
  short* xdbl   = (short*)(ws + 72 * MB);
  float* stats  = (float*)(ws + 73 * MB);
  unsigned short* part_A = (unsigned short*)(ws + 8 * MB);
  unsigned short* part_h = (unsigned short*)(ws + 16 * MB);
  float* means = stats, *stdevp = stats + 4096, *rstd = stats + 8192, *xlast = stats + 12288;

  short* emb_wb = (short*)(ws + 80 * MB);
  short* in_wb  = emb_wb + 262144;      // 6 x 2048x512
  short* xp_wb  = in_wb  + 6291456;     // 6 x 64x1024
  short* dt_wb  = xp_wb  + 393216;      // 6 x 1024x32
  short* out_wb = dt_wb  + 196608;      // 6 x 512x1024
  short* w1b    = out_wb + 3145728;     // 3 x 2048x512
  short* w2b    = w1b    + 3145728;     // 3 x 512x2048
  short* projb  = w2b    + 3145728;     // 96x512

  dim3 blk(256);
  const int NOSPLIT = 1 << 30;

  wcvt_k<<<dim3(16240), blk, 0, stream>>>(
      emb_w, m_in_w, m_xp_w, m_dt_w, m_out_w, ffn_w1, ffn_w2, proj_w,
      emb_wb, in_wb, xp_wb, dt_wb, out_wb, w1b, w2b, projb);

  stats_k<<<dim3(2, B_), blk, 0, stream>>>(x, means, stdevp, rstd, xlast);
  tnorm_k<<<dim3(8, 8, B_), blk, 0, stream>>>(x, means, rstd, xnT);
  // emb: M=4096, N=512, K=512
  gemm_k<EPI_F32_BIAS, 64, 32, 64><<<dim3(64, 16), blk, 0, stream>>>(
      xnT, xnT, emb_wb, emb_wb, NOSPLIT, NOSPLIT, DM_, L_, L_, L_,
      h, nullptr, DM_, emb_b, nullptr, nullptr, nullptr);

  for (int il = 0; il < EL_; il++) {
    if (il == 0)
      ln_k<0><<<dim3(4096), blk, 0, stream>>>(h, nullptr, nullptr, ln_g, ln_b, hn);
    else
      ln_k<2><<<dim3(4096), blk, 0, stream>>>(h, ftmp, ffn_b2 + (il - 1) * DM_,
          ln_g + il * DM_, ln_b + il * DM_, hn);
    for (int dir = 0; dir < 2; dir++) {
      int mod = 2 * il + dir;
      // in-proj dir: N=2048, K=512; dir1 stores BOTH outputs time-reversed;
      // z-half stored as silu(z)
      if (dir == 0)
        gemm_k<EPI_INPROJ, 64, 128, 32><<<dim3(64, 16), blk, 0, stream>>>(
            hn, hn, in_wb + (size_t)mod * 2 * DI_ * DM_,
            in_wb + (size_t)mod * 2 * DI_ * DM_, NOSPLIT, NOSPLIT,
            2 * DI_, DM_, DM_, DM_,
            (float*)(zbuf + (size_t)dir * M_ * DI_), scratch, DI_,
            nullptr, nullptr, nullptr, nullptr);
      else
        gemm_k<EPI_INPROJ_REV, 64, 128, 32><<<dim3(64, 16), blk, 0, stream>>>(
            hn, hn, in_wb + (size_t)mod * 2 * DI_ * DM_,
            in_wb + (size_t)mod * 2 * DI_ * DM_, NOSPLIT, NOSPLIT,
            2 * DI_, DM_, DM_, DM_,
            (float*)(zbuf + (size_t)dir * M_ * DI_), scratch, DI_,
            nullptr, nullptr, nullptr, nullptr);
      // conv: plain forward for both dirs (dir1 input already reversed)
      conv_k<<<dim3(2048), blk, 0, stream>>>(
          scratch, m_conv_w + (size_t)mod * DI_ * DC_,
          m_conv_b + (size_t)mod * DI_, xc + (size_t)dir * M_ * DI_);
    }
    // xdbl (both dirs): M=8192, N=64, K=1024; W switches at m=4096
    gemm_k<EPI_BF16, 32, 32, 64><<<dim3(256, 2), blk, 0, stream>>>(
        xc, xc, xp_wb + (size_t)(2 * il) * 64 * DI_,
        xp_wb + (size_t)(2 * il + 1) * 64 * DI_, NOSPLIT, M_,
        64, DI_, DI_, DI_,
        nullptr, xdbl, 64, nullptr, nullptr, nullptr, nullptr);
    // dt (both dirs): M=8192, N=1024, K=32; W+bias switch at m=4096
    gemm_k<EPI_F16_SOFTPLUS, 64, 64, 32><<<dim3(128, 16), blk, 0, stream>>>(
        xdbl, xdbl, dt_wb + (size_t)(2 * il) * DI_ * DTR_,
        dt_wb + (size_t)(2 * il + 1) * DI_ * DTR_, NOSPLIT, M_,
        DI_, DTR_, 64, DTR_,
        nullptr, (short*)dtb, DI_, m_dt_b + (size_t)(2 * il) * DI_,
        nullptr, nullptr, nullptr);
    // fused scans, forward-only: grid (256,16) = 4096 blocks
    const float* Alog = m_A_log + (size_t)(2 * il) * DI_ * DS_;
    const float* Dp = m_D + (size_t)(2 * il) * DI_;
    scan_p1<<<dim3(256, CH_), blk, 0, stream>>>(dtb, xc, xdbl, Alog, part_h, part_A);
    scan_p2<<<dim3(1024), blk, 0, stream>>>(part_h, part_A);
    scan_p3<<<dim3(256, CH_), blk, 0, stream>>>(dtb, xc, xdbl, zbuf, Alog, Dp, part_h);
    // out-proj (concat-K over y0|y1); A1 rows un-reversed via REVA=1
    gemm_k<EPI_HALF_BF16, 64, 32, 64, 1><<<dim3(64, 16), blk, 0, stream>>>(
        (const short*)dtb, (const short*)(dtb + (size_t)M_ * DI_),
        out_wb + (size_t)(2 * il) * DM_ * DI_,
        out_wb + (size_t)(2 * il + 1) * DM_ * DI_,
        DI_, NOSPLIT, DM_, 2 * DI_, DI_, DI_,
        nullptr, vtmp, DM_, nullptr, nullptr, nullptr, nullptr);
    ln_k<1><<<dim3(4096), blk, 0, stream>>>(h, vtmp, nullptr,
        ffn_ln_g + il * DM_, ffn_ln_b + il * DM_, hn);
    // ffn1: N=2048, K=512 -> f1out [M][2048]
    gemm_k<EPI_GELU, 64, 128, 32><<<dim3(64, 16), blk, 0, stream>>>(
        hn, hn, w1b + (size_t)il * 4 * DM_ * DM_,
        w1b + (size_t)il * 4 * DM_ * DM_, NOSPLIT, NOSPLIT,
        4 * DM_, DM_, DM_, DM_,
        nullptr, f1out, 4 * DM_, ffn_b1 + (size_t)il * 4 * DM_,
        nullptr, nullptr, nullptr);
    // ffn2: N=512, K=2048 -> ftmp
    gemm_k<EPI_BF16, 64, 32, 64><<<dim3(64, 16), blk, 0, stream>>>(
        f1out, f1out, w2b + (size_t)il * DM_ * 4 * DM_,
        w2b + (size_t)il * DM_ * 4 * DM_, NOSPLIT, NOSPLIT,
        DM_, 4 * DM_, 4 * DM_, 4 * DM_,
        nullptr, ftmp, DM_, nullptr, nullptr, nullptr, nullptr);
  }

  ln_k<2><<<dim3(4096), blk, 0, stream>>>(h, ftmp, ffn_b2 + 2 * DM_,
      enc_g, enc_b, hn);
  // proj: N=96, K=512
  gemm_k<EPI_PROJ, 64, 32, 64><<<dim3(64, 3), blk, 0, stream>>>(
      hn, hn, projb, projb, NOSPLIT, NOSPLIT, PL_, DM_, DM_, DM_,
      out, nullptr, 0, proj_b, xlast, stdevp, means);
}

// Round 12
// 992.561 us; speedup vs baseline: 1.2623x; 1.0681x over previous
//
#include <hip/hip_runtime.h>
#include <hip/hip_bf16.h>
#include <math.h>

#define B_ 8
#define L_ 512
#define DV_ 512
#define DM_ 512
#define PL_ 96
#define EL_ 3
#define DS_ 16
#define DC_ 4
#define DI_ 1024
#define DTR_ 32
#define S_ 512
#define M_ 4096        // B*S
#define CH_ 16         // scan chunks
#define CS_ 32         // steps per chunk
#define LOG2E_ 1.44269504088896f

typedef float f32x4 __attribute__((ext_vector_type(4)));
typedef short bf16x8 __attribute__((ext_vector_type(8)));
typedef short bf16x4 __attribute__((ext_vector_type(4)));

__device__ __forceinline__ float bf2f(short s) {
  unsigned u = ((unsigned)(unsigned short)s) << 16;
  return __builtin_bit_cast(float, u);
}
__device__ __forceinline__ short f2bf(float f) {
  unsigned u = __builtin_bit_cast(unsigned, f);
  u = u + 0x7FFFu + ((u >> 16) & 1u);   // RNE
  return (short)(u >> 16);
}
__device__ __forceinline__ float h2f(unsigned short u) {
  _Float16 h = __builtin_bit_cast(_Float16, u);
  return (float)h;
}
__device__ __forceinline__ unsigned short f2h(float f) {
  _Float16 h = (_Float16)f;
  return __builtin_bit_cast(unsigned short, h);
}

// Native v_exp_f32 (exp2).  NOT libm exp2f (denormal fixups — round-7
// regression).  Fallback keeps correctness if the builtin is missing.
__device__ __forceinline__ float exp2n(float x) {
#if __has_builtin(__builtin_amdgcn_exp2f)
  return __builtin_amdgcn_exp2f(x);
#else
  return __expf(x * 0.69314718055994531f);
#endif
}

// global -> LDS DMA, 16B per lane.  LDS dest is wave-uniform base + lane*16.
__device__ __forceinline__ void gload16(const short* g, short* l) {
  __builtin_amdgcn_global_load_lds(
      (const __attribute__((address_space(1))) void*)g,
      (__attribute__((address_space(3))) void*)l, 16, 0, 0);
}

// ---------------------------------------------------------------------------
// One-shot fp32 -> bf16 conversion of ALL GEMM weights into workspace.
// ---------------------------------------------------------------------------
#define WC0 65536                 // emb_w      512*512
#define WC1 (WC0 + 1572864)       // m_in_w     6*2048*512
#define WC2 (WC1 + 98304)         // m_xp_w     6*64*1024
#define WC3 (WC2 + 49152)         // m_dt_w     6*1024*32
#define WC4 (WC3 + 786432)        // m_out_w    6*512*1024
#define WC5 (WC4 + 786432)        // ffn_w1     3*2048*512
#define WC6 (WC5 + 786432)        // ffn_w2     3*512*2048
#define WC7 (WC6 + 12288)        // proj_w     96*512
// WC7 = 4157440 float4s; grid = 16240 * 256 exactly.

__global__ __launch_bounds__(256)
void wcvt_k(const float* __restrict__ e, const float* __restrict__ iw,
            const float* __restrict__ xp, const float* __restrict__ dtw,
            const float* __restrict__ ow, const float* __restrict__ w1,
            const float* __restrict__ w2, const float* __restrict__ pw,
            short* __restrict__ de, short* __restrict__ di,
            short* __restrict__ dxp, short* __restrict__ ddt,
            short* __restrict__ dow, short* __restrict__ dw1,
            short* __restrict__ dw2, short* __restrict__ dpw)
{
  int idx = blockIdx.x * 256 + threadIdx.x;
  const float* s; short* d; int off;
  if (idx < WC0)      { s = e;   d = de;  off = idx; }
  else if (idx < WC1) { s = iw;  d = di;  off = idx - WC0; }
  else if (idx < WC2) { s = xp;  d = dxp; off = idx - WC1; }
  else if (idx < WC3) { s = dtw; d = ddt; off = idx - WC2; }
  else if (idx < WC4) { s = ow;  d = dow; off = idx - WC3; }
  else if (idx < WC5) { s = w1;  d = dw1; off = idx - WC4; }
  else if (idx < WC6) { s = w2;  d = dw2; off = idx - WC5; }
  else                { s = pw;  d = dpw; off = idx - WC6; }
  float4 v = ((const float4*)s)[off];
  union { short sh[4]; int2 p; } r;
  r.sh[0] = f2bf(v.x); r.sh[1] = f2bf(v.y);
  r.sh[2] = f2bf(v.z); r.sh[3] = f2bf(v.w);
  ((int2*)d)[off] = r.p;
}

// ---------------------------------------------------------------------------
// Instance-norm statistics over the time axis (L) of x (B,L,DV) fp32.
// ---------------------------------------------------------------------------
__global__ __launch_bounds__(256)
void stats_k(const float* __restrict__ x, float* __restrict__ means,
             float* __restrict__ stdev, float* __restrict__ rstd,
             float* __restrict__ xlast)
{
  int d = blockIdx.x * 256 + threadIdx.x;       // 0..511
  int b = blockIdx.y;
  const float* xp = x + (size_t)b * L_ * DV_ + d;
  float s = 0.f, ss = 0.f;
  for (int l = 0; l < L_; l++) {
    float v = xp[(size_t)l * DV_];
    s += v; ss += v * v;
  }
  float mu = s / (float)L_;
  float var = ss / (float)L_ - mu * mu;
  float sd = sqrtf(var + 1e-5f);
  float rs = 1.f / sd;
  int idx = b * DV_ + d;
  means[idx] = mu; stdev[idx] = sd; rstd[idx] = rs;
  xlast[idx] = (xp[(size_t)(L_ - 1) * DV_] - mu) * rs;
}

// ---------------------------------------------------------------------------
// Normalize + transpose: xnT[b,d,l] = (x[b,l,d]-mu[b,d])*rstd[b,d]  (bf16)
// ---------------------------------------------------------------------------
__global__ __launch_bounds__(256)
void tnorm_k(const float* __restrict__ x, const float* __restrict__ means,
             const float* __restrict__ rstd, short* __restrict__ xnT)
{
  __shared__ float tile[64][65];
  const int t = threadIdx.x;
  const int j = t & 63;
  const int i0 = t >> 6;                 // 0..3
  const int bz = blockIdx.z;
  const int l0 = blockIdx.y << 6;
  const int d0 = blockIdx.x << 6;
  const float* xp = x + ((size_t)bz * L_ + l0) * DV_ + d0;
  #pragma unroll
  for (int i = i0; i < 64; i += 4) tile[i][j] = xp[(size_t)i * DV_ + j];
  __syncthreads();
  short* op = xnT + ((size_t)bz * DV_ + d0) * L_ + l0;
  const int sb = bz * DV_ + d0;
  #pragma unroll
  for (int i = i0; i < 64; i += 4) {
    float mu = means[sb + i];
    float rs = rstd[sb + i];
    op[(size_t)i * L_ + j] = f2bf((tile[j][i] - mu) * rs);
  }
}

// ---------------------------------------------------------------------------
// Fused LayerNorm: optionally h += add (+ abias) in place, then LN -> bf16.
// ---------------------------------------------------------------------------
template <int ADD>
__global__ __launch_bounds__(256)
void ln_k(float* __restrict__ X, const short* __restrict__ add,
          const float* __restrict__ abias,
          const float* __restrict__ g, const float* __restrict__ b,
          short* __restrict__ Y)
{
  int row = blockIdx.x;
  float* x = X + (size_t)row * DM_;
  int t = threadIdx.x;
  float v0 = x[t], v1 = x[t + 256];
  if constexpr (ADD >= 1) {
    v0 += bf2f(add[(size_t)row * DM_ + t]);
    v1 += bf2f(add[(size_t)row * DM_ + t + 256]);
    if constexpr (ADD == 2) { v0 += abias[t]; v1 += abias[t + 256]; }
    x[t] = v0; x[t + 256] = v1;
  }
  float s = v0 + v1, ss = v0 * v0 + v1 * v1;
  #pragma unroll
  for (int o = 1; o < 64; o <<= 1) { s += __shfl_xor(s, o); ss += __shfl_xor(ss, o); }
  __shared__ float sb[8];
  int wave = t >> 6, lane = t & 63;
  if (lane == 0) { sb[wave] = s; sb[4 + wave] = ss; }
  __syncthreads();
  s = sb[0] + sb[1] + sb[2] + sb[3];
  ss = sb[4] + sb[5] + sb[6] + sb[7];
  float mu = s / (float)DM_;
  float var = ss / (float)DM_ - mu * mu;
  float rs = rsqrtf(var + 1e-5f);
  Y[(size_t)row * DM_ + t]       = f2bf((v0 - mu) * rs * g[t]       + b[t]);
  Y[(size_t)row * DM_ + t + 256] = f2bf((v1 - mu) * rs * g[t + 256] + b[t + 256]);
}

// ---------------------------------------------------------------------------
// Depthwise causal conv (DC=4 taps) + bias + silu.  Vectorized, 8 ch/thread.
// FORWARD ONLY: dir-1 input arrives already time-reversed (v-domain).
// ---------------------------------------------------------------------------
__global__ __launch_bounds__(256)
void conv_k(const short* __restrict__ xcin, const float* __restrict__ w,
            const float* __restrict__ cb, short* __restrict__ xcout)
{
  int idx = blockIdx.x * 256 + threadIdx.x;   // over B*S*DI/8
  int ig = (idx & 127) << 3;                  // channel group base
  int bs = idx >> 7;                          // b*S + tau
  int tt0 = bs & (S_ - 1);
  int b = bs >> 9;
  const short* u = xcin + (size_t)(b * S_) * DI_ + ig;  // row stride DI
  float4 wv[8];
  #pragma unroll
  for (int n = 0; n < 8; n++) wv[n] = *(const float4*)(w + (ig + n) * DC_);
  float acc[8];
  {
    float4 c0 = *(const float4*)(cb + ig);
    float4 c1 = *(const float4*)(cb + ig + 4);
    acc[0] = c0.x; acc[1] = c0.y; acc[2] = c0.z; acc[3] = c0.w;
    acc[4] = c1.x; acc[5] = c1.y; acc[6] = c1.z; acc[7] = c1.w;
  }
  #pragma unroll
  for (int k = 0; k < DC_; k++) {
    int tt = tt0 - (DC_ - 1) + k;
    if (tt >= 0) {
      bf16x8 uv = *(const bf16x8*)(u + (size_t)tt * DI_);
      #pragma unroll
      for (int n = 0; n < 8; n++) {
        float wk = (k == 0) ? wv[n].x : (k == 1) ? wv[n].y
                 : (k == 2) ? wv[n].z : wv[n].w;
        acc[n] += wk * bf2f(uv[n]);
      }
    }
  }
  union { short sh[8]; bf16x8 v; } r;
  #pragma unroll
  for (int n = 0; n < 8; n++) {
    float sig = 1.f / (1.f + __expf(-acc[n]));
    r.sh[n] = f2bf(acc[n] * sig);
  }
  *(bf16x8*)(xcout + ((size_t)bs << 10) + ig) = r.v;
}

// ---------------------------------------------------------------------------
// Chunked selective scan, both dirs fused, forward-only traversal.
// Round 12: CHUNK INPUTS STAGED TO LDS via global_load_lds DMA.  A block
// covers (dir,b, 64 channels x 4 quads) x one 32-step chunk; its whole
// input is dt 4KB + u 4KB (+ z 4KB) + B/C 2KB — one coalesced burst at
// kernel start, then the steady-state loop issues ZERO global loads: only
// ds_read with immediate offsets (dt/u/z: 16 addr/wave over 8 banks =
// 2-way = free; B/C: 16-lane broadcast).  Kills the per-step VMEM latency
// the round-11 reg-batching only partially hid, and the 16x-redundant
// B/C fetches (B/C depend on (b,t) only).  LDS 14KB (p3) / 9KB (p1) at
// 8 blocks/CU = 112/72KB < 160KB — occupancy unchanged.
// ---------------------------------------------------------------------------
__global__ __launch_bounds__(256)
void scan_p1(const unsigned short* __restrict__ dt16, const short* __restrict__ xc,
             const short* __restrict__ xdbl, const float* __restrict__ A_log,
             unsigned short* __restrict__ part_h, unsigned short* __restrict__ part_A)
{
  __shared__ short ldt[CS_ * 64];   // [32][64] fp16 dt
  __shared__ short lu [CS_ * 64];   // [32][64] bf16 u
  __shared__ short lb [CS_ * 16];   // [32][16] bf16 B
  const int tid = threadIdx.x;
  const int bid = blockIdx.x;                 // 0..255
  const int c = blockIdx.y;
  const int q = tid & 3;
  const int il = tid >> 2;                    // 0..63
  const int i = ((bid & 15) << 6) + il;
  const int b = (bid >> 4) & (B_ - 1);
  const int dir = bid >> 7;

  {  // stage: dt,u rows [32][64] (16B/thread each); B rows [32][16] (wave 0)
    const int srow = tid >> 3, scol = (tid & 7) << 3;
    const size_t g = (size_t)dir * M_ * DI_ +
                     ((size_t)b * S_ + c * CS_ + srow) * DI_ + ((bid & 15) << 6) + scol;
    const int wb = (tid >> 6) << 9;           // wave*512 shorts
    gload16((const short*)dt16 + g, &ldt[wb]);
    gload16(xc + g, &lu[wb]);
    if (tid < 64) {
      const int brow = tid >> 1, bcol = (tid & 1) << 3;
      const size_t gb = (size_t)dir * M_ * 64 +
                        ((size_t)b * S_ + c * CS_ + brow) * 64 + DTR_ + bcol;
      gload16(xdbl + gb, &lb[0]);
    }
  }
  asm volatile("s_waitcnt vmcnt(0)" ::: "memory");
  __builtin_amdgcn_s_barrier();

  float Ai2[4];
  const float* al = A_log + (size_t)dir * DI_ * DS_ + i * DS_ + q * 4;
  #pragma unroll
  for (int n = 0; n < 4; n++) Ai2[n] = -__expf(al[n]) * LOG2E_;

  float h[4];
  #pragma unroll
  for (int n = 0; n < 4; n++) h[n] = 0.f;
  float dsum = 0.f;

  const unsigned short* pdt = (const unsigned short*)ldt + il;
  const short* pu = lu + il;
  const short* pb = lb + q * 4;
  for (int s0 = 0; s0 < CS_; s0 += 8) {
    #pragma unroll
    for (int k = 0; k < 8; k++) {
      float dtv = h2f(pdt[k * 64]);
      float u = bf2f(pu[k * 64]);
      bf16x4 vB = *(const bf16x4*)(pb + k * 16);
      float du = dtv * u;
      dsum += dtv;
      #pragma unroll
      for (int n = 0; n < 4; n++) {
        float dA = exp2n(dtv * Ai2[n]);
        h[n] = dA * h[n] + du * bf2f(vB[n]);
      }
    }
    pdt += 512; pu += 512; pb += 128;
  }
  union { unsigned short s[4]; int2 v; } uh, ua;
  #pragma unroll
  for (int n = 0; n < 4; n++) {
    uh.s[n] = f2h(h[n]);
    ua.s[n] = f2h(exp2n(Ai2[n] * dsum));   // exact: prod exp(dt*A)=exp(A*sum dt)
  }
  const size_t ix = ((((size_t)c * 2 * B_ + dir * B_ + b) * DI_ + i) << 4) + (q << 2);
  *(int2*)(part_h + ix) = uh.v;
  *(int2*)(part_A + ix) = ua.v;
}

__global__ __launch_bounds__(256)
void scan_p2(unsigned short* __restrict__ part_h,
             const unsigned short* __restrict__ part_A)
{
  const size_t gid = (size_t)blockIdx.x * 256 + threadIdx.x;   // 2*B*DI*DS
  const size_t stride = (size_t)2 * B_ * DI_ * DS_;
  float hin = 0.f;
  #pragma unroll
  for (int c = 0; c < CH_; c++) {
    size_t ix = (size_t)c * stride + gid;
    float hh = h2f(part_h[ix]);
    float pA = h2f(part_A[ix]);
    part_h[ix] = f2h(hin);            // becomes chunk c's incoming state
    hin = hh + pA * hin;
  }
}

// y overwrites dt16 in place; reads come from the LDS snapshot staged
// before any store, so there is no RAW hazard at all.
__global__ __launch_bounds__(256)
void scan_p3(unsigned short* dt16, const short* __restrict__ xc,
             const short* __restrict__ xdbl, const short* __restrict__ zb,
             const float* __restrict__ A_log, const float* __restrict__ Dp,
             const unsigned short* __restrict__ part_h)
{
  __shared__ short ldt[CS_ * 64];   // [32][64] fp16 dt
  __shared__ short lu [CS_ * 64];   // [32][64] bf16 u
  __shared__ short lz [CS_ * 64];   // [32][64] bf16 silu(z)
  __shared__ short lbc[CS_ * 32];   // [32][32] bf16 B|C
  const int tid = threadIdx.x;
  const int bid = blockIdx.x;
  const int c = blockIdx.y;
  const int q = tid & 3;
  const int il = tid >> 2;
  const int i = ((bid & 15) << 6) + il;
  const int b = (bid >> 4) & (B_ - 1);
  const int dir = bid >> 7;

  const size_t base = (size_t)dir * M_ * DI_ +
                      ((size_t)b * S_ + c * CS_) * DI_ + ((bid & 15) << 6);
  {  // stage: dt,u,z rows [32][64]; B|C rows [32][32] (waves 0-1)
    const int srow = tid >> 3, scol = (tid & 7) << 3;
    const size_t g = base + (size_t)srow * DI_ + scol;
    const int wb = (tid >> 6) << 9;
    gload16((const short*)dt16 + g, &ldt[wb]);
    gload16(xc + g, &lu[wb]);
    gload16(zb + g, &lz[wb]);
    if (tid < 128) {
      const int brow = tid >> 2, bcol = (tid & 3) << 3;
      const size_t gb = (size_t)dir * M_ * 64 +
                        ((size_t)b * S_ + c * CS_ + brow) * 64 + DTR_ + bcol;
      gload16(xdbl + gb, &lbc[(tid >> 6) << 9]);
    }
  }
  asm volatile("s_waitcnt vmcnt(0)" ::: "memory");
  __builtin_amdgcn_s_barrier();

  float Ai2[4];
  const float* al = A_log + (size_t)dir * DI_ * DS_ + i * DS_ + q * 4;
  #pragma unroll
  for (int n = 0; n < 4; n++) Ai2[n] = -__expf(al[n]) * LOG2E_;
  const float Di = Dp[(size_t)dir * DI_ + i];

  float h[4];
  {
    const size_t ix = ((((size_t)c * 2 * B_ + dir * B_ + b) * DI_ + i) << 4) + (q << 2);
    union { unsigned short s[4]; int2 v; } uh;
    uh.v = *(const int2*)(part_h + ix);
    #pragma unroll
    for (int n = 0; n < 4; n++) h[n] = h2f(uh.s[n]);
  }

  const unsigned short* pdt = (const unsigned short*)ldt + il;
  const short* pu = lu + il;
  const short* pz = lz + il;
  const short* pbc = lbc + q * 4;
  short* py = (short*)dt16 + base + il;       // y over dt (global)

  for (int s0 = 0; s0 < CS_; s0 += 4) {
    #pragma unroll
    for (int k = 0; k < 4; k++) {
      float dtv = h2f(pdt[k * 64]);
      float u = bf2f(pu[k * 64]);
      float sil = bf2f(pz[k * 64]);
      bf16x4 vB = *(const bf16x4*)(pbc + k * 32);
      bf16x4 vC = *(const bf16x4*)(pbc + k * 32 + 16);
      float du = dtv * u;
      float yp = 0.f;
      #pragma unroll
      for (int n = 0; n < 4; n++) {
        float dA = exp2n(dtv * Ai2[n]);
        h[n] = dA * h[n] + du * bf2f(vB[n]);
        yp += h[n] * bf2f(vC[n]);
      }
      yp += __shfl_xor(yp, 1);
      yp += __shfl_xor(yp, 2);          // quad-wide sum over all 16 states
      float yv = (yp + u * Di) * sil;
      if (q == 0) py[(size_t)k * DI_] = f2bf(yv);
    }
    pdt += 256; pu += 256; pz += 256; pbc += 128; py += 4 * DI_;
  }
}

// ---------------------------------------------------------------------------
// bf16 MFMA GEMM: C[M,N] = A[M,K] * W[N,K]^T, fp32 accum.  global_load_lds
// DMA staging, source-swizzled, 3 LDS buffers, counted vmcnt.
// khalf: concat-K source switch.  mhalf: block-uniform M-half W switch.
// REVA: reverse time (row^511) when reading A1 slabs.
// INPROJ epilogues: z-half is written as silu(z) (scan consumes it directly).
// ---------------------------------------------------------------------------
enum { EPI_F32_BIAS, EPI_BF16, EPI_F16_SOFTPLUS, EPI_HALF_BF16, EPI_GELU,
       EPI_PROJ, EPI_INPROJ, EPI_INPROJ_REV };

template <int EPI, int BM, int BN, int BK, int REVA = 0>
__global__ __launch_bounds__(256)
void gemm_k(const short* __restrict__ A0, const short* __restrict__ A1,
            const short* __restrict__ W0, const short* __restrict__ W1,
            int khalf, int mhalf, int N, int K, int lda, int ldw,
            float* __restrict__ Cf, short* __restrict__ Cb, int ldc,
            const float* __restrict__ bias,
            const float* __restrict__ xlast, const float* __restrict__ stdev,
            const float* __restrict__ means)
{
  constexpr int MT = BM / 32;
  constexpr int NT = BN / 32;
  constexpr int KS = BK / 32;
  constexpr int CHK = BK / 8;
  constexpr int MSK = CHK - 1;
  constexpr int NA = (BM * CHK) / 256;
  constexpr int NW = (BN * CHK) / 256;
  constexpr int VC = NA + NW;
  __shared__ __align__(16) short As[3][BM * BK];
  __shared__ __align__(16) short Ws[3][BN * BK];
  const int tid = threadIdx.x;
  const int m0 = blockIdx.x * BM;
  const int n0 = blockIdx.y * BN;
  const int wave = tid >> 6, lane = tid & 63;
  const int wm = (wave & 1) * (BM / 2), wn = (wave >> 1) * (BN / 2);
  const int quad = lane >> 4, l16 = lane & 15;

  const short* W0m = (m0 < mhalf) ? W0 : W1;   // block-uniform M-half switch

  f32x4 acc[MT][NT] = {};

  size_t aoff[NA], aoffR[REVA ? NA : 1];
  #pragma unroll
  for (int j = 0; j < NA; j++) {
    int id = j * 256 + tid;
    int r = id / CHK, qp = id % CHK;
    aoff[j] = (size_t)(m0 + r) * lda + ((qp ^ (r & MSK)) << 3);
    if constexpr (REVA)
      aoffR[j] = (size_t)((m0 + r) ^ (S_ - 1)) * lda + ((qp ^ (r & MSK)) << 3);
  }
  size_t woff[NW];
  #pragma unroll
  for (int j = 0; j < NW; j++) {
    int id = j * 256 + tid;
    int r = id / CHK, qp = id % CHK;
    int wr = n0 + r; if (wr > N - 1) wr = N - 1;
    woff[j] = (size_t)wr * ldw + ((qp ^ (r & MSK)) << 3);
  }
  const int lbase = wave * 512;

  const int KB = K / BK;

  auto stage = [&](int slab, int bi) {
    const int k0 = slab * BK;
    const short* Ab = (k0 < khalf) ? A0 + k0 : A1 + (k0 - khalf);
    const short* Wb = (k0 < khalf) ? W0m + k0 : W1 + (k0 - khalf);
    const size_t* ao = (REVA && k0 >= khalf) ? aoffR : aoff;
    #pragma unroll
    for (int j = 0; j < NA; j++)
      gload16(Ab + ao[j], &As[bi][j * 2048 + lbase]);
    #pragma unroll
    for (int j = 0; j < NW; j++)
      gload16(Wb + woff[j], &Ws[bi][j * 2048 + lbase]);
  };

  stage(0, 0);
  if (KB > 1) stage(1, 1);
  __builtin_amdgcn_sched_barrier(0);
  if (KB > 1) asm volatile("s_waitcnt vmcnt(%0)" :: "n"(VC) : "memory");
  else        asm volatile("s_waitcnt vmcnt(0)" ::: "memory");
  __builtin_amdgcn_s_barrier();
  __builtin_amdgcn_sched_barrier(0);

  int cur = 0, nxt = 2;
  for (int kb = 0; kb < KB; kb++) {
    if (kb + 2 < KB) {
      stage(kb + 2, nxt);
      __builtin_amdgcn_sched_barrier(0);
    }
    bf16x8 af[MT][KS], bfr[NT][KS];
    #pragma unroll
    for (int mt = 0; mt < MT; mt++)
      #pragma unroll
      for (int st = 0; st < KS; st++)
        af[mt][st] = *(const bf16x8*)(&As[cur][0] + (wm + mt * 16 + l16) * BK +
                                      (((st * 4 + quad) ^ (l16 & MSK)) << 3));
    #pragma unroll
    for (int nt = 0; nt < NT; nt++)
      #pragma unroll
      for (int st = 0; st < KS; st++)
        bfr[nt][st] = *(const bf16x8*)(&Ws[cur][0] + (wn + nt * 16 + l16) * BK +
                                       (((st * 4 + quad) ^ (l16 & MSK)) << 3));
    #pragma unroll
    for (int st = 0; st < KS; st++)
      #pragma unroll
      for (int mt = 0; mt < MT; mt++)
        #pragma unroll
        for (int nt = 0; nt < NT; nt++)
          acc[mt][nt] = __builtin_amdgcn_mfma_f32_16x16x32_bf16(
              af[mt][st], bfr[nt][st], acc[mt][nt], 0, 0, 0);
    if (kb + 1 < KB) {
      __builtin_amdgcn_sched_barrier(0);
      if (kb + 2 < KB) asm volatile("s_waitcnt vmcnt(%0)" :: "n"(VC) : "memory");
      else             asm volatile("s_waitcnt vmcnt(0)" ::: "memory");
      __builtin_amdgcn_s_barrier();
      __builtin_amdgcn_sched_barrier(0);
      cur = (cur == 2) ? 0 : cur + 1;
      nxt = (nxt == 2) ? 0 : nxt + 1;
    }
  }

  const int boff = (m0 < mhalf) ? 0 : N;   // M-half bias switch (contiguous)

  #pragma unroll
  for (int mt = 0; mt < MT; mt++) {
    #pragma unroll
    for (int nt = 0; nt < NT; nt++) {
      int n = n0 + wn + nt * 16 + l16;
      if (n >= N) continue;
      #pragma unroll
      for (int r = 0; r < 4; r++) {
        int m = m0 + wm + mt * 16 + quad * 4 + r;
        float v = acc[mt][nt][r];
        if constexpr (EPI == EPI_F32_BIAS) {
          Cf[(size_t)m * ldc + n] = v + bias[n];
        } else if constexpr (EPI == EPI_BF16) {
          Cb[(size_t)m * ldc + n] = f2bf(v);
        } else if constexpr (EPI == EPI_F16_SOFTPLUS) {
          float tt = v + bias[n + boff];
          float sp = (tt > 20.f) ? tt : log1pf(__expf(tt));
          ((unsigned short*)Cb)[(size_t)m * ldc + n] = f2h(sp);
        } else if constexpr (EPI == EPI_HALF_BF16) {
          Cb[(size_t)m * ldc + n] = f2bf(0.5f * v);
        } else if constexpr (EPI == EPI_GELU) {
          float tt = v + bias[n];
          Cb[(size_t)m * ldc + n] = f2bf(0.5f * tt * (1.f + erff(tt * 0.70710678118f)));
        } else if constexpr (EPI == EPI_PROJ) {
          int bb = m >> 9, d = m & 511;
          float tt = v + bias[n] + xlast[m];
          tt = tt * stdev[m] + means[m];
          Cf[((size_t)bb * PL_ + n) * DV_ + d] = tt;
        } else if constexpr (EPI == EPI_INPROJ) {
          if (n < DI_) Cb[(size_t)m * ldc + n] = f2bf(v);
          else {
            float sz = v / (1.f + __expf(-v));     // pre-apply silu to z
            ((short*)Cf)[(size_t)m * DI_ + (n - DI_)] = f2bf(sz);
          }
        } else if constexpr (EPI == EPI_INPROJ_REV) {
          // store in reversed time-domain: row m -> m^511 (t -> S-1-t)
          int mr = m ^ (S_ - 1);
          if (n < DI_) Cb[(size_t)mr * ldc + n] = f2bf(v);
          else {
            float sz = v / (1.f + __expf(-v));     // pre-apply silu to z
            ((short*)Cf)[(size_t)mr * DI_ + (n - DI_)] = f2bf(sz);
          }
        }
      }
    }
  }
}

// ---------------------------------------------------------------------------
extern "C" void kernel_launch(void* const* d_in, const int* in_sizes, int n_in,
                              void* d_out, int out_size, void* d_ws, size_t ws_size,
                              hipStream_t stream)
{
  (void)in_sizes; (void)n_in; (void)out_size; (void)ws_size;
  const float* x        = (const float*)d_in[0];
  const float* emb_w    = (const float*)d_in[1];
  const float* emb_b    = (const float*)d_in[2];
  const float* ln_g     = (const float*)d_in[3];
  const float* ln_b     = (const float*)d_in[4];
  const float* m_in_w   = (const float*)d_in[5];
  const float* m_conv_w = (const float*)d_in[6];
  const float* m_conv_b = (const float*)d_in[7];
  const float* m_xp_w   = (const float*)d_in[8];
  const float* m_dt_w   = (const float*)d_in[9];
  const float* m_dt_b   = (const float*)d_in[10];
  const float* m_A_log  = (const float*)d_in[11];
  const float* m_D      = (const float*)d_in[12];
  const float* m_out_w  = (const float*)d_in[13];
  const float* ffn_ln_g = (const float*)d_in[14];
  const float* ffn_ln_b = (const float*)d_in[15];
  const float* ffn_w1   = (const float*)d_in[16];
  const float* ffn_b1   = (const float*)d_in[17];
  const float* ffn_w2   = (const float*)d_in[18];
  const float* ffn_b2   = (const float*)d_in[19];
  const float* enc_g    = (const float*)d_in[20];
  const float* enc_b    = (const float*)d_in[21];
  const float* proj_w   = (const float*)d_in[22];
  const float* proj_b   = (const float*)d_in[23];
  float* out = (float*)d_out;

  char* ws = (char*)d_ws;
  const size_t MB = 1024 * 1024;
  // Layout (high-water 112 MB), identical to rounds 8-11:
  //  0-8   h | 8-12 hn | 12-16 ftmp/vtmp | 16-24 conv scratch (+part_h alias)
  //  8-16  part_A alias | 24-40 zbuf/xnT/f1out | 40-56 xc | 56-72 dtb (y in
  //  place) | 72-73 xdbl | 73 stats | 80-112 bf16 weight pool
  float* h      = (float*)(ws + 0);
  short* hn     = (short*)(ws + 8 * MB);
  short* ftmp   = (short*)(ws + 12 * MB);
  short* vtmp   = ftmp;
  short* scratch= (short*)(ws + 16 * MB);
  short* zbuf   = (short*)(ws + 24 * MB);
  short* xnT    = zbuf;
  short* f1out  = zbuf;
  short* xc     = (short*)(ws + 40 * MB);
  unsigned short* dtb = (unsigned short*)(ws + 56 * MB);
  short* xdbl   = (short*)(ws + 72 * MB);
  float* stats  = (float*)(ws + 73 * MB);
  unsigned short* part_A = (unsigned short*)(ws + 8 * MB);
  unsigned short* part_h = (unsigned short*)(ws + 16 * MB);
  float* means = stats, *stdevp = stats + 4096, *rstd = stats + 8192, *xlast = stats + 12288;

  short* emb_wb = (short*)(ws + 80 * MB);
  short* in_wb  = emb_wb + 262144;      // 6 x 2048x512
  short* xp_wb  = in_wb  + 6291456;     // 6 x 64x1024
  short* dt_wb  = xp_wb  + 393216;      // 6 x 1024x32
  short* out_wb = dt_wb  + 196608;      // 6 x 512x1024
  short* w1b    = out_wb + 3145728;     // 3 x 2048x512
  short* w2b    = w1b    + 3145728;     // 3 x 512x2048
  short* projb  = w2b    + 3145728;     // 96x512

  dim3 blk(256);
  const int NOSPLIT = 1 << 30;

  wcvt_k<<<dim3(16240), blk, 0, stream>>>(
      emb_w, m_in_w, m_xp_w, m_dt_w, m_out_w, ffn_w1, ffn_w2, proj_w,
      emb_wb, in_wb, xp_wb, dt_wb, out_wb, w1b, w2b, projb);

  stats_k<<<dim3(2, B_), blk, 0, stream>>>(x, means, stdevp, rstd, xlast);
  tnorm_k<<<dim3(8, 8, B_), blk, 0, stream>>>(x, means, rstd, xnT);
  // emb: M=4096, N=512, K=512
  gemm_k<EPI_F32_BIAS, 64, 32, 64><<<dim3(64, 16), blk, 0, stream>>>(
      xnT, xnT, emb_wb, emb_wb, NOSPLIT, NOSPLIT, DM_, L_, L_, L_,
      h, nullptr, DM_, emb_b, nullptr, nullptr, nullptr);

  for (int il = 0; il < EL_; il++) {
    if (il == 0)
      ln_k<0><<<dim3(4096), blk, 0, stream>>>(h, nullptr, nullptr, ln_g, ln_b, hn);
    else
      ln_k<2><<<dim3(4096), blk, 0, stream>>>(h, ftmp, ffn_b2 + (il - 1) * DM_,
          ln_g + il * DM_, ln_b + il * DM_, hn);
    for (int dir = 0; dir < 2; dir++) {
      int mod = 2 * il + dir;
      // in-proj dir: N=2048, K=512; dir1 stores BOTH outputs time-reversed;
      // z-half stored as silu(z)
      if (dir == 0)
        gemm_k<EPI_INPROJ, 64, 128, 32><<<dim3(64, 16), blk, 0, stream>>>(
            hn, hn, in_wb + (size_t)mod * 2 * DI_ * DM_,
            in_wb + (size_t)mod * 2 * DI_ * DM_, NOSPLIT, NOSPLIT,
            2 * DI_, DM_, DM_, DM_,
            (float*)(zbuf + (size_t)dir * M_ * DI_), scratch, DI_,
            nullptr, nullptr, nullptr, nullptr);
      else
        gemm_k<EPI_INPROJ_REV, 64, 128, 32><<<dim3(64, 16), blk, 0, stream>>>(
            hn, hn, in_wb + (size_t)mod * 2 * DI_ * DM_,
            in_wb + (size_t)mod * 2 * DI_ * DM_, NOSPLIT, NOSPLIT,
            2 * DI_, DM_, DM_, DM_,
            (float*)(zbuf + (size_t)dir * M_ * DI_), scratch, DI_,
            nullptr, nullptr, nullptr, nullptr);
      // conv: plain forward for both dirs (dir1 input already reversed)
      conv_k<<<dim3(2048), blk, 0, stream>>>(
          scratch, m_conv_w + (size_t)mod * DI_ * DC_,
          m_conv_b + (size_t)mod * DI_, xc + (size_t)dir * M_ * DI_);
    }
    // xdbl (both dirs): M=8192, N=64, K=1024; W switches at m=4096
    gemm_k<EPI_BF16, 32, 32, 64><<<dim3(256, 2), blk, 0, stream>>>(
        xc, xc, xp_wb + (size_t)(2 * il) * 64 * DI_,
        xp_wb + (size_t)(2 * il + 1) * 64 * DI_, NOSPLIT, M_,
        64, DI_, DI_, DI_,
        nullptr, xdbl, 64, nullptr, nullptr, nullptr, nullptr);
    // dt (both dirs): M=8192, N=1024, K=32; W+bias switch at m=4096
    gemm_k<EPI_F16_SOFTPLUS, 64, 64, 32><<<dim3(128, 16), blk, 0, stream>>>(
        xdbl, xdbl, dt_wb + (size_t)(2 * il) * DI_ * DTR_,
        dt_wb + (size_t)(2 * il + 1) * DI_ * DTR_, NOSPLIT, M_,
        DI_, DTR_, 64, DTR_,
        nullptr, (short*)dtb, DI_, m_dt_b + (size_t)(2 * il) * DI_,
        nullptr, nullptr, nullptr);
    // fused scans, LDS-staged: grid (256,16) = 4096 blocks
    const float* Alog = m_A_log + (size_t)(2 * il) * DI_ * DS_;
    const float* Dp = m_D + (size_t)(2 * il) * DI_;
    scan_p1<<<dim3(256, CH_), blk, 0, stream>>>(dtb, xc, xdbl, Alog, part_h, part_A);
    scan_p2<<<dim3(1024), blk, 0, stream>>>(part_h, part_A);
    scan_p3<<<dim3(256, CH_), blk, 0, stream>>>(dtb, xc, xdbl, zbuf, Alog, Dp, part_h);
    // out-proj (concat-K over y0|y1); A1 rows un-reversed via REVA=1
    gemm_k<EPI_HALF_BF16, 64, 32, 64, 1><<<dim3(64, 16), blk, 0, stream>>>(
        (const short*)dtb, (const short*)(dtb + (size_t)M_ * DI_),
        out_wb + (size_t)(2 * il) * DM_ * DI_,
        out_wb + (size_t)(2 * il + 1) * DM_ * DI_,
        DI_, NOSPLIT, DM_, 2 * DI_, DI_, DI_,
        nullptr, vtmp, DM_, nullptr, nullptr, nullptr, nullptr);
    ln_k<1><<<dim3(4096), blk, 0, stream>>>(h, vtmp, nullptr,
        ffn_ln_g + il * DM_, ffn_ln_b + il * DM_, hn);
    // ffn1: N=2048, K=512 -> f1out [M][2048]
    gemm_k<EPI_GELU, 64, 128, 32><<<dim3(64, 16), blk, 0, stream>>>(
        hn, hn, w1b + (size_t)il * 4 * DM_ * DM_,
        w1b + (size_t)il * 4 * DM_ * DM_, NOSPLIT, NOSPLIT,
        4 * DM_, DM_, DM_, DM_,
        nullptr, f1out, 4 * DM_, ffn_b1 + (size_t)il * 4 * DM_,
        nullptr, nullptr, nullptr);
    // ffn2: N=512, K=2048 -> ftmp
    gemm_k<EPI_BF16, 64, 32, 64><<<dim3(64, 16), blk, 0, stream>>>(
        f1out, f1out, w2b + (size_t)il * DM_ * 4 * DM_,
        w2b + (size_t)il * DM_ * 4 * DM_, NOSPLIT, NOSPLIT,
        DM_, 4 * DM_, 4 * DM_, 4 * DM_,
        nullptr, ftmp, DM_, nullptr, nullptr, nullptr, nullptr);
  }

  ln_k<2><<<dim3(4096), blk, 0, stream>>>(h, ftmp, ffn_b2 + 2 * DM_,
      enc_g, enc_b, hn);
  // proj: N=96, K=512
  gemm_k<EPI_PROJ, 64, 32, 64><<<dim3(64, 3), blk, 0, stream>>>(
      hn, hn, projb, projb, NOSPLIT, NOSPLIT, PL_, DM_, DM_, DM_,
      out, nullptr, 0, proj_b, xlast, stdevp, means);
}